// Round 1
// baseline (1187.199 us; speedup 1.0000x reference)
//
#include <hip/hip_runtime.h>

#define NTOK 4096          // B*Lq = 2*2048
#define EMBED 1024
#define HEADS 16
#define HD 64
#define LQ 2048

// ---------------------------------------------------------------------------
// Kernel 1: materialize W[o][e] for one projection from its 3 TT cores.
//   o = q0*128 + q1*8 + q2,  e = i0*128 + i1*8 + i2
//   W[o,e] = sum_{s,s2} G0[0,i0,q0,s] * G1[s,i1,q1,s2] * G2[s2,i2,q2,0]
// grid = 64 blocks (one per (i0,q0)), 256 threads.
// ---------------------------------------------------------------------------
__global__ __launch_bounds__(256) void build_w_kernel(
    const float* __restrict__ c0,   // (1,8,8,16)
    const float* __restrict__ c1,   // (16,16,16,16)
    const float* __restrict__ c2,   // (16,8,8,1)
    float* __restrict__ W)          // [1024][1024]
{
    __shared__ float B1[16 * 16 * 16];   // [i1][q1][s2]
    const int i0 = blockIdx.x >> 3;
    const int q0 = blockIdx.x & 7;
    const int t  = threadIdx.x;

    float g0[16];
#pragma unroll
    for (int s = 0; s < 16; ++s) g0[s] = c0[(i0 * 8 + q0) * 16 + s];

    // stage 1: B1[i1][q1][s2] = sum_s g0[s] * G1[s,i1,q1,s2]
    for (int idx = t; idx < 4096; idx += 256) {
        const int s2 = idx & 15;
        const int q1 = (idx >> 4) & 15;
        const int i1 = idx >> 8;
        float acc = 0.f;
#pragma unroll
        for (int s = 0; s < 16; ++s)
            acc += g0[s] * c1[((s * 16 + i1) * 16 + q1) * 16 + s2];
        B1[idx] = acc;
    }
    __syncthreads();

    // stage 2: W[o,e] = sum_{s2} B1[i1,q1,s2] * G2[s2,i2,q2]
    for (int idx = t; idx < 16384; idx += 256) {
        const int q2 = idx & 7;
        const int i2 = (idx >> 3) & 7;
        const int q1 = (idx >> 6) & 15;
        const int i1 = idx >> 10;
        float acc = 0.f;
#pragma unroll
        for (int s2 = 0; s2 < 16; ++s2)
            acc += B1[(i1 * 16 + q1) * 16 + s2] * c2[(s2 * 8 + i2) * 8 + q2];
        const int o = q0 * 128 + q1 * 8 + q2;
        const int e = i0 * 128 + i1 * 8 + i2;
        W[o * 1024 + e] = acc;
    }
}

// ---------------------------------------------------------------------------
// Kernel 2: Y[n][c] = sum_e X[n][e] * W[c][e] + bias(c)   (NT gemm, K=1024)
// 64x64 block tile, 256 threads, 4x4 register micro-tile, K-chunk=32.
// bias pointer selected by c>>10 (for fused QKV: b0=wq_b, b1=wk_b, b2=wv_b).
// grid = (N/64, M/64)
// ---------------------------------------------------------------------------
__global__ __launch_bounds__(256) void gemm_xwt_kernel(
    const float* __restrict__ X,   // [M][1024]
    const float* __restrict__ W,   // [N][1024]
    const float* __restrict__ b0,
    const float* __restrict__ b1,
    const float* __restrict__ b2,
    float* __restrict__ Y,         // [M][N]
    int N)
{
    __shared__ float Xs[32][68];   // [e][n] transposed, +4 pad
    __shared__ float Ws[32][68];   // [e][c] transposed

    const int t  = threadIdx.x;
    const int tr = t >> 4, tc = t & 15;
    const int r0 = tr * 4, c0 = tc * 4;
    const int bn = blockIdx.x * 64;
    const int bm = blockIdx.y * 64;

    const int srow = t >> 3;         // 0..31
    const int se   = (t & 7) * 4;    // 0,4,...,28

    float acc[4][4] = {};

    for (int e0 = 0; e0 < 1024; e0 += 32) {
#pragma unroll
        for (int h = 0; h < 2; ++h) {
            const int row = srow + h * 32;      // 0..63
            const float4 xv = *(const float4*)&X[(size_t)(bm + row) * 1024 + e0 + se];
            Xs[se + 0][row] = xv.x; Xs[se + 1][row] = xv.y;
            Xs[se + 2][row] = xv.z; Xs[se + 3][row] = xv.w;
            const float4 wv = *(const float4*)&W[(size_t)(bn + row) * 1024 + e0 + se];
            Ws[se + 0][row] = wv.x; Ws[se + 1][row] = wv.y;
            Ws[se + 2][row] = wv.z; Ws[se + 3][row] = wv.w;
        }
        __syncthreads();
#pragma unroll 8
        for (int kk = 0; kk < 32; ++kk) {
            const float4 a = *(const float4*)&Xs[kk][r0];
            const float4 b = *(const float4*)&Ws[kk][c0];
            const float av[4] = {a.x, a.y, a.z, a.w};
            const float bv[4] = {b.x, b.y, b.z, b.w};
#pragma unroll
            for (int i = 0; i < 4; ++i)
#pragma unroll
                for (int j = 0; j < 4; ++j) acc[i][j] += av[i] * bv[j];
        }
        __syncthreads();
    }

#pragma unroll
    for (int i = 0; i < 4; ++i) {
        const int row = bm + r0 + i;
#pragma unroll
        for (int j = 0; j < 4; ++j) {
            const int col = bn + c0 + j;
            const float* bp = (col < 1024) ? b0 : (col < 2048) ? b1 : b2;
            acc[i][j] += bp[col & 1023];
        }
        float4 o4 = {acc[i][0], acc[i][1], acc[i][2], acc[i][3]};
        *(float4*)&Y[(size_t)row * N + bn + c0] = o4;
    }
}

// ---------------------------------------------------------------------------
// Kernel 3: flash attention, fp32.
// QKV: [4096][3072] (q | k | v each 1024 wide, col = h*64 + d)
// CTX: [4096][1024], ctx[b*2048+q][h*64+d]
// grid = (32 qtiles, 16 heads, 2 batches), 256 threads. Q-tile 64, K-tile 64.
// ---------------------------------------------------------------------------
__global__ __launch_bounds__(256) void attn_kernel(
    const float* __restrict__ QKV,
    float* __restrict__ CTX)
{
    __shared__ float Qs[64][68];   // [d][r], pre-scaled
    __shared__ float Ks[64][68];   // [d][k]
    __shared__ float Vs[64][68];   // [k][d]
    __shared__ float Ps[64][68];   // [k][r]

    const int t  = threadIdx.x;
    const int qt = blockIdx.x;
    const int h  = blockIdx.y;
    const int b  = blockIdx.z;
    const int base_row = b * LQ;
    const int colQ = h * 64;

    const int tr = t >> 4, tc = t & 15;
    const int r0 = tr * 4, c0 = tc * 4;

    // stage Q tile (transposed, scaled by 1/8)
    {
        const int rr = t >> 4;            // 0..15
        const int d0 = (t & 15) * 4;
#pragma unroll
        for (int it = 0; it < 4; ++it) {
            const int r = rr + it * 16;
            const float4 q4 = *(const float4*)&QKV[(size_t)(base_row + qt * 64 + r) * 3072 + colQ + d0];
            Qs[d0 + 0][r] = q4.x * 0.125f;
            Qs[d0 + 1][r] = q4.y * 0.125f;
            Qs[d0 + 2][r] = q4.z * 0.125f;
            Qs[d0 + 3][r] = q4.w * 0.125f;
        }
    }

    float m[4], l[4];
    float oacc[4][4] = {};
#pragma unroll
    for (int j = 0; j < 4; ++j) { m[j] = -1e30f; l[j] = 0.f; }

    for (int kt = 0; kt < 32; ++kt) {
        __syncthreads();   // previous tile's Ps/Vs reads done before overwrite
        {
            const int rr = t >> 4;
            const int d0 = (t & 15) * 4;
#pragma unroll
            for (int it = 0; it < 4; ++it) {
                const int k = rr + it * 16;
                const size_t grow = (size_t)(base_row + kt * 64 + k) * 3072;
                const float4 k4 = *(const float4*)&QKV[grow + 1024 + colQ + d0];
                Ks[d0 + 0][k] = k4.x; Ks[d0 + 1][k] = k4.y;
                Ks[d0 + 2][k] = k4.z; Ks[d0 + 3][k] = k4.w;
                const float4 v4 = *(const float4*)&QKV[grow + 2048 + colQ + d0];
                *(float4*)&Vs[k][d0] = v4;
            }
        }
        __syncthreads();

        // scores: S[r][c] = sum_d Qs[d][r] * Ks[d][c]
        float s[4][4] = {};
#pragma unroll 8
        for (int d = 0; d < 64; ++d) {
            const float4 a = *(const float4*)&Qs[d][r0];
            const float4 bvec = *(const float4*)&Ks[d][c0];
            const float av[4] = {a.x, a.y, a.z, a.w};
            const float bv[4] = {bvec.x, bvec.y, bvec.z, bvec.w};
#pragma unroll
            for (int i = 0; i < 4; ++i)
#pragma unroll
                for (int j = 0; j < 4; ++j) s[i][j] += av[i] * bv[j];
        }

        // online softmax (rows distributed across 16 lanes: tc)
#pragma unroll
        for (int j = 0; j < 4; ++j) {
            float pm = fmaxf(fmaxf(s[j][0], s[j][1]), fmaxf(s[j][2], s[j][3]));
#pragma unroll
            for (int mask = 1; mask < 16; mask <<= 1)
                pm = fmaxf(pm, __shfl_xor(pm, mask, 64));
            const float mn = fmaxf(m[j], pm);
            const float alpha = __expf(m[j] - mn);
            float rs = 0.f;
#pragma unroll
            for (int i = 0; i < 4; ++i) {
                s[j][i] = __expf(s[j][i] - mn);
                rs += s[j][i];
            }
#pragma unroll
            for (int mask = 1; mask < 16; mask <<= 1)
                rs += __shfl_xor(rs, mask, 64);
            l[j] = l[j] * alpha + rs;
            m[j] = mn;
#pragma unroll
            for (int i = 0; i < 4; ++i) oacc[j][i] *= alpha;
        }

        // write P transposed: Ps[k][r]
#pragma unroll
        for (int cc = 0; cc < 4; ++cc) {
            float4 p4 = {s[0][cc], s[1][cc], s[2][cc], s[3][cc]};
            *(float4*)&Ps[c0 + cc][r0] = p4;
        }
        __syncthreads();

        // PV: oacc[j][i] += sum_k Ps[k][r0+j] * Vs[k][c0+i]
#pragma unroll 8
        for (int k = 0; k < 64; ++k) {
            const float4 pa = *(const float4*)&Ps[k][r0];
            const float4 vb = *(const float4*)&Vs[k][c0];
            const float pv[4] = {pa.x, pa.y, pa.z, pa.w};
            const float vv[4] = {vb.x, vb.y, vb.z, vb.w};
#pragma unroll
            for (int j = 0; j < 4; ++j)
#pragma unroll
                for (int i = 0; i < 4; ++i) oacc[j][i] += pv[j] * vv[i];
        }
    }

    // finalize + write ctx
#pragma unroll
    for (int j = 0; j < 4; ++j) {
        const float inv = 1.f / l[j];
        float4 o4 = {oacc[j][0] * inv, oacc[j][1] * inv, oacc[j][2] * inv, oacc[j][3] * inv};
        const int row = base_row + qt * 64 + r0 + j;
        *(float4*)&CTX[(size_t)row * 1024 + colQ + c0] = o4;
    }
}

// ---------------------------------------------------------------------------
extern "C" void kernel_launch(void* const* d_in, const int* in_sizes, int n_in,
                              void* d_out, int out_size, void* d_ws, size_t ws_size,
                              hipStream_t stream)
{
    const float* query = (const float*)d_in[0];
    float* ws    = (float*)d_ws;
    float* W_all = ws;                                   // [4096][1024]  (q,k,v,o)
    float* QKV   = ws + (size_t)4 * 1024 * 1024;         // [4096][3072]
    float* CTX   = QKV + (size_t)NTOK * 3072;            // [4096][1024]

    // 1) materialize the 4 TT weight matrices
    for (int p = 0; p < 4; ++p) {
        build_w_kernel<<<64, 256, 0, stream>>>(
            (const float*)d_in[1 + 4 * p],
            (const float*)d_in[2 + 4 * p],
            (const float*)d_in[3 + 4 * p],
            W_all + (size_t)p * 1024 * 1024);
    }

    // 2) fused QKV projection: [4096][3072]
    gemm_xwt_kernel<<<dim3(3072 / 64, NTOK / 64), 256, 0, stream>>>(
        query, W_all,
        (const float*)d_in[4], (const float*)d_in[8], (const float*)d_in[12],
        QKV, 3072);

    // 3) attention -> CTX [4096][1024]
    attn_kernel<<<dim3(32, HEADS, 2), 256, 0, stream>>>(QKV, CTX);

    // 4) output projection -> d_out
    gemm_xwt_kernel<<<dim3(1024 / 64, NTOK / 64), 256, 0, stream>>>(
        CTX, W_all + (size_t)3 * 1024 * 1024,
        (const float*)d_in[16], (const float*)d_in[16], (const float*)d_in[16],
        (float*)d_out, 1024);
}

// Round 3
// 416.842 us; speedup vs baseline: 2.8481x; 2.8481x over previous
//
#include <hip/hip_runtime.h>
#include <stdint.h>

#define LQ 2048
#define NTOK 4096

typedef __attribute__((ext_vector_type(8))) short short8;
typedef __attribute__((ext_vector_type(4))) float f32x4;
typedef __attribute__((ext_vector_type(4))) unsigned short u16x4;

#define MFMA16(a, b, c) __builtin_amdgcn_mfma_f32_16x16x32_bf16((a), (b), (c), 0, 0, 0)

__device__ __forceinline__ unsigned short f2bf(float x) {
    union { float f; uint32_t u; } v; v.f = x;
    uint32_t r = (v.u + 0x7FFFu + ((v.u >> 16) & 1u)) >> 16;
    return (unsigned short)r;
}
__device__ __forceinline__ float bf2f(unsigned short h) {
    union { uint32_t u; float f; } v; v.u = ((uint32_t)h) << 16; return v.f;
}

struct CorePtrs {
    const float* c0[4];
    const float* c1[4];
    const float* c2[4];
};

// ---------------------------------------------------------------------------
// Kernel 1: materialize W (bf16 hi + lo residual) for all 4 projections.
// grid = (64, 4): x = (i0,q0), y = projection. 256 threads.
// ---------------------------------------------------------------------------
__global__ __launch_bounds__(256) void build_w_kernel(
    CorePtrs cp, unsigned short* __restrict__ Whi, unsigned short* __restrict__ Wlo)
{
    __shared__ float B1[16 * 16 * 16];   // [i1][q1][s2]
    const int p  = blockIdx.y;
    const int i0 = blockIdx.x >> 3;
    const int q0 = blockIdx.x & 7;
    const int t  = threadIdx.x;
    const float* __restrict__ c0 = cp.c0[p];
    const float* __restrict__ c1 = cp.c1[p];
    const float* __restrict__ c2 = cp.c2[p];

    float g0[16];
#pragma unroll
    for (int s = 0; s < 16; ++s) g0[s] = c0[(i0 * 8 + q0) * 16 + s];

    for (int idx = t; idx < 4096; idx += 256) {
        const int s2 = idx & 15;
        const int q1 = (idx >> 4) & 15;
        const int i1 = idx >> 8;
        float acc = 0.f;
#pragma unroll
        for (int s = 0; s < 16; ++s)
            acc += g0[s] * c1[((s * 16 + i1) * 16 + q1) * 16 + s2];
        B1[idx] = acc;
    }
    __syncthreads();

    const size_t base = (size_t)p * 1024 * 1024;
    for (int idx = t; idx < 16384; idx += 256) {
        const int q2 = idx & 7;
        const int i2 = (idx >> 3) & 7;
        const int q1 = (idx >> 6) & 15;
        const int i1 = idx >> 10;
        float acc = 0.f;
#pragma unroll
        for (int s2 = 0; s2 < 16; ++s2)
            acc += B1[(i1 * 16 + q1) * 16 + s2] * c2[(s2 * 8 + i2) * 8 + q2];
        const int o = q0 * 128 + q1 * 8 + q2;
        const int e = i0 * 128 + i1 * 8 + i2;
        const unsigned short hi = f2bf(acc);
        Whi[base + o * 1024 + e] = hi;
        Wlo[base + o * 1024 + e] = f2bf(acc - bf2f(hi));
    }
}

// ---------------------------------------------------------------------------
// Kernel 2: fp32 -> bf16 hi/lo split of the input activations.
// ---------------------------------------------------------------------------
__global__ __launch_bounds__(256) void convert_x_kernel(
    const float* __restrict__ X, unsigned short* __restrict__ Xhi,
    unsigned short* __restrict__ Xlo, int n4)
{
    const int i = blockIdx.x * 256 + threadIdx.x;
    if (i >= n4) return;
    const float4 v = ((const float4*)X)[i];
    u16x4 hi, lo;
    float vv[4] = {v.x, v.y, v.z, v.w};
#pragma unroll
    for (int j = 0; j < 4; ++j) {
        unsigned short h = f2bf(vv[j]);
        hi[j] = h;
        lo[j] = f2bf(vv[j] - bf2f(h));
    }
    ((u16x4*)Xhi)[i] = hi;
    ((u16x4*)Xlo)[i] = lo;
}

// ---------------------------------------------------------------------------
// Kernel 3: MFMA NT-GEMM  Y[m][c] = sum_e X[m,e] W[c,e] (+bias)*oscale.
// 128x128 tile, 4 waves (2x2), 4x4 frags of 16x16x32, BK=32, reg-staged LDS.
// SPLIT: 3-pass hi/lo (near-fp32). OUTMODE 0: bf16 hi/lo out; 1: bf16 out;
// 2: f32 out.  N fixed = 1024, K = 1024.
// ---------------------------------------------------------------------------
template <bool SPLIT, int OUTMODE>
__global__ __launch_bounds__(256) void gemm_kernel(
    const unsigned short* __restrict__ Xh, const unsigned short* __restrict__ Xl,
    const unsigned short* __restrict__ Wh, const unsigned short* __restrict__ Wl,
    const float* __restrict__ bias, float oscale,
    unsigned short* __restrict__ Yhi, unsigned short* __restrict__ Ylo,
    float* __restrict__ Yf)
{
    __shared__ unsigned short Ah[128 * 32];
    __shared__ unsigned short Bh[128 * 32];
    __shared__ unsigned short Al[SPLIT ? 128 * 32 : 8];
    __shared__ unsigned short Bl[SPLIT ? 128 * 32 : 8];

    const int t = threadIdx.x;
    const int l = t & 63;
    const int w = t >> 6;
    const int wr = (w >> 1) * 64, wc = (w & 1) * 64;
    const int bm = blockIdx.y * 128, bn = blockIdx.x * 128;

    f32x4 acc[4][4];
#pragma unroll
    for (int i = 0; i < 4; ++i)
#pragma unroll
        for (int j = 0; j < 4; ++j) acc[i][j] = (f32x4){0.f, 0.f, 0.f, 0.f};

    const int srow  = t >> 1;          // 0..127
    const int shalf = (t & 1) * 16;    // element offset within 32-wide K chunk
    const size_t xoff = (size_t)(bm + srow) * 1024 + shalf;
    const size_t woff = (size_t)(bn + srow) * 1024 + shalf;

    for (int e0 = 0; e0 < 1024; e0 += 32) {
        __syncthreads();
        {
            short8 a0 = *(const short8*)&Xh[xoff + e0];
            short8 a1 = *(const short8*)&Xh[xoff + e0 + 8];
            short8 b0 = *(const short8*)&Wh[woff + e0];
            short8 b1 = *(const short8*)&Wh[woff + e0 + 8];
            *(short8*)&Ah[srow * 32 + shalf]     = a0;
            *(short8*)&Ah[srow * 32 + shalf + 8] = a1;
            *(short8*)&Bh[srow * 32 + shalf]     = b0;
            *(short8*)&Bh[srow * 32 + shalf + 8] = b1;
            if constexpr (SPLIT) {
                short8 c0 = *(const short8*)&Xl[xoff + e0];
                short8 c1 = *(const short8*)&Xl[xoff + e0 + 8];
                short8 d0 = *(const short8*)&Wl[woff + e0];
                short8 d1 = *(const short8*)&Wl[woff + e0 + 8];
                *(short8*)&Al[srow * 32 + shalf]     = c0;
                *(short8*)&Al[srow * 32 + shalf + 8] = c1;
                *(short8*)&Bl[srow * 32 + shalf]     = d0;
                *(short8*)&Bl[srow * 32 + shalf + 8] = d1;
            }
        }
        __syncthreads();

        short8 af[4], bfv[4], afl[4], bfl[4];
#pragma unroll
        for (int rb = 0; rb < 4; ++rb) {
            af[rb] = *(const short8*)&Ah[(wr + rb * 16 + (l & 15)) * 32 + (l >> 4) * 8];
            bfv[rb] = *(const short8*)&Bh[(wc + rb * 16 + (l & 15)) * 32 + (l >> 4) * 8];
            if constexpr (SPLIT) {
                afl[rb] = *(const short8*)&Al[(wr + rb * 16 + (l & 15)) * 32 + (l >> 4) * 8];
                bfl[rb] = *(const short8*)&Bl[(wc + rb * 16 + (l & 15)) * 32 + (l >> 4) * 8];
            }
        }
#pragma unroll
        for (int rb = 0; rb < 4; ++rb)
#pragma unroll
            for (int cb = 0; cb < 4; ++cb) {
                acc[rb][cb] = MFMA16(af[rb], bfv[cb], acc[rb][cb]);
                if constexpr (SPLIT) {
                    acc[rb][cb] = MFMA16(afl[rb], bfv[cb], acc[rb][cb]);
                    acc[rb][cb] = MFMA16(af[rb], bfl[cb], acc[rb][cb]);
                }
            }
    }

    const int r0 = (l >> 4) * 4;
    const int cc = l & 15;
#pragma unroll
    for (int rb = 0; rb < 4; ++rb)
#pragma unroll
        for (int cb = 0; cb < 4; ++cb) {
            const int col = bn + wc + cb * 16 + cc;
            const float bv = bias[col];
#pragma unroll
            for (int r = 0; r < 4; ++r) {
                const int row = bm + wr + rb * 16 + r0 + r;
                const float v = (acc[rb][cb][r] + bv) * oscale;
                if constexpr (OUTMODE == 0) {
                    const unsigned short hi = f2bf(v);
                    Yhi[(size_t)row * 1024 + col] = hi;
                    Ylo[(size_t)row * 1024 + col] = f2bf(v - bf2f(hi));
                } else if constexpr (OUTMODE == 1) {
                    Yhi[(size_t)row * 1024 + col] = f2bf(v);
                } else {
                    Yf[(size_t)row * 1024 + col] = v;
                }
            }
        }
}

// ---------------------------------------------------------------------------
// Kernel 4: 64x64 bf16 transpose: V [4096][1024] -> VT [1024][4096].
// (Round-2 fix: read phase now covers all 64 output rows; previous version
//  only wrote half of each tile -> absmax 818.)
// ---------------------------------------------------------------------------
__global__ __launch_bounds__(256) void transpose_kernel(
    const unsigned short* __restrict__ V, unsigned short* __restrict__ VT)
{
    __shared__ unsigned short tile[64][65];
    const int t = threadIdx.x;
    const int c0 = blockIdx.x * 64;
    const int r0 = blockIdx.y * 64;
    {
        const int r = t >> 2;
        const int q = (t & 3) * 16;
        short8 v0 = *(const short8*)&V[(size_t)(r0 + r) * 1024 + c0 + q];
        short8 v1 = *(const short8*)&V[(size_t)(r0 + r) * 1024 + c0 + q + 8];
#pragma unroll
        for (int i = 0; i < 8; ++i) {
            tile[r][q + i]     = (unsigned short)v0[i];
            tile[r][q + 8 + i] = (unsigned short)v1[i];
        }
    }
    __syncthreads();
    {
        const int c = t >> 2;          // 0..63  (VT row within tile)
        const int g = (t & 3) * 16;    // 0,16,32,48
        short8 out0, out1;
#pragma unroll
        for (int i = 0; i < 8; ++i) {
            out0[i] = (short)tile[g + i][c];
            out1[i] = (short)tile[g + 8 + i][c];
        }
        *(short8*)&VT[(size_t)(c0 + c) * 4096 + r0 + g]     = out0;
        *(short8*)&VT[(size_t)(c0 + c) * 4096 + r0 + g + 8] = out1;
    }
}

// ---------------------------------------------------------------------------
// Kernel 5: MFMA flash attention.
// Q split hi/lo (3-pass QK^T vs K hi/lo), PV plain bf16. 64 q-rows/block
// (4 waves x 16), 64-key tiles. XOR-swizzled LDS (16B units, ^((row&7)<<4)).
// grid = (32, 16, 2).
// ---------------------------------------------------------------------------
__global__ __launch_bounds__(256) void attn_kernel(
    const unsigned short* __restrict__ Qh, const unsigned short* __restrict__ Ql,
    const unsigned short* __restrict__ Kh_g, const unsigned short* __restrict__ Kl_g,
    const unsigned short* __restrict__ VT, unsigned short* __restrict__ CTX)
{
    __shared__ unsigned short Khs[64 * 64];
    __shared__ unsigned short Kls[64 * 64];
    __shared__ unsigned short Vts[64 * 64];   // [d][k]
    __shared__ unsigned short Ps [64 * 64];   // [q][k]

    const int t = threadIdx.x;
    const int l = t & 63;
    const int w = t >> 6;
    const int qt = blockIdx.x, h = blockIdx.y, b = blockIdx.z;
    const int tokq = b * LQ + qt * 64;

    // Q fragments in registers (A-operand: row = l&15, k = (l>>4)*8 + i)
    short8 qhi[2], qlo[2];
    {
        const size_t qr = (size_t)(tokq + w * 16 + (l & 15)) * 1024 + h * 64 + (l >> 4) * 8;
        qhi[0] = *(const short8*)&Qh[qr];
        qhi[1] = *(const short8*)&Qh[qr + 32];
        qlo[0] = *(const short8*)&Ql[qr];
        qlo[1] = *(const short8*)&Ql[qr + 32];
    }

    f32x4 o[4];
#pragma unroll
    for (int f = 0; f < 4; ++f) o[f] = (f32x4){0.f, 0.f, 0.f, 0.f};
    float m[4], lsum[4];
#pragma unroll
    for (int r = 0; r < 4; ++r) { m[r] = -1e30f; lsum[r] = 0.f; }

    const int sk = t >> 3;   // 0..31
    const int sc = t & 7;    // 16B chunk within 128B row

    for (int kt = 0; kt < 32; ++kt) {
        __syncthreads();
        const int tokk = b * LQ + kt * 64;
#pragma unroll
        for (int it = 0; it < 2; ++it) {
            const int k = it * 32 + sk;
            const size_t gsrc = (size_t)(tokk + k) * 1024 + h * 64 + sc * 8;
            const int dst = k * 64 + ((sc ^ (k & 7)) << 3);
            *(short8*)&Khs[dst] = *(const short8*)&Kh_g[gsrc];
            *(short8*)&Kls[dst] = *(const short8*)&Kl_g[gsrc];
            // V^T rows: d = k
            *(short8*)&Vts[dst] = *(const short8*)&VT[(size_t)(h * 64 + k) * 4096 + tokk + sc * 8];
        }
        __syncthreads();

        // ---- QK^T (3-pass split) ----
        f32x4 s[4];
#pragma unroll
        for (int f = 0; f < 4; ++f) {
            s[f] = (f32x4){0.f, 0.f, 0.f, 0.f};
#pragma unroll
            for (int ks = 0; ks < 2; ++ks) {
                const int kk = f * 16 + (l & 15);
                const int ch = ks * 4 + (l >> 4);
                const int off = kk * 64 + ((ch ^ (kk & 7)) << 3);
                short8 kh = *(const short8*)&Khs[off];
                short8 kl = *(const short8*)&Kls[off];
                s[f] = MFMA16(qhi[ks], kh, s[f]);
                s[f] = MFMA16(qlo[ks], kh, s[f]);
                s[f] = MFMA16(qhi[ks], kl, s[f]);
            }
        }

        // ---- online softmax (C-layout: row q = w*16+(l>>4)*4+r, col k = f*16+(l&15)) ----
        float alpha[4];
#pragma unroll
        for (int r = 0; r < 4; ++r) {
            float vm = fmaxf(fmaxf(s[0][r], s[1][r]), fmaxf(s[2][r], s[3][r]));
            vm = fmaxf(vm, __shfl_xor(vm, 1));
            vm = fmaxf(vm, __shfl_xor(vm, 2));
            vm = fmaxf(vm, __shfl_xor(vm, 4));
            vm = fmaxf(vm, __shfl_xor(vm, 8));
            const float mn = fmaxf(m[r], vm);
            alpha[r] = __expf(m[r] - mn);
            m[r] = mn;
        }
        float rs[4] = {0.f, 0.f, 0.f, 0.f};
#pragma unroll
        for (int f = 0; f < 4; ++f)
#pragma unroll
            for (int r = 0; r < 4; ++r) {
                const float p = __expf(s[f][r] - m[r]);
                s[f][r] = p;
                rs[r] += p;
            }
#pragma unroll
        for (int r = 0; r < 4; ++r) {
            rs[r] += __shfl_xor(rs[r], 1);
            rs[r] += __shfl_xor(rs[r], 2);
            rs[r] += __shfl_xor(rs[r], 4);
            rs[r] += __shfl_xor(rs[r], 8);
            lsum[r] = lsum[r] * alpha[r] + rs[r];
        }
#pragma unroll
        for (int f = 0; f < 4; ++f)
#pragma unroll
            for (int r = 0; r < 4; ++r) o[f][r] *= alpha[r];

        // ---- P -> LDS (bf16), swizzled ----
#pragma unroll
        for (int f = 0; f < 4; ++f)
#pragma unroll
            for (int r = 0; r < 4; ++r) {
                const int q  = w * 16 + (l >> 4) * 4 + r;
                const int kk = f * 16 + (l & 15);
                Ps[q * 64 + (((kk >> 3) ^ (q & 7)) << 3) + (kk & 7)] = f2bf(s[f][r]);
            }
        __syncthreads();

        // ---- PV ----
#pragma unroll
        for (int ks = 0; ks < 2; ++ks) {
            const int qq = w * 16 + (l & 15);
            const int ch = ks * 4 + (l >> 4);
            short8 pa = *(const short8*)&Ps[qq * 64 + ((ch ^ (qq & 7)) << 3)];
#pragma unroll
            for (int f = 0; f < 4; ++f) {
                const int dd = f * 16 + (l & 15);
                short8 vb = *(const short8*)&Vts[dd * 64 + ((ch ^ (dd & 7)) << 3)];
                o[f] = MFMA16(pa, vb, o[f]);
            }
        }
    }

    // ---- finalize ----
#pragma unroll
    for (int r = 0; r < 4; ++r) {
        const float inv = 1.f / lsum[r];
        const size_t row = (size_t)(tokq + w * 16 + (l >> 4) * 4 + r) * 1024 + h * 64;
#pragma unroll
        for (int f = 0; f < 4; ++f)
            CTX[row + f * 16 + (l & 15)] = f2bf(o[f][r] * inv);
    }
}

// ---------------------------------------------------------------------------
extern "C" void kernel_launch(void* const* d_in, const int* in_sizes, int n_in,
                              void* d_out, int out_size, void* d_ws, size_t ws_size,
                              hipStream_t stream)
{
    (void)in_sizes; (void)n_in; (void)out_size; (void)ws_size;
    const float* query = (const float*)d_in[0];
    char* base = (char*)d_ws;
    const size_t MB = 1 << 20;
    unsigned short* Whi = (unsigned short*)(base + 0 * MB);    // 4 x 1M x 2B = 8MB
    unsigned short* Wlo = (unsigned short*)(base + 8 * MB);
    unsigned short* Xhi = (unsigned short*)(base + 16 * MB);   // 8MB
    unsigned short* Xlo = (unsigned short*)(base + 24 * MB);
    unsigned short* Qhi = (unsigned short*)(base + 32 * MB);
    unsigned short* Qlo = (unsigned short*)(base + 40 * MB);
    unsigned short* Khi = (unsigned short*)(base + 48 * MB);
    unsigned short* Klo = (unsigned short*)(base + 56 * MB);
    unsigned short* Vh  = (unsigned short*)(base + 64 * MB);
    unsigned short* VTp = (unsigned short*)(base + 72 * MB);
    unsigned short* CTX = (unsigned short*)(base + 16 * MB);   // reuse X region

    CorePtrs cp;
    for (int p = 0; p < 4; ++p) {
        cp.c0[p] = (const float*)d_in[1 + 4 * p];
        cp.c1[p] = (const float*)d_in[2 + 4 * p];
        cp.c2[p] = (const float*)d_in[3 + 4 * p];
    }
    const size_t WSZ = (size_t)1024 * 1024;

    build_w_kernel<<<dim3(64, 4), 256, 0, stream>>>(cp, Whi, Wlo);
    convert_x_kernel<<<4096, 256, 0, stream>>>(query, Xhi, Xlo, 1048576);

    // Q (scale 1/8 folded, split out), K (split out), V (bf16 out)
    gemm_kernel<true, 0><<<dim3(8, 32), 256, 0, stream>>>(
        Xhi, Xlo, Whi + 0 * WSZ, Wlo + 0 * WSZ, (const float*)d_in[4], 0.125f,
        Qhi, Qlo, nullptr);
    gemm_kernel<true, 0><<<dim3(8, 32), 256, 0, stream>>>(
        Xhi, Xlo, Whi + 1 * WSZ, Wlo + 1 * WSZ, (const float*)d_in[8], 1.0f,
        Khi, Klo, nullptr);
    gemm_kernel<false, 1><<<dim3(8, 32), 256, 0, stream>>>(
        Xhi, nullptr, Whi + 2 * WSZ, nullptr, (const float*)d_in[12], 1.0f,
        Vh, nullptr, nullptr);

    transpose_kernel<<<dim3(16, 64), 256, 0, stream>>>(Vh, VTp);

    attn_kernel<<<dim3(32, 16, 2), 256, 0, stream>>>(Qhi, Qlo, Khi, Klo, VTp, CTX);

    gemm_kernel<false, 2><<<dim3(8, 32), 256, 0, stream>>>(
        CTX, nullptr, Whi + 3 * WSZ, nullptr, (const float*)d_in[16], 1.0f,
        nullptr, nullptr, (float*)d_out);
}

// Round 4
// 387.278 us; speedup vs baseline: 3.0655x; 1.0763x over previous
//
#include <hip/hip_runtime.h>
#include <hip/hip_bf16.h>
#include <stdint.h>

#define LQ 2048
#define NTOK 4096

typedef __attribute__((ext_vector_type(8))) short short8;
typedef __attribute__((ext_vector_type(4))) float f32x4;
typedef __attribute__((ext_vector_type(4))) unsigned short u16x4;

#define MFMA16(a, b, c) __builtin_amdgcn_mfma_f32_16x16x32_bf16((a), (b), (c), 0, 0, 0)

__device__ __forceinline__ unsigned short f2bf(float x) {
    union { __hip_bfloat16 b; unsigned short u; } v;
    v.b = __float2bfloat16(x);
    return v.u;
}
__device__ __forceinline__ float bf2f(unsigned short h) {
    union { uint32_t u; float f; } v; v.u = ((uint32_t)h) << 16; return v.f;
}

struct CorePtrs {
    const float* c0[4];
    const float* c1[4];
    const float* c2[4];
};

// ---------------------------------------------------------------------------
// Kernel 1: materialize W (bf16 hi + lo residual) for all 4 projections.
// ---------------------------------------------------------------------------
__global__ __launch_bounds__(256) void build_w_kernel(
    CorePtrs cp, unsigned short* __restrict__ Whi, unsigned short* __restrict__ Wlo)
{
    __shared__ float B1[16 * 16 * 16];   // [i1][q1][s2]
    const int p  = blockIdx.y;
    const int i0 = blockIdx.x >> 3;
    const int q0 = blockIdx.x & 7;
    const int t  = threadIdx.x;
    const float* __restrict__ c0 = cp.c0[p];
    const float* __restrict__ c1 = cp.c1[p];
    const float* __restrict__ c2 = cp.c2[p];

    float g0[16];
#pragma unroll
    for (int s = 0; s < 16; ++s) g0[s] = c0[(i0 * 8 + q0) * 16 + s];

    for (int idx = t; idx < 4096; idx += 256) {
        const int s2 = idx & 15;
        const int q1 = (idx >> 4) & 15;
        const int i1 = idx >> 8;
        float acc = 0.f;
#pragma unroll
        for (int s = 0; s < 16; ++s)
            acc += g0[s] * c1[((s * 16 + i1) * 16 + q1) * 16 + s2];
        B1[idx] = acc;
    }
    __syncthreads();

    const size_t base = (size_t)p * 1024 * 1024;
    for (int idx = t; idx < 16384; idx += 256) {
        const int q2 = idx & 7;
        const int i2 = (idx >> 3) & 7;
        const int q1 = (idx >> 6) & 15;
        const int i1 = idx >> 10;
        float acc = 0.f;
#pragma unroll
        for (int s2 = 0; s2 < 16; ++s2)
            acc += B1[(i1 * 16 + q1) * 16 + s2] * c2[(s2 * 8 + i2) * 8 + q2];
        const int o = q0 * 128 + q1 * 8 + q2;
        const int e = i0 * 128 + i1 * 8 + i2;
        const unsigned short hi = f2bf(acc);
        Whi[base + o * 1024 + e] = hi;
        Wlo[base + o * 1024 + e] = f2bf(acc - bf2f(hi));
    }
}

// ---------------------------------------------------------------------------
// Kernel 2: fp32 -> bf16 hi/lo split of the input activations.
// ---------------------------------------------------------------------------
__global__ __launch_bounds__(256) void convert_x_kernel(
    const float* __restrict__ X, unsigned short* __restrict__ Xhi,
    unsigned short* __restrict__ Xlo, int n4)
{
    const int i = blockIdx.x * 256 + threadIdx.x;
    if (i >= n4) return;
    const float4 v = ((const float4*)X)[i];
    u16x4 hi, lo;
    float vv[4] = {v.x, v.y, v.z, v.w};
#pragma unroll
    for (int j = 0; j < 4; ++j) {
        unsigned short h = f2bf(vv[j]);
        hi[j] = h;
        lo[j] = f2bf(vv[j] - bf2f(h));
    }
    ((u16x4*)Xhi)[i] = hi;
    ((u16x4*)Xlo)[i] = lo;
}

// ---------------------------------------------------------------------------
// Kernel 3: MFMA NT-GEMM, 128x128 tile, 4 waves, BK=32.
// R4 changes: 16B-chunk XOR swizzle (pos = chunk ^ ((row>>1)&3)) kills the
// 8-way read conflicts of the 64B-row layout; register prefetch of the next
// K-chunk overlaps global latency with MFMA compute.
// ---------------------------------------------------------------------------
template <bool SPLIT, int OUTMODE>
__global__ __launch_bounds__(256) void gemm_kernel(
    const unsigned short* __restrict__ Xh, const unsigned short* __restrict__ Xl,
    const unsigned short* __restrict__ Wh, const unsigned short* __restrict__ Wl,
    const float* __restrict__ bias, float oscale,
    unsigned short* __restrict__ Yhi, unsigned short* __restrict__ Ylo,
    float* __restrict__ Yf)
{
    __shared__ unsigned short Ah[128 * 32];
    __shared__ unsigned short Bh[128 * 32];
    __shared__ unsigned short Al[SPLIT ? 128 * 32 : 8];
    __shared__ unsigned short Bl[SPLIT ? 128 * 32 : 8];

    const int t = threadIdx.x;
    const int l = t & 63;
    const int w = t >> 6;
    const int wr = (w >> 1) * 64, wc = (w & 1) * 64;
    const int bm = blockIdx.y * 128, bn = blockIdx.x * 128;

    f32x4 acc[4][4];
#pragma unroll
    for (int i = 0; i < 4; ++i)
#pragma unroll
        for (int j = 0; j < 4; ++j) acc[i][j] = (f32x4){0.f, 0.f, 0.f, 0.f};

    // staging: thread covers row srow, chunks sch, sch+1 (16B units)
    const int srow = t >> 1;
    const int sch  = (t & 1) * 2;
    const int ssel = (srow >> 1) & 3;
    const int sd0  = srow * 32 + (((sch)     ^ ssel) << 3);
    const int sd1  = srow * 32 + (((sch + 1) ^ ssel) << 3);
    const size_t xoff = (size_t)(bm + srow) * 1024 + sch * 8;
    const size_t woff = (size_t)(bn + srow) * 1024 + sch * 8;

    // fragment read addressing: row = base + rb*16 + (l&15); chunk = l>>4.
    // ((row>>1)&3) == (((l&15)>>1)&3) since wr, rb*16 are multiples of 16.
    const int fsel = ((l & 15) >> 1) & 3;
    const int fpos = ((l >> 4) ^ fsel) << 3;
    const int fra  = (wr + (l & 15)) * 32 + fpos;
    const int frb  = (wc + (l & 15)) * 32 + fpos;

    short8 pXh0, pXh1, pWh0, pWh1, pXl0, pXl1, pWl0, pWl1;
    // prologue: prefetch K-chunk 0
    pXh0 = *(const short8*)&Xh[xoff];     pXh1 = *(const short8*)&Xh[xoff + 8];
    pWh0 = *(const short8*)&Wh[woff];     pWh1 = *(const short8*)&Wh[woff + 8];
    if constexpr (SPLIT) {
        pXl0 = *(const short8*)&Xl[xoff]; pXl1 = *(const short8*)&Xl[xoff + 8];
        pWl0 = *(const short8*)&Wl[woff]; pWl1 = *(const short8*)&Wl[woff + 8];
    }

    for (int e0 = 0; e0 < 1024; e0 += 32) {
        __syncthreads();
        *(short8*)&Ah[sd0] = pXh0; *(short8*)&Ah[sd1] = pXh1;
        *(short8*)&Bh[sd0] = pWh0; *(short8*)&Bh[sd1] = pWh1;
        if constexpr (SPLIT) {
            *(short8*)&Al[sd0] = pXl0; *(short8*)&Al[sd1] = pXl1;
            *(short8*)&Bl[sd0] = pWl0; *(short8*)&Bl[sd1] = pWl1;
        }
        __syncthreads();

        if (e0 + 32 < 1024) {
            const size_t xo = xoff + e0 + 32, wo = woff + e0 + 32;
            pXh0 = *(const short8*)&Xh[xo];     pXh1 = *(const short8*)&Xh[xo + 8];
            pWh0 = *(const short8*)&Wh[wo];     pWh1 = *(const short8*)&Wh[wo + 8];
            if constexpr (SPLIT) {
                pXl0 = *(const short8*)&Xl[xo]; pXl1 = *(const short8*)&Xl[xo + 8];
                pWl0 = *(const short8*)&Wl[wo]; pWl1 = *(const short8*)&Wl[wo + 8];
            }
        }

        short8 af[4], bfv[4], afl[4], bfl[4];
#pragma unroll
        for (int rb = 0; rb < 4; ++rb) {
            af[rb]  = *(const short8*)&Ah[fra + rb * 512];
            bfv[rb] = *(const short8*)&Bh[frb + rb * 512];
        }
#pragma unroll
        for (int rb = 0; rb < 4; ++rb)
#pragma unroll
            for (int cb = 0; cb < 4; ++cb)
                acc[rb][cb] = MFMA16(af[rb], bfv[cb], acc[rb][cb]);
        if constexpr (SPLIT) {
#pragma unroll
            for (int rb = 0; rb < 4; ++rb) afl[rb] = *(const short8*)&Al[fra + rb * 512];
#pragma unroll
            for (int rb = 0; rb < 4; ++rb)
#pragma unroll
                for (int cb = 0; cb < 4; ++cb)
                    acc[rb][cb] = MFMA16(afl[rb], bfv[cb], acc[rb][cb]);
#pragma unroll
            for (int rb = 0; rb < 4; ++rb) bfl[rb] = *(const short8*)&Bl[frb + rb * 512];
#pragma unroll
            for (int rb = 0; rb < 4; ++rb)
#pragma unroll
                for (int cb = 0; cb < 4; ++cb)
                    acc[rb][cb] = MFMA16(af[rb], bfl[cb], acc[rb][cb]);
        }
    }

    const int r0 = (l >> 4) * 4;
    const int cc = l & 15;
#pragma unroll
    for (int rb = 0; rb < 4; ++rb)
#pragma unroll
        for (int cb = 0; cb < 4; ++cb) {
            const int col = bn + wc + cb * 16 + cc;
            const float bv = bias[col];
#pragma unroll
            for (int r = 0; r < 4; ++r) {
                const int row = bm + wr + rb * 16 + r0 + r;
                const float v = (acc[rb][cb][r] + bv) * oscale;
                if constexpr (OUTMODE == 0) {
                    const unsigned short hi = f2bf(v);
                    Yhi[(size_t)row * 1024 + col] = hi;
                    Ylo[(size_t)row * 1024 + col] = f2bf(v - bf2f(hi));
                } else if constexpr (OUTMODE == 1) {
                    Yhi[(size_t)row * 1024 + col] = f2bf(v);
                } else {
                    Yf[(size_t)row * 1024 + col] = v;
                }
            }
        }
}

// ---------------------------------------------------------------------------
// Kernel 4: 64x64 bf16 transpose: V [4096][1024] -> VT [1024][4096].
// ---------------------------------------------------------------------------
__global__ __launch_bounds__(256) void transpose_kernel(
    const unsigned short* __restrict__ V, unsigned short* __restrict__ VT)
{
    __shared__ unsigned short tile[64][65];
    const int t = threadIdx.x;
    const int c0 = blockIdx.x * 64;
    const int r0 = blockIdx.y * 64;
    {
        const int r = t >> 2;
        const int q = (t & 3) * 16;
        short8 v0 = *(const short8*)&V[(size_t)(r0 + r) * 1024 + c0 + q];
        short8 v1 = *(const short8*)&V[(size_t)(r0 + r) * 1024 + c0 + q + 8];
#pragma unroll
        for (int i = 0; i < 8; ++i) {
            tile[r][q + i]     = (unsigned short)v0[i];
            tile[r][q + 8 + i] = (unsigned short)v1[i];
        }
    }
    __syncthreads();
    {
        const int c = t >> 2;          // 0..63
        const int g = (t & 3) * 16;    // 0,16,32,48
        short8 out0, out1;
#pragma unroll
        for (int i = 0; i < 8; ++i) {
            out0[i] = (short)tile[g + i][c];
            out1[i] = (short)tile[g + 8 + i][c];
        }
        *(short8*)&VT[(size_t)(c0 + c) * 4096 + r0 + g]     = out0;
        *(short8*)&VT[(size_t)(c0 + c) * 4096 + r0 + g + 8] = out1;
    }
}

// ---------------------------------------------------------------------------
// Kernel 5: MFMA flash attention. Scores are in LOG2 units (log2e folded
// into Q's projection scale) -> exp2f softmax. T13 defer-max (THR=8).
// T14 register prefetch of next K/V tile. XOR-swizzled LDS.
// ---------------------------------------------------------------------------
__global__ __launch_bounds__(256) void attn_kernel(
    const unsigned short* __restrict__ Qh, const unsigned short* __restrict__ Ql,
    const unsigned short* __restrict__ Kh_g, const unsigned short* __restrict__ Kl_g,
    const unsigned short* __restrict__ VT, unsigned short* __restrict__ CTX)
{
    __shared__ unsigned short Khs[64 * 64];
    __shared__ unsigned short Kls[64 * 64];
    __shared__ unsigned short Vts[64 * 64];   // [d][k]
    __shared__ unsigned short Ps [64 * 64];   // [q][k]

    const int t = threadIdx.x;
    const int l = t & 63;
    const int w = t >> 6;
    const int qt = blockIdx.x, h = blockIdx.y, b = blockIdx.z;
    const int tokq = b * LQ + qt * 64;

    short8 qhi[2], qlo[2];
    {
        const size_t qr = (size_t)(tokq + w * 16 + (l & 15)) * 1024 + h * 64 + (l >> 4) * 8;
        qhi[0] = *(const short8*)&Qh[qr];
        qhi[1] = *(const short8*)&Qh[qr + 32];
        qlo[0] = *(const short8*)&Ql[qr];
        qlo[1] = *(const short8*)&Ql[qr + 32];
    }

    f32x4 o[4];
#pragma unroll
    for (int f = 0; f < 4; ++f) o[f] = (f32x4){0.f, 0.f, 0.f, 0.f};
    float m[4], lsum[4];
#pragma unroll
    for (int r = 0; r < 4; ++r) { m[r] = -1e30f; lsum[r] = 0.f; }

    const int sk = t >> 3;   // 0..31
    const int sc = t & 7;    // 16B chunk within 128B row
    int dst[2];
#pragma unroll
    for (int it = 0; it < 2; ++it) {
        const int k = it * 32 + sk;
        dst[it] = k * 64 + ((sc ^ (k & 7)) << 3);
    }

    // prefetch tile 0
    short8 pf_kh[2], pf_kl[2], pf_vt[2];
#pragma unroll
    for (int it = 0; it < 2; ++it) {
        const int k = it * 32 + sk;
        const size_t gsrc = (size_t)(b * LQ + k) * 1024 + h * 64 + sc * 8;
        pf_kh[it] = *(const short8*)&Kh_g[gsrc];
        pf_kl[it] = *(const short8*)&Kl_g[gsrc];
        pf_vt[it] = *(const short8*)&VT[(size_t)(h * 64 + k) * 4096 + b * LQ + sc * 8];
    }

    for (int kt = 0; kt < 32; ++kt) {
        __syncthreads();   // prior tile's LDS reads (and Ps reads) complete
#pragma unroll
        for (int it = 0; it < 2; ++it) {
            *(short8*)&Khs[dst[it]] = pf_kh[it];
            *(short8*)&Kls[dst[it]] = pf_kl[it];
            *(short8*)&Vts[dst[it]] = pf_vt[it];
        }
        __syncthreads();

        if (kt < 31) {
            const int tokn = b * LQ + (kt + 1) * 64;
#pragma unroll
            for (int it = 0; it < 2; ++it) {
                const int k = it * 32 + sk;
                const size_t gsrc = (size_t)(tokn + k) * 1024 + h * 64 + sc * 8;
                pf_kh[it] = *(const short8*)&Kh_g[gsrc];
                pf_kl[it] = *(const short8*)&Kl_g[gsrc];
                pf_vt[it] = *(const short8*)&VT[(size_t)(h * 64 + k) * 4096 + tokn + sc * 8];
            }
        }

        // ---- QK^T (3-pass split), scores in log2 units ----
        f32x4 s[4];
#pragma unroll
        for (int f = 0; f < 4; ++f) {
            s[f] = (f32x4){0.f, 0.f, 0.f, 0.f};
#pragma unroll
            for (int ks = 0; ks < 2; ++ks) {
                const int kk = f * 16 + (l & 15);
                const int ch = ks * 4 + (l >> 4);
                const int off = kk * 64 + ((ch ^ (kk & 7)) << 3);
                short8 kh = *(const short8*)&Khs[off];
                short8 kl = *(const short8*)&Kls[off];
                s[f] = MFMA16(qhi[ks], kh, s[f]);
                s[f] = MFMA16(qlo[ks], kh, s[f]);
                s[f] = MFMA16(qhi[ks], kl, s[f]);
            }
        }

        // ---- online softmax (base 2), defer-max THR=8 ----
        float pm[4];
#pragma unroll
        for (int r = 0; r < 4; ++r) {
            float vm = fmaxf(fmaxf(s[0][r], s[1][r]), fmaxf(s[2][r], s[3][r]));
            vm = fmaxf(vm, __shfl_xor(vm, 1));
            vm = fmaxf(vm, __shfl_xor(vm, 2));
            vm = fmaxf(vm, __shfl_xor(vm, 4));
            vm = fmaxf(vm, __shfl_xor(vm, 8));
            pm[r] = vm;
        }
        int skip = 1;
#pragma unroll
        for (int r = 0; r < 4; ++r) skip &= (pm[r] <= m[r] + 8.f) ? 1 : 0;
        if (!__all(skip)) {
#pragma unroll
            for (int r = 0; r < 4; ++r) {
                const float mn = fmaxf(m[r], pm[r]);
                const float alpha = exp2f(m[r] - mn);
                m[r] = mn;
                lsum[r] *= alpha;
#pragma unroll
                for (int f = 0; f < 4; ++f) o[f][r] *= alpha;
            }
        }
        float rs[4] = {0.f, 0.f, 0.f, 0.f};
#pragma unroll
        for (int f = 0; f < 4; ++f)
#pragma unroll
            for (int r = 0; r < 4; ++r) {
                const float p = exp2f(s[f][r] - m[r]);
                s[f][r] = p;
                rs[r] += p;
            }
#pragma unroll
        for (int r = 0; r < 4; ++r) {
            rs[r] += __shfl_xor(rs[r], 1);
            rs[r] += __shfl_xor(rs[r], 2);
            rs[r] += __shfl_xor(rs[r], 4);
            rs[r] += __shfl_xor(rs[r], 8);
            lsum[r] += rs[r];
        }

        // ---- P -> LDS (bf16), swizzled ----
#pragma unroll
        for (int f = 0; f < 4; ++f)
#pragma unroll
            for (int r = 0; r < 4; ++r) {
                const int q  = w * 16 + (l >> 4) * 4 + r;
                const int kk = f * 16 + (l & 15);
                Ps[q * 64 + (((kk >> 3) ^ (q & 7)) << 3) + (kk & 7)] = f2bf(s[f][r]);
            }
        __syncthreads();

        // ---- PV ----
#pragma unroll
        for (int ks = 0; ks < 2; ++ks) {
            const int qq = w * 16 + (l & 15);
            const int ch = ks * 4 + (l >> 4);
            short8 pa = *(const short8*)&Ps[qq * 64 + ((ch ^ (qq & 7)) << 3)];
#pragma unroll
            for (int f = 0; f < 4; ++f) {
                const int dd = f * 16 + (l & 15);
                short8 vb = *(const short8*)&Vts[dd * 64 + ((ch ^ (dd & 7)) << 3)];
                o[f] = MFMA16(pa, vb, o[f]);
            }
        }
    }

    // ---- finalize ----
#pragma unroll
    for (int r = 0; r < 4; ++r) {
        const float inv = 1.f / lsum[r];
        const size_t row = (size_t)(tokq + w * 16 + (l >> 4) * 4 + r) * 1024 + h * 64;
#pragma unroll
        for (int f = 0; f < 4; ++f)
            CTX[row + f * 16 + (l & 15)] = f2bf(o[f][r] * inv);
    }
}

// ---------------------------------------------------------------------------
extern "C" void kernel_launch(void* const* d_in, const int* in_sizes, int n_in,
                              void* d_out, int out_size, void* d_ws, size_t ws_size,
                              hipStream_t stream)
{
    (void)in_sizes; (void)n_in; (void)out_size; (void)ws_size;
    const float* query = (const float*)d_in[0];
    char* base = (char*)d_ws;
    const size_t MB = 1 << 20;
    unsigned short* Whi = (unsigned short*)(base + 0 * MB);
    unsigned short* Wlo = (unsigned short*)(base + 8 * MB);
    unsigned short* Xhi = (unsigned short*)(base + 16 * MB);
    unsigned short* Xlo = (unsigned short*)(base + 24 * MB);
    unsigned short* Qhi = (unsigned short*)(base + 32 * MB);
    unsigned short* Qlo = (unsigned short*)(base + 40 * MB);
    unsigned short* Khi = (unsigned short*)(base + 48 * MB);
    unsigned short* Klo = (unsigned short*)(base + 56 * MB);
    unsigned short* Vh  = (unsigned short*)(base + 64 * MB);
    unsigned short* VTp = (unsigned short*)(base + 72 * MB);
    unsigned short* CTX = (unsigned short*)(base + 16 * MB);   // reuse X region

    CorePtrs cp;
    for (int p = 0; p < 4; ++p) {
        cp.c0[p] = (const float*)d_in[1 + 4 * p];
        cp.c1[p] = (const float*)d_in[2 + 4 * p];
        cp.c2[p] = (const float*)d_in[3 + 4 * p];
    }
    const size_t WSZ = (size_t)1024 * 1024;
    const float QSCALE = 0.125f * 1.44269504088896340736f;   // fold log2(e): softmax in base 2

    build_w_kernel<<<dim3(64, 4), 256, 0, stream>>>(cp, Whi, Wlo);
    convert_x_kernel<<<4096, 256, 0, stream>>>(query, Xhi, Xlo, 1048576);

    gemm_kernel<true, 0><<<dim3(8, 32), 256, 0, stream>>>(
        Xhi, Xlo, Whi + 0 * WSZ, Wlo + 0 * WSZ, (const float*)d_in[4], QSCALE,
        Qhi, Qlo, nullptr);
    gemm_kernel<true, 0><<<dim3(8, 32), 256, 0, stream>>>(
        Xhi, Xlo, Whi + 1 * WSZ, Wlo + 1 * WSZ, (const float*)d_in[8], 1.0f,
        Khi, Klo, nullptr);
    gemm_kernel<false, 1><<<dim3(8, 32), 256, 0, stream>>>(
        Xhi, nullptr, Whi + 2 * WSZ, nullptr, (const float*)d_in[12], 1.0f,
        Vh, nullptr, nullptr);

    transpose_kernel<<<dim3(16, 64), 256, 0, stream>>>(Vh, VTp);

    attn_kernel<<<dim3(32, 16, 2), 256, 0, stream>>>(Qhi, Qlo, Khi, Klo, VTp, CTX);

    gemm_kernel<false, 2><<<dim3(8, 32), 256, 0, stream>>>(
        CTX, nullptr, Whi + 3 * WSZ, nullptr, (const float*)d_in[16], 1.0f,
        nullptr, nullptr, (float*)d_out);
}

// Round 5
// 325.822 us; speedup vs baseline: 3.6437x; 1.1886x over previous
//
#include <hip/hip_runtime.h>
#include <hip/hip_bf16.h>
#include <stdint.h>

#define LQ 2048
#define NTOK 4096

typedef __attribute__((ext_vector_type(8))) short short8;
typedef __attribute__((ext_vector_type(4))) float f32x4;
typedef __attribute__((ext_vector_type(16))) float f32x16;
typedef __attribute__((ext_vector_type(4))) unsigned short u16x4;

#define MFMA16(a, b, c) __builtin_amdgcn_mfma_f32_16x16x32_bf16((a), (b), (c), 0, 0, 0)
#define MFMA32(a, b, c) __builtin_amdgcn_mfma_f32_32x32x16_bf16((a), (b), (c), 0, 0, 0)

__device__ __forceinline__ unsigned short f2bf(float x) {
    union { __hip_bfloat16 b; unsigned short u; } v;
    v.b = __float2bfloat16(x);
    return v.u;
}
__device__ __forceinline__ float bf2f(unsigned short h) {
    union { uint32_t u; float f; } v; v.u = ((uint32_t)h) << 16; return v.f;
}
__device__ __forceinline__ unsigned int cvtpk_bf16(float lo, float hi_) {
    unsigned int r;
    asm("v_cvt_pk_bf16_f32 %0, %1, %2" : "=v"(r) : "v"(lo), "v"(hi_));
    return r;
}
// a' = [a.lanes0-31 | b.lanes0-31], b' = [a.lanes32-63 | b.lanes32-63]
__device__ __forceinline__ void permswap(unsigned int &a, unsigned int &b) {
    asm("v_permlane32_swap_b32 %0, %1" : "+v"(a), "+v"(b));
}

struct CorePtrs {
    const float* c0[4];
    const float* c1[4];
    const float* c2[4];
};

// ---------------------------------------------------------------------------
// Kernel 1: materialize W (bf16 hi + lo residual) for all 4 projections.
// ---------------------------------------------------------------------------
__global__ __launch_bounds__(256) void build_w_kernel(
    CorePtrs cp, unsigned short* __restrict__ Whi, unsigned short* __restrict__ Wlo)
{
    __shared__ float B1[16 * 16 * 16];   // [i1][q1][s2]
    const int p  = blockIdx.y;
    const int i0 = blockIdx.x >> 3;
    const int q0 = blockIdx.x & 7;
    const int t  = threadIdx.x;
    const float* __restrict__ c0 = cp.c0[p];
    const float* __restrict__ c1 = cp.c1[p];
    const float* __restrict__ c2 = cp.c2[p];

    float g0[16];
#pragma unroll
    for (int s = 0; s < 16; ++s) g0[s] = c0[(i0 * 8 + q0) * 16 + s];

    for (int idx = t; idx < 4096; idx += 256) {
        const int s2 = idx & 15;
        const int q1 = (idx >> 4) & 15;
        const int i1 = idx >> 8;
        float acc = 0.f;
#pragma unroll
        for (int s = 0; s < 16; ++s)
            acc += g0[s] * c1[((s * 16 + i1) * 16 + q1) * 16 + s2];
        B1[idx] = acc;
    }
    __syncthreads();

    const size_t base = (size_t)p * 1024 * 1024;
    for (int idx = t; idx < 16384; idx += 256) {
        const int q2 = idx & 7;
        const int i2 = (idx >> 3) & 7;
        const int q1 = (idx >> 6) & 15;
        const int i1 = idx >> 10;
        float acc = 0.f;
#pragma unroll
        for (int s2 = 0; s2 < 16; ++s2)
            acc += B1[(i1 * 16 + q1) * 16 + s2] * c2[(s2 * 8 + i2) * 8 + q2];
        const int o = q0 * 128 + q1 * 8 + q2;
        const int e = i0 * 128 + i1 * 8 + i2;
        const unsigned short hi = f2bf(acc);
        Whi[base + o * 1024 + e] = hi;
        Wlo[base + o * 1024 + e] = f2bf(acc - bf2f(hi));
    }
}

// ---------------------------------------------------------------------------
// Kernel 2: fp32 -> bf16 hi/lo split of the input activations.
// ---------------------------------------------------------------------------
__global__ __launch_bounds__(256) void convert_x_kernel(
    const float* __restrict__ X, unsigned short* __restrict__ Xhi,
    unsigned short* __restrict__ Xlo, int n4)
{
    const int i = blockIdx.x * 256 + threadIdx.x;
    if (i >= n4) return;
    const float4 v = ((const float4*)X)[i];
    u16x4 hi, lo;
    float vv[4] = {v.x, v.y, v.z, v.w};
#pragma unroll
    for (int j = 0; j < 4; ++j) {
        unsigned short h = f2bf(vv[j]);
        hi[j] = h;
        lo[j] = f2bf(vv[j] - bf2f(h));
    }
    ((u16x4*)Xhi)[i] = hi;
    ((u16x4*)Xlo)[i] = lo;
}

// ---------------------------------------------------------------------------
// Kernel 3: MFMA NT-GEMM, 128x128 tile, 4 waves, BK=32, swizzled LDS,
// register prefetch. (unchanged from R4 — measured improvement)
// ---------------------------------------------------------------------------
template <bool SPLIT, int OUTMODE>
__global__ __launch_bounds__(256) void gemm_kernel(
    const unsigned short* __restrict__ Xh, const unsigned short* __restrict__ Xl,
    const unsigned short* __restrict__ Wh, const unsigned short* __restrict__ Wl,
    const float* __restrict__ bias, float oscale,
    unsigned short* __restrict__ Yhi, unsigned short* __restrict__ Ylo,
    float* __restrict__ Yf)
{
    __shared__ unsigned short Ah[128 * 32];
    __shared__ unsigned short Bh[128 * 32];
    __shared__ unsigned short Al[SPLIT ? 128 * 32 : 8];
    __shared__ unsigned short Bl[SPLIT ? 128 * 32 : 8];

    const int t = threadIdx.x;
    const int l = t & 63;
    const int w = t >> 6;
    const int wr = (w >> 1) * 64, wc = (w & 1) * 64;
    const int bm = blockIdx.y * 128, bn = blockIdx.x * 128;

    f32x4 acc[4][4];
#pragma unroll
    for (int i = 0; i < 4; ++i)
#pragma unroll
        for (int j = 0; j < 4; ++j) acc[i][j] = (f32x4){0.f, 0.f, 0.f, 0.f};

    const int srow = t >> 1;
    const int sch  = (t & 1) * 2;
    const int ssel = (srow >> 1) & 3;
    const int sd0  = srow * 32 + (((sch)     ^ ssel) << 3);
    const int sd1  = srow * 32 + (((sch + 1) ^ ssel) << 3);
    const size_t xoff = (size_t)(bm + srow) * 1024 + sch * 8;
    const size_t woff = (size_t)(bn + srow) * 1024 + sch * 8;

    const int fsel = ((l & 15) >> 1) & 3;
    const int fpos = ((l >> 4) ^ fsel) << 3;
    const int fra  = (wr + (l & 15)) * 32 + fpos;
    const int frb  = (wc + (l & 15)) * 32 + fpos;

    short8 pXh0, pXh1, pWh0, pWh1, pXl0, pXl1, pWl0, pWl1;
    pXh0 = *(const short8*)&Xh[xoff];     pXh1 = *(const short8*)&Xh[xoff + 8];
    pWh0 = *(const short8*)&Wh[woff];     pWh1 = *(const short8*)&Wh[woff + 8];
    if constexpr (SPLIT) {
        pXl0 = *(const short8*)&Xl[xoff]; pXl1 = *(const short8*)&Xl[xoff + 8];
        pWl0 = *(const short8*)&Wl[woff]; pWl1 = *(const short8*)&Wl[woff + 8];
    }

    for (int e0 = 0; e0 < 1024; e0 += 32) {
        __syncthreads();
        *(short8*)&Ah[sd0] = pXh0; *(short8*)&Ah[sd1] = pXh1;
        *(short8*)&Bh[sd0] = pWh0; *(short8*)&Bh[sd1] = pWh1;
        if constexpr (SPLIT) {
            *(short8*)&Al[sd0] = pXl0; *(short8*)&Al[sd1] = pXl1;
            *(short8*)&Bl[sd0] = pWl0; *(short8*)&Bl[sd1] = pWl1;
        }
        __syncthreads();

        if (e0 + 32 < 1024) {
            const size_t xo = xoff + e0 + 32, wo = woff + e0 + 32;
            pXh0 = *(const short8*)&Xh[xo];     pXh1 = *(const short8*)&Xh[xo + 8];
            pWh0 = *(const short8*)&Wh[wo];     pWh1 = *(const short8*)&Wh[wo + 8];
            if constexpr (SPLIT) {
                pXl0 = *(const short8*)&Xl[xo]; pXl1 = *(const short8*)&Xl[xo + 8];
                pWl0 = *(const short8*)&Wl[wo]; pWl1 = *(const short8*)&Wl[wo + 8];
            }
        }

        short8 af[4], bfv[4], afl[4], bfl[4];
#pragma unroll
        for (int rb = 0; rb < 4; ++rb) {
            af[rb]  = *(const short8*)&Ah[fra + rb * 512];
            bfv[rb] = *(const short8*)&Bh[frb + rb * 512];
        }
#pragma unroll
        for (int rb = 0; rb < 4; ++rb)
#pragma unroll
            for (int cb = 0; cb < 4; ++cb)
                acc[rb][cb] = MFMA16(af[rb], bfv[cb], acc[rb][cb]);
        if constexpr (SPLIT) {
#pragma unroll
            for (int rb = 0; rb < 4; ++rb) afl[rb] = *(const short8*)&Al[fra + rb * 512];
#pragma unroll
            for (int rb = 0; rb < 4; ++rb)
#pragma unroll
                for (int cb = 0; cb < 4; ++cb)
                    acc[rb][cb] = MFMA16(afl[rb], bfv[cb], acc[rb][cb]);
#pragma unroll
            for (int rb = 0; rb < 4; ++rb) bfl[rb] = *(const short8*)&Bl[frb + rb * 512];
#pragma unroll
            for (int rb = 0; rb < 4; ++rb)
#pragma unroll
                for (int cb = 0; cb < 4; ++cb)
                    acc[rb][cb] = MFMA16(af[rb], bfl[cb], acc[rb][cb]);
        }
    }

    const int r0 = (l >> 4) * 4;
    const int cc = l & 15;
#pragma unroll
    for (int rb = 0; rb < 4; ++rb)
#pragma unroll
        for (int cb = 0; cb < 4; ++cb) {
            const int col = bn + wc + cb * 16 + cc;
            const float bv = bias[col];
#pragma unroll
            for (int r = 0; r < 4; ++r) {
                const int row = bm + wr + rb * 16 + r0 + r;
                const float v = (acc[rb][cb][r] + bv) * oscale;
                if constexpr (OUTMODE == 0) {
                    const unsigned short hi = f2bf(v);
                    Yhi[(size_t)row * 1024 + col] = hi;
                    Ylo[(size_t)row * 1024 + col] = f2bf(v - bf2f(hi));
                } else if constexpr (OUTMODE == 1) {
                    Yhi[(size_t)row * 1024 + col] = f2bf(v);
                } else {
                    Yf[(size_t)row * 1024 + col] = v;
                }
            }
        }
}

// ---------------------------------------------------------------------------
// Kernel 4: 64x64 bf16 transpose: V [4096][1024] -> VT [1024][4096].
// ---------------------------------------------------------------------------
__global__ __launch_bounds__(256) void transpose_kernel(
    const unsigned short* __restrict__ V, unsigned short* __restrict__ VT)
{
    __shared__ unsigned short tile[64][65];
    const int t = threadIdx.x;
    const int c0 = blockIdx.x * 64;
    const int r0 = blockIdx.y * 64;
    {
        const int r = t >> 2;
        const int q = (t & 3) * 16;
        short8 v0 = *(const short8*)&V[(size_t)(r0 + r) * 1024 + c0 + q];
        short8 v1 = *(const short8*)&V[(size_t)(r0 + r) * 1024 + c0 + q + 8];
#pragma unroll
        for (int i = 0; i < 8; ++i) {
            tile[r][q + i]     = (unsigned short)v0[i];
            tile[r][q + 8 + i] = (unsigned short)v1[i];
        }
    }
    __syncthreads();
    {
        const int c = t >> 2;          // 0..63
        const int g = (t & 3) * 16;    // 0,16,32,48
        short8 out0, out1;
#pragma unroll
        for (int i = 0; i < 8; ++i) {
            out0[i] = (short)tile[g + i][c];
            out1[i] = (short)tile[g + 8 + i][c];
        }
        *(short8*)&VT[(size_t)(c0 + c) * 4096 + r0 + g]     = out0;
        *(short8*)&VT[(size_t)(c0 + c) * 4096 + r0 + g + 8] = out1;
    }
}

// ---------------------------------------------------------------------------
// Kernel 5 (R5 rewrite): flash attention, 32x32 MFMA, swapped QK^T.
//  - S' = mfma(A=K, B=Q): lane owns q-col = lane&31; softmax lane-local
//    (31 fmax + one shfl_xor(32)); P assembled in-register via
//    v_cvt_pk_bf16_f32 + v_permlane32_swap_b32 (no P LDS round trip).
//  - PV = mfma(A=V^T, B=P) -> O^T: q stays lane-local, rescale = 1 scalar.
//  - 4 waves x 32 q-rows = 128-row blocks, KVBLK=64, double-buffered LDS,
//    one barrier per tile, K/V register prefetch.
// grid = (16, 16, 2), 256 threads.
// ---------------------------------------------------------------------------
__global__ __launch_bounds__(256) void attn_kernel(
    const unsigned short* __restrict__ Qh, const unsigned short* __restrict__ Ql,
    const unsigned short* __restrict__ Kh_g, const unsigned short* __restrict__ Kl_g,
    const unsigned short* __restrict__ VT, unsigned short* __restrict__ CTX)
{
    __shared__ unsigned short Khs[2][64 * 64];
    __shared__ unsigned short Kls[2][64 * 64];
    __shared__ unsigned short Vts[2][64 * 64];   // [d][k]

    const int t = threadIdx.x;
    const int l = t & 63;
    const int w = t >> 6;
    const int qt = blockIdx.x, h = blockIdx.y, b = blockIdx.z;
    const int lq = l & 31;     // this lane's q-row (within the wave's 32)
    const int hi = l >> 5;
    const int tokq = b * LQ + qt * 128 + w * 32;

    // Q fragments (B-operand): col q = lq, contraction k = d = ds*16 + hi*8 + j
    short8 qhf[4], qlf[4];
    {
        const size_t qr = (size_t)(tokq + lq) * 1024 + h * 64 + hi * 8;
#pragma unroll
        for (int ds = 0; ds < 4; ++ds) {
            qhf[ds] = *(const short8*)&Qh[qr + ds * 16];
            qlf[ds] = *(const short8*)&Ql[qr + ds * 16];
        }
    }

    f32x16 o0, o1;
#pragma unroll
    for (int i = 0; i < 16; ++i) { o0[i] = 0.f; o1[i] = 0.f; }
    float m = -1e30f, lsum = 0.f;

    // staging: 3 arrays x 64 rows x 8 chunks(16B); 256 threads x 2 chunks each
    const int srow = t >> 2;          // 0..63
    const int sch  = (t & 3) * 2;     // chunk base
    int sdst[2];
#pragma unroll
    for (int it = 0; it < 2; ++it)
        sdst[it] = srow * 64 + (((sch + it) ^ (srow & 7)) << 3);

    short8 pf_kh[2], pf_kl[2], pf_vt[2];
    {
        const int tokk = b * LQ;
#pragma unroll
        for (int it = 0; it < 2; ++it) {
            const size_t gk = (size_t)(tokk + srow) * 1024 + h * 64 + (sch + it) * 8;
            pf_kh[it] = *(const short8*)&Kh_g[gk];
            pf_kl[it] = *(const short8*)&Kl_g[gk];
            pf_vt[it] = *(const short8*)&VT[(size_t)(h * 64 + srow) * 4096 + tokk + (sch + it) * 8];
        }
    }

    const int lq7 = lq & 7;
    int cur = 0;
    for (int kt = 0; kt < 32; ++kt) {
#pragma unroll
        for (int it = 0; it < 2; ++it) {
            *(short8*)&Khs[cur][sdst[it]] = pf_kh[it];
            *(short8*)&Kls[cur][sdst[it]] = pf_kl[it];
            *(short8*)&Vts[cur][sdst[it]] = pf_vt[it];
        }
        if (kt < 31) {
            const int tokk = b * LQ + (kt + 1) * 64;
#pragma unroll
            for (int it = 0; it < 2; ++it) {
                const size_t gk = (size_t)(tokk + srow) * 1024 + h * 64 + (sch + it) * 8;
                pf_kh[it] = *(const short8*)&Kh_g[gk];
                pf_kl[it] = *(const short8*)&Kl_g[gk];
                pf_vt[it] = *(const short8*)&VT[(size_t)(h * 64 + srow) * 4096 + tokk + (sch + it) * 8];
            }
        }
        __syncthreads();

        // ---- swapped QK^T (3-pass split): S'[key][q] ----
        f32x16 s0, s1;
#pragma unroll
        for (int i = 0; i < 16; ++i) { s0[i] = 0.f; s1[i] = 0.f; }
#pragma unroll
        for (int ds = 0; ds < 4; ++ds) {
            const int slot = (((2 * ds + hi) ^ lq7) << 3);
            const int off = lq * 64 + slot;
            short8 kh0 = *(const short8*)&Khs[cur][off];
            short8 kh1 = *(const short8*)&Khs[cur][off + 2048];
            short8 kl0 = *(const short8*)&Kls[cur][off];
            short8 kl1 = *(const short8*)&Kls[cur][off + 2048];
            s0 = MFMA32(kh0, qhf[ds], s0);
            s1 = MFMA32(kh1, qhf[ds], s1);
            s0 = MFMA32(kl0, qhf[ds], s0);
            s1 = MFMA32(kl1, qhf[ds], s1);
            s0 = MFMA32(kh0, qlf[ds], s0);
            s1 = MFMA32(kh1, qlf[ds], s1);
        }

        // ---- lane-local online softmax (base 2), defer-max THR=8 ----
        float vm = s0[0];
#pragma unroll
        for (int i = 1; i < 16; ++i) vm = fmaxf(vm, s0[i]);
#pragma unroll
        for (int i = 0; i < 16; ++i) vm = fmaxf(vm, s1[i]);
        vm = fmaxf(vm, __shfl_xor(vm, 32));
        const float mg = fmaxf(m, vm);
        if (__any(mg > m + 8.f)) {
            const float mu = (mg > m + 8.f) ? mg : m;
            const float alpha = exp2f(m - mu);
            lsum *= alpha;
            o0 *= alpha;
            o1 *= alpha;
            m = mu;
        }
        float ps = 0.f;
#pragma unroll
        for (int i = 0; i < 16; ++i) { s0[i] = exp2f(s0[i] - m); ps += s0[i]; }
#pragma unroll
        for (int i = 0; i < 16; ++i) { s1[i] = exp2f(s1[i] - m); ps += s1[i]; }
        lsum += ps;

        // ---- pack P into PV B-fragments (cvt_pk + permlane32_swap) ----
        unsigned int pw[4][4];
        {
            unsigned int a, bb;
            // ks0 <- s0[0..7]
            a = cvtpk_bf16(s0[0], s0[1]); bb = cvtpk_bf16(s0[4], s0[5]);
            permswap(a, bb); pw[0][0] = a; pw[0][2] = bb;
            a = cvtpk_bf16(s0[2], s0[3]); bb = cvtpk_bf16(s0[6], s0[7]);
            permswap(a, bb); pw[0][1] = a; pw[0][3] = bb;
            // ks1 <- s0[8..15]
            a = cvtpk_bf16(s0[8], s0[9]); bb = cvtpk_bf16(s0[12], s0[13]);
            permswap(a, bb); pw[1][0] = a; pw[1][2] = bb;
            a = cvtpk_bf16(s0[10], s0[11]); bb = cvtpk_bf16(s0[14], s0[15]);
            permswap(a, bb); pw[1][1] = a; pw[1][3] = bb;
            // ks2 <- s1[0..7]
            a = cvtpk_bf16(s1[0], s1[1]); bb = cvtpk_bf16(s1[4], s1[5]);
            permswap(a, bb); pw[2][0] = a; pw[2][2] = bb;
            a = cvtpk_bf16(s1[2], s1[3]); bb = cvtpk_bf16(s1[6], s1[7]);
            permswap(a, bb); pw[2][1] = a; pw[2][3] = bb;
            // ks3 <- s1[8..15]
            a = cvtpk_bf16(s1[8], s1[9]); bb = cvtpk_bf16(s1[12], s1[13]);
            permswap(a, bb); pw[3][0] = a; pw[3][2] = bb;
            a = cvtpk_bf16(s1[10], s1[11]); bb = cvtpk_bf16(s1[14], s1[15]);
            permswap(a, bb); pw[3][1] = a; pw[3][3] = bb;
        }

        // ---- PV: O^T += V^T-frag x P-frag ----
#pragma unroll
        for (int ks = 0; ks < 4; ++ks) {
            union { unsigned int u[4]; short8 v; } pa;
            pa.u[0] = pw[ks][0]; pa.u[1] = pw[ks][1];
            pa.u[2] = pw[ks][2]; pa.u[3] = pw[ks][3];
            const int slot = (((2 * ks + hi) ^ lq7) << 3);
            short8 v0 = *(const short8*)&Vts[cur][lq * 64 + slot];
            short8 v1 = *(const short8*)&Vts[cur][(32 + lq) * 64 + slot];
            o0 = MFMA32(v0, pa.v, o0);
            o1 = MFMA32(v1, pa.v, o1);
        }
        cur ^= 1;
    }

    // ---- finalize: combine half-row sums, normalize, write O^T ----
    lsum += __shfl_xor(lsum, 32);
    const float inv = 1.f / lsum;
    const size_t orow = (size_t)(tokq + lq) * 1024 + h * 64 + hi * 4;
#pragma unroll
    for (int g = 0; g < 4; ++g) {
        u16x4 pack0, pack1;
#pragma unroll
        for (int j = 0; j < 4; ++j) {
            pack0[j] = f2bf(o0[4 * g + j] * inv);
            pack1[j] = f2bf(o1[4 * g + j] * inv);
        }
        *(u16x4*)&CTX[orow + 8 * g]      = pack0;   // d = 8g + 4hi + j
        *(u16x4*)&CTX[orow + 32 + 8 * g] = pack1;   // d = 32 + 8g + 4hi + j
    }
}

// ---------------------------------------------------------------------------
extern "C" void kernel_launch(void* const* d_in, const int* in_sizes, int n_in,
                              void* d_out, int out_size, void* d_ws, size_t ws_size,
                              hipStream_t stream)
{
    (void)in_sizes; (void)n_in; (void)out_size; (void)ws_size;
    const float* query = (const float*)d_in[0];
    char* base = (char*)d_ws;
    const size_t MB = 1 << 20;
    unsigned short* Whi = (unsigned short*)(base + 0 * MB);
    unsigned short* Wlo = (unsigned short*)(base + 8 * MB);
    unsigned short* Xhi = (unsigned short*)(base + 16 * MB);
    unsigned short* Xlo = (unsigned short*)(base + 24 * MB);
    unsigned short* Qhi = (unsigned short*)(base + 32 * MB);
    unsigned short* Qlo = (unsigned short*)(base + 40 * MB);
    unsigned short* Khi = (unsigned short*)(base + 48 * MB);
    unsigned short* Klo = (unsigned short*)(base + 56 * MB);
    unsigned short* Vh  = (unsigned short*)(base + 64 * MB);
    unsigned short* VTp = (unsigned short*)(base + 72 * MB);
    unsigned short* CTX = (unsigned short*)(base + 16 * MB);   // reuse X region

    CorePtrs cp;
    for (int p = 0; p < 4; ++p) {
        cp.c0[p] = (const float*)d_in[1 + 4 * p];
        cp.c1[p] = (const float*)d_in[2 + 4 * p];
        cp.c2[p] = (const float*)d_in[3 + 4 * p];
    }
    const size_t WSZ = (size_t)1024 * 1024;
    const float QSCALE = 0.125f * 1.44269504088896340736f;   // fold log2(e)

    build_w_kernel<<<dim3(64, 4), 256, 0, stream>>>(cp, Whi, Wlo);
    convert_x_kernel<<<4096, 256, 0, stream>>>(query, Xhi, Xlo, 1048576);

    gemm_kernel<true, 0><<<dim3(8, 32), 256, 0, stream>>>(
        Xhi, Xlo, Whi + 0 * WSZ, Wlo + 0 * WSZ, (const float*)d_in[4], QSCALE,
        Qhi, Qlo, nullptr);
    gemm_kernel<true, 0><<<dim3(8, 32), 256, 0, stream>>>(
        Xhi, Xlo, Whi + 1 * WSZ, Wlo + 1 * WSZ, (const float*)d_in[8], 1.0f,
        Khi, Klo, nullptr);
    gemm_kernel<false, 1><<<dim3(8, 32), 256, 0, stream>>>(
        Xhi, nullptr, Whi + 2 * WSZ, nullptr, (const float*)d_in[12], 1.0f,
        Vh, nullptr, nullptr);

    transpose_kernel<<<dim3(16, 64), 256, 0, stream>>>(Vh, VTp);

    attn_kernel<<<dim3(16, 16, 2), 256, 0, stream>>>(Qhi, Qlo, Khi, Klo, VTp, CTX);

    gemm_kernel<false, 2><<<dim3(8, 32), 256, 0, stream>>>(
        CTX, nullptr, Whi + 3 * WSZ, nullptr, (const float*)d_in[16], 1.0f,
        nullptr, nullptr, (float*)d_out);
}

// Round 6
// 294.756 us; speedup vs baseline: 4.0277x; 1.1054x over previous
//
#include <hip/hip_runtime.h>
#include <hip/hip_bf16.h>
#include <stdint.h>

#define LQ 2048
#define NTOK 4096

typedef __attribute__((ext_vector_type(8))) short short8;
typedef __attribute__((ext_vector_type(4))) float f32x4;
typedef __attribute__((ext_vector_type(16))) float f32x16;
typedef __attribute__((ext_vector_type(4))) unsigned short u16x4;

#define MFMA16(a, b, c) __builtin_amdgcn_mfma_f32_16x16x32_bf16((a), (b), (c), 0, 0, 0)
#define MFMA32(a, b, c) __builtin_amdgcn_mfma_f32_32x32x16_bf16((a), (b), (c), 0, 0, 0)

__device__ __forceinline__ unsigned short f2bf(float x) {
    union { __hip_bfloat16 b; unsigned short u; } v;
    v.b = __float2bfloat16(x);
    return v.u;
}
__device__ __forceinline__ float bf2f(unsigned short h) {
    union { uint32_t u; float f; } v; v.u = ((uint32_t)h) << 16; return v.f;
}
__device__ __forceinline__ unsigned int cvtpk_bf16(float lo, float hi_) {
    unsigned int r;
    asm("v_cvt_pk_bf16_f32 %0, %1, %2" : "=v"(r) : "v"(lo), "v"(hi_));
    return r;
}
__device__ __forceinline__ void permswap(unsigned int &a, unsigned int &b) {
    asm("v_permlane32_swap_b32 %0, %1" : "+v"(a), "+v"(b));
}
// raw v_exp_f32: args here are always <= 0 (s - m), no guard code needed
__device__ __forceinline__ float fast_exp2(float x) {
    float r;
    asm("v_exp_f32 %0, %1" : "=v"(r) : "v"(x));
    return r;
}

struct CorePtrs {
    const float* c0[4];
    const float* c1[4];
    const float* c2[4];
};

struct QkvOut {
    unsigned short* hi[3];       // Qhi, Khi, Vh
    unsigned short* lo[2];       // Qlo, Klo
    const float* bias[3];
    float osc[3];
};

// ---------------------------------------------------------------------------
// Kernel 1: materialize W (bf16 hi + lo residual) for all 4 projections.
// ---------------------------------------------------------------------------
__global__ __launch_bounds__(256) void build_w_kernel(
    CorePtrs cp, unsigned short* __restrict__ Whi, unsigned short* __restrict__ Wlo)
{
    __shared__ float B1[16 * 16 * 16];   // [i1][q1][s2]
    const int p  = blockIdx.y;
    const int i0 = blockIdx.x >> 3;
    const int q0 = blockIdx.x & 7;
    const int t  = threadIdx.x;
    const float* __restrict__ c0 = cp.c0[p];
    const float* __restrict__ c1 = cp.c1[p];
    const float* __restrict__ c2 = cp.c2[p];

    float g0[16];
#pragma unroll
    for (int s = 0; s < 16; ++s) g0[s] = c0[(i0 * 8 + q0) * 16 + s];

    for (int idx = t; idx < 4096; idx += 256) {
        const int s2 = idx & 15;
        const int q1 = (idx >> 4) & 15;
        const int i1 = idx >> 8;
        float acc = 0.f;
#pragma unroll
        for (int s = 0; s < 16; ++s)
            acc += g0[s] * c1[((s * 16 + i1) * 16 + q1) * 16 + s2];
        B1[idx] = acc;
    }
    __syncthreads();

    const size_t base = (size_t)p * 1024 * 1024;
    for (int idx = t; idx < 16384; idx += 256) {
        const int q2 = idx & 7;
        const int i2 = (idx >> 3) & 7;
        const int q1 = (idx >> 6) & 15;
        const int i1 = idx >> 10;
        float acc = 0.f;
#pragma unroll
        for (int s2 = 0; s2 < 16; ++s2)
            acc += B1[(i1 * 16 + q1) * 16 + s2] * c2[(s2 * 8 + i2) * 8 + q2];
        const int o = q0 * 128 + q1 * 8 + q2;
        const int e = i0 * 128 + i1 * 8 + i2;
        const unsigned short hi = f2bf(acc);
        Whi[base + o * 1024 + e] = hi;
        Wlo[base + o * 1024 + e] = f2bf(acc - bf2f(hi));
    }
}

// ---------------------------------------------------------------------------
// Kernel 2: fp32 -> bf16 hi/lo split of the input activations.
// ---------------------------------------------------------------------------
__global__ __launch_bounds__(256) void convert_x_kernel(
    const float* __restrict__ X, unsigned short* __restrict__ Xhi,
    unsigned short* __restrict__ Xlo, int n4)
{
    const int i = blockIdx.x * 256 + threadIdx.x;
    if (i >= n4) return;
    const float4 v = ((const float4*)X)[i];
    u16x4 hi, lo;
    float vv[4] = {v.x, v.y, v.z, v.w};
#pragma unroll
    for (int j = 0; j < 4; ++j) {
        unsigned short h = f2bf(vv[j]);
        hi[j] = h;
        lo[j] = f2bf(vv[j] - bf2f(h));
    }
    ((u16x4*)Xhi)[i] = hi;
    ((u16x4*)Xlo)[i] = lo;
}

// ---------------------------------------------------------------------------
// Kernel 3a (R6): FUSED QKV 3-pass split GEMM over N=3072.
// W rows 0-1023 = Wq, 1024-2047 = Wk, 2048-3071 = Wv (contiguous in ws).
// 128x128 tile -> grid (24, 32) = 768 blocks (3/CU). A 128-col tile never
// straddles a projection (1024 % 128 == 0) so output select is block-uniform.
// ---------------------------------------------------------------------------
__global__ __launch_bounds__(256) void gemm_qkv_kernel(
    const unsigned short* __restrict__ Xh, const unsigned short* __restrict__ Xl,
    const unsigned short* __restrict__ Wh, const unsigned short* __restrict__ Wl,
    QkvOut op)
{
    __shared__ unsigned short Ah[128 * 32];
    __shared__ unsigned short Bh[128 * 32];
    __shared__ unsigned short Al[128 * 32];
    __shared__ unsigned short Bl[128 * 32];

    const int t = threadIdx.x;
    const int l = t & 63;
    const int w = t >> 6;
    const int wr = (w >> 1) * 64, wc = (w & 1) * 64;
    const int bm = blockIdx.y * 128, bn = blockIdx.x * 128;

    f32x4 acc[4][4];
#pragma unroll
    for (int i = 0; i < 4; ++i)
#pragma unroll
        for (int j = 0; j < 4; ++j) acc[i][j] = (f32x4){0.f, 0.f, 0.f, 0.f};

    const int srow = t >> 1;
    const int sch  = (t & 1) * 2;
    const int ssel = (srow >> 1) & 3;
    const int sd0  = srow * 32 + (((sch)     ^ ssel) << 3);
    const int sd1  = srow * 32 + (((sch + 1) ^ ssel) << 3);
    const size_t xoff = (size_t)(bm + srow) * 1024 + sch * 8;
    const size_t woff = (size_t)(bn + srow) * 1024 + sch * 8;

    const int fsel = ((l & 15) >> 1) & 3;
    const int fpos = ((l >> 4) ^ fsel) << 3;
    const int fra  = (wr + (l & 15)) * 32 + fpos;
    const int frb  = (wc + (l & 15)) * 32 + fpos;

    short8 pXh0, pXh1, pWh0, pWh1, pXl0, pXl1, pWl0, pWl1;
    pXh0 = *(const short8*)&Xh[xoff];     pXh1 = *(const short8*)&Xh[xoff + 8];
    pWh0 = *(const short8*)&Wh[woff];     pWh1 = *(const short8*)&Wh[woff + 8];
    pXl0 = *(const short8*)&Xl[xoff];     pXl1 = *(const short8*)&Xl[xoff + 8];
    pWl0 = *(const short8*)&Wl[woff];     pWl1 = *(const short8*)&Wl[woff + 8];

    for (int e0 = 0; e0 < 1024; e0 += 32) {
        __syncthreads();
        *(short8*)&Ah[sd0] = pXh0; *(short8*)&Ah[sd1] = pXh1;
        *(short8*)&Bh[sd0] = pWh0; *(short8*)&Bh[sd1] = pWh1;
        *(short8*)&Al[sd0] = pXl0; *(short8*)&Al[sd1] = pXl1;
        *(short8*)&Bl[sd0] = pWl0; *(short8*)&Bl[sd1] = pWl1;
        __syncthreads();

        if (e0 + 32 < 1024) {
            const size_t xo = xoff + e0 + 32, wo = woff + e0 + 32;
            pXh0 = *(const short8*)&Xh[xo];     pXh1 = *(const short8*)&Xh[xo + 8];
            pWh0 = *(const short8*)&Wh[wo];     pWh1 = *(const short8*)&Wh[wo + 8];
            pXl0 = *(const short8*)&Xl[xo];     pXl1 = *(const short8*)&Xl[xo + 8];
            pWl0 = *(const short8*)&Wl[wo];     pWl1 = *(const short8*)&Wl[wo + 8];
        }

        short8 af[4], bfv[4], afl[4], bfl[4];
#pragma unroll
        for (int rb = 0; rb < 4; ++rb) {
            af[rb]  = *(const short8*)&Ah[fra + rb * 512];
            bfv[rb] = *(const short8*)&Bh[frb + rb * 512];
        }
#pragma unroll
        for (int rb = 0; rb < 4; ++rb)
#pragma unroll
            for (int cb = 0; cb < 4; ++cb)
                acc[rb][cb] = MFMA16(af[rb], bfv[cb], acc[rb][cb]);
#pragma unroll
        for (int rb = 0; rb < 4; ++rb) afl[rb] = *(const short8*)&Al[fra + rb * 512];
#pragma unroll
        for (int rb = 0; rb < 4; ++rb)
#pragma unroll
            for (int cb = 0; cb < 4; ++cb)
                acc[rb][cb] = MFMA16(afl[rb], bfv[cb], acc[rb][cb]);
#pragma unroll
        for (int rb = 0; rb < 4; ++rb) bfl[rb] = *(const short8*)&Bl[frb + rb * 512];
#pragma unroll
        for (int rb = 0; rb < 4; ++rb)
#pragma unroll
            for (int cb = 0; cb < 4; ++cb)
                acc[rb][cb] = MFMA16(af[rb], bfl[cb], acc[rb][cb]);
    }

    const int p = bn >> 10;                       // 0=Q 1=K 2=V (block-uniform)
    unsigned short* __restrict__ yh = op.hi[p];
    unsigned short* __restrict__ yl = (p < 2) ? op.lo[p] : nullptr;
    const float* __restrict__ bp = op.bias[p];
    const float osc = op.osc[p];
    const int bnl = bn & 1023;

    const int r0 = (l >> 4) * 4;
    const int cc = l & 15;
#pragma unroll
    for (int rb = 0; rb < 4; ++rb)
#pragma unroll
        for (int cb = 0; cb < 4; ++cb) {
            const int col = bnl + wc + cb * 16 + cc;
            const float bv = bp[col];
#pragma unroll
            for (int r = 0; r < 4; ++r) {
                const int row = bm + wr + rb * 16 + r0 + r;
                const float v = (acc[rb][cb][r] + bv) * osc;
                const unsigned short hi = f2bf(v);
                yh[(size_t)row * 1024 + col] = hi;
                if (p < 2)
                    yl[(size_t)row * 1024 + col] = f2bf(v - bf2f(hi));
            }
        }
}

// ---------------------------------------------------------------------------
// Kernel 3b: plain 1-pass NT-GEMM (output projection), f32 out. Unchanged.
// ---------------------------------------------------------------------------
__global__ __launch_bounds__(256) void gemm_out_kernel(
    const unsigned short* __restrict__ Xh,
    const unsigned short* __restrict__ Wh,
    const float* __restrict__ bias,
    float* __restrict__ Yf)
{
    __shared__ unsigned short Ah[128 * 32];
    __shared__ unsigned short Bh[128 * 32];

    const int t = threadIdx.x;
    const int l = t & 63;
    const int w = t >> 6;
    const int wr = (w >> 1) * 64, wc = (w & 1) * 64;
    const int bm = blockIdx.y * 128, bn = blockIdx.x * 128;

    f32x4 acc[4][4];
#pragma unroll
    for (int i = 0; i < 4; ++i)
#pragma unroll
        for (int j = 0; j < 4; ++j) acc[i][j] = (f32x4){0.f, 0.f, 0.f, 0.f};

    const int srow = t >> 1;
    const int sch  = (t & 1) * 2;
    const int ssel = (srow >> 1) & 3;
    const int sd0  = srow * 32 + (((sch)     ^ ssel) << 3);
    const int sd1  = srow * 32 + (((sch + 1) ^ ssel) << 3);
    const size_t xoff = (size_t)(bm + srow) * 1024 + sch * 8;
    const size_t woff = (size_t)(bn + srow) * 1024 + sch * 8;

    const int fsel = ((l & 15) >> 1) & 3;
    const int fpos = ((l >> 4) ^ fsel) << 3;
    const int fra  = (wr + (l & 15)) * 32 + fpos;
    const int frb  = (wc + (l & 15)) * 32 + fpos;

    short8 pXh0, pXh1, pWh0, pWh1;
    pXh0 = *(const short8*)&Xh[xoff]; pXh1 = *(const short8*)&Xh[xoff + 8];
    pWh0 = *(const short8*)&Wh[woff]; pWh1 = *(const short8*)&Wh[woff + 8];

    for (int e0 = 0; e0 < 1024; e0 += 32) {
        __syncthreads();
        *(short8*)&Ah[sd0] = pXh0; *(short8*)&Ah[sd1] = pXh1;
        *(short8*)&Bh[sd0] = pWh0; *(short8*)&Bh[sd1] = pWh1;
        __syncthreads();

        if (e0 + 32 < 1024) {
            const size_t xo = xoff + e0 + 32, wo = woff + e0 + 32;
            pXh0 = *(const short8*)&Xh[xo]; pXh1 = *(const short8*)&Xh[xo + 8];
            pWh0 = *(const short8*)&Wh[wo]; pWh1 = *(const short8*)&Wh[wo + 8];
        }

        short8 af[4], bfv[4];
#pragma unroll
        for (int rb = 0; rb < 4; ++rb) {
            af[rb]  = *(const short8*)&Ah[fra + rb * 512];
            bfv[rb] = *(const short8*)&Bh[frb + rb * 512];
        }
#pragma unroll
        for (int rb = 0; rb < 4; ++rb)
#pragma unroll
            for (int cb = 0; cb < 4; ++cb)
                acc[rb][cb] = MFMA16(af[rb], bfv[cb], acc[rb][cb]);
    }

    const int r0 = (l >> 4) * 4;
    const int cc = l & 15;
#pragma unroll
    for (int rb = 0; rb < 4; ++rb)
#pragma unroll
        for (int cb = 0; cb < 4; ++cb) {
            const int col = bn + wc + cb * 16 + cc;
            const float bv = bias[col];
#pragma unroll
            for (int r = 0; r < 4; ++r) {
                const int row = bm + wr + rb * 16 + r0 + r;
                Yf[(size_t)row * 1024 + col] = acc[rb][cb][r] + bv;
            }
        }
}

// ---------------------------------------------------------------------------
// Kernel 4: 64x64 bf16 transpose: V [4096][1024] -> VT [1024][4096].
// ---------------------------------------------------------------------------
__global__ __launch_bounds__(256) void transpose_kernel(
    const unsigned short* __restrict__ V, unsigned short* __restrict__ VT)
{
    __shared__ unsigned short tile[64][65];
    const int t = threadIdx.x;
    const int c0 = blockIdx.x * 64;
    const int r0 = blockIdx.y * 64;
    {
        const int r = t >> 2;
        const int q = (t & 3) * 16;
        short8 v0 = *(const short8*)&V[(size_t)(r0 + r) * 1024 + c0 + q];
        short8 v1 = *(const short8*)&V[(size_t)(r0 + r) * 1024 + c0 + q + 8];
#pragma unroll
        for (int i = 0; i < 8; ++i) {
            tile[r][q + i]     = (unsigned short)v0[i];
            tile[r][q + 8 + i] = (unsigned short)v1[i];
        }
    }
    __syncthreads();
    {
        const int c = t >> 2;
        const int g = (t & 3) * 16;
        short8 out0, out1;
#pragma unroll
        for (int i = 0; i < 8; ++i) {
            out0[i] = (short)tile[g + i][c];
            out1[i] = (short)tile[g + 8 + i][c];
        }
        *(short8*)&VT[(size_t)(c0 + c) * 4096 + r0 + g]     = out0;
        *(short8*)&VT[(size_t)(c0 + c) * 4096 + r0 + g + 8] = out1;
    }
}

// ---------------------------------------------------------------------------
// Kernel 5: flash attention, 32x32 MFMA, swapped QK^T (R5 structure).
// R6: incremental global pointers, raw v_exp_f32, precomputed LDS offsets,
// s_setprio around MFMA clusters.
// ---------------------------------------------------------------------------
__global__ __launch_bounds__(256) void attn_kernel(
    const unsigned short* __restrict__ Qh, const unsigned short* __restrict__ Ql,
    const unsigned short* __restrict__ Kh_g, const unsigned short* __restrict__ Kl_g,
    const unsigned short* __restrict__ VT, unsigned short* __restrict__ CTX)
{
    __shared__ unsigned short Khs[2][64 * 64];
    __shared__ unsigned short Kls[2][64 * 64];
    __shared__ unsigned short Vts[2][64 * 64];   // [d][k]

    const int t = threadIdx.x;
    const int l = t & 63;
    const int w = t >> 6;
    const int qt = blockIdx.x, h = blockIdx.y, b = blockIdx.z;
    const int lq = l & 31;
    const int hi = l >> 5;
    const int tokq = b * LQ + qt * 128 + w * 32;

    short8 qhf[4], qlf[4];
    {
        const size_t qr = (size_t)(tokq + lq) * 1024 + h * 64 + hi * 8;
#pragma unroll
        for (int ds = 0; ds < 4; ++ds) {
            qhf[ds] = *(const short8*)&Qh[qr + ds * 16];
            qlf[ds] = *(const short8*)&Ql[qr + ds * 16];
        }
    }

    f32x16 o0, o1;
#pragma unroll
    for (int i = 0; i < 16; ++i) { o0[i] = 0.f; o1[i] = 0.f; }
    float m = -1e30f, lsum = 0.f;

    const int srow = t >> 2;          // 0..63
    const int sch  = (t & 3) * 2;
    int sdst[2];
#pragma unroll
    for (int it = 0; it < 2; ++it)
        sdst[it] = srow * 64 + (((sch + it) ^ (srow & 7)) << 3);

    // incremental staging pointers (advance by constant stride per tile)
    const unsigned short* pkh = Kh_g + (size_t)(b * LQ + srow) * 1024 + h * 64 + sch * 8;
    const unsigned short* pkl = Kl_g + (size_t)(b * LQ + srow) * 1024 + h * 64 + sch * 8;
    const unsigned short* pvt = VT + (size_t)(h * 64 + srow) * 4096 + b * LQ + sch * 8;

    short8 pf_kh[2], pf_kl[2], pf_vt[2];
    pf_kh[0] = *(const short8*)pkh;       pf_kh[1] = *(const short8*)(pkh + 8);
    pf_kl[0] = *(const short8*)pkl;       pf_kl[1] = *(const short8*)(pkl + 8);
    pf_vt[0] = *(const short8*)pvt;       pf_vt[1] = *(const short8*)(pvt + 8);

    // precomputed LDS read offsets (loop-invariant)
    const int lq7 = lq & 7;
    int qkoff[4], pvslot[4];
#pragma unroll
    for (int i = 0; i < 4; ++i) {
        qkoff[i]  = lq * 64 + (((2 * i + hi) ^ lq7) << 3);
        pvslot[i] = (((2 * i + hi) ^ lq7) << 3);
    }

    int cur = 0;
    for (int kt = 0; kt < 32; ++kt) {
#pragma unroll
        for (int it = 0; it < 2; ++it) {
            *(short8*)&Khs[cur][sdst[it]] = pf_kh[it];
            *(short8*)&Kls[cur][sdst[it]] = pf_kl[it];
            *(short8*)&Vts[cur][sdst[it]] = pf_vt[it];
        }
        if (kt < 31) {
            pkh += 64 * 1024; pkl += 64 * 1024; pvt += 64;
            pf_kh[0] = *(const short8*)pkh;  pf_kh[1] = *(const short8*)(pkh + 8);
            pf_kl[0] = *(const short8*)pkl;  pf_kl[1] = *(const short8*)(pkl + 8);
            pf_vt[0] = *(const short8*)pvt;  pf_vt[1] = *(const short8*)(pvt + 8);
        }
        __syncthreads();

        // ---- swapped QK^T (3-pass split): S'[key][q] ----
        f32x16 s0, s1;
#pragma unroll
        for (int i = 0; i < 16; ++i) { s0[i] = 0.f; s1[i] = 0.f; }
        __builtin_amdgcn_s_setprio(1);
#pragma unroll
        for (int ds = 0; ds < 4; ++ds) {
            const int off = qkoff[ds];
            short8 kh0 = *(const short8*)&Khs[cur][off];
            short8 kh1 = *(const short8*)&Khs[cur][off + 2048];
            short8 kl0 = *(const short8*)&Kls[cur][off];
            short8 kl1 = *(const short8*)&Kls[cur][off + 2048];
            s0 = MFMA32(kh0, qhf[ds], s0);
            s1 = MFMA32(kh1, qhf[ds], s1);
            s0 = MFMA32(kl0, qhf[ds], s0);
            s1 = MFMA32(kl1, qhf[ds], s1);
            s0 = MFMA32(kh0, qlf[ds], s0);
            s1 = MFMA32(kh1, qlf[ds], s1);
        }
        __builtin_amdgcn_s_setprio(0);

        // ---- lane-local online softmax (base 2), defer-max THR=8 ----
        float vm = fmaxf(fmaxf(s0[0], s0[1]), s0[2]);
#pragma unroll
        for (int i = 3; i < 15; i += 2) vm = fmaxf(fmaxf(s0[i], s0[i + 1]), vm);
        vm = fmaxf(fmaxf(s0[15], s1[0]), vm);
#pragma unroll
        for (int i = 1; i < 15; i += 2) vm = fmaxf(fmaxf(s1[i], s1[i + 1]), vm);
        vm = fmaxf(s1[15], vm);
        vm = fmaxf(vm, __shfl_xor(vm, 32));
        const float mg = fmaxf(m, vm);
        if (__any(mg > m + 8.f)) {
            const float mu = (mg > m + 8.f) ? mg : m;
            const float alpha = fast_exp2(m - mu);
            lsum *= alpha;
            o0 *= alpha;
            o1 *= alpha;
            m = mu;
        }
        float ps = 0.f;
#pragma unroll
        for (int i = 0; i < 16; ++i) { s0[i] = fast_exp2(s0[i] - m); ps += s0[i]; }
#pragma unroll
        for (int i = 0; i < 16; ++i) { s1[i] = fast_exp2(s1[i] - m); ps += s1[i]; }
        lsum += ps;

        // ---- pack P into PV B-fragments (cvt_pk + permlane32_swap) ----
        unsigned int pw[4][4];
        {
            unsigned int a, bb;
            a = cvtpk_bf16(s0[0], s0[1]); bb = cvtpk_bf16(s0[4], s0[5]);
            permswap(a, bb); pw[0][0] = a; pw[0][2] = bb;
            a = cvtpk_bf16(s0[2], s0[3]); bb = cvtpk_bf16(s0[6], s0[7]);
            permswap(a, bb); pw[0][1] = a; pw[0][3] = bb;
            a = cvtpk_bf16(s0[8], s0[9]); bb = cvtpk_bf16(s0[12], s0[13]);
            permswap(a, bb); pw[1][0] = a; pw[1][2] = bb;
            a = cvtpk_bf16(s0[10], s0[11]); bb = cvtpk_bf16(s0[14], s0[15]);
            permswap(a, bb); pw[1][1] = a; pw[1][3] = bb;
            a = cvtpk_bf16(s1[0], s1[1]); bb = cvtpk_bf16(s1[4], s1[5]);
            permswap(a, bb); pw[2][0] = a; pw[2][2] = bb;
            a = cvtpk_bf16(s1[2], s1[3]); bb = cvtpk_bf16(s1[6], s1[7]);
            permswap(a, bb); pw[2][1] = a; pw[2][3] = bb;
            a = cvtpk_bf16(s1[8], s1[9]); bb = cvtpk_bf16(s1[12], s1[13]);
            permswap(a, bb); pw[3][0] = a; pw[3][2] = bb;
            a = cvtpk_bf16(s1[10], s1[11]); bb = cvtpk_bf16(s1[14], s1[15]);
            permswap(a, bb); pw[3][1] = a; pw[3][3] = bb;
        }

        // ---- PV: O^T += V^T-frag x P-frag ----
        __builtin_amdgcn_s_setprio(1);
#pragma unroll
        for (int ks = 0; ks < 4; ++ks) {
            union { unsigned int u[4]; short8 v; } pa;
            pa.u[0] = pw[ks][0]; pa.u[1] = pw[ks][1];
            pa.u[2] = pw[ks][2]; pa.u[3] = pw[ks][3];
            const int slot = pvslot[ks];
            short8 v0 = *(const short8*)&Vts[cur][lq * 64 + slot];
            short8 v1 = *(const short8*)&Vts[cur][(32 + lq) * 64 + slot];
            o0 = MFMA32(v0, pa.v, o0);
            o1 = MFMA32(v1, pa.v, o1);
        }
        __builtin_amdgcn_s_setprio(0);
        cur ^= 1;
    }

    // ---- finalize ----
    lsum += __shfl_xor(lsum, 32);
    const float inv = 1.f / lsum;
    const size_t orow = (size_t)(tokq + lq) * 1024 + h * 64 + hi * 4;
#pragma unroll
    for (int g = 0; g < 4; ++g) {
        u16x4 pack0, pack1;
#pragma unroll
        for (int j = 0; j < 4; ++j) {
            pack0[j] = f2bf(o0[4 * g + j] * inv);
            pack1[j] = f2bf(o1[4 * g + j] * inv);
        }
        *(u16x4*)&CTX[orow + 8 * g]      = pack0;
        *(u16x4*)&CTX[orow + 32 + 8 * g] = pack1;
    }
}

// ---------------------------------------------------------------------------
extern "C" void kernel_launch(void* const* d_in, const int* in_sizes, int n_in,
                              void* d_out, int out_size, void* d_ws, size_t ws_size,
                              hipStream_t stream)
{
    (void)in_sizes; (void)n_in; (void)out_size; (void)ws_size;
    const float* query = (const float*)d_in[0];
    char* base = (char*)d_ws;
    const size_t MB = 1 << 20;
    unsigned short* Whi = (unsigned short*)(base + 0 * MB);
    unsigned short* Wlo = (unsigned short*)(base + 8 * MB);
    unsigned short* Xhi = (unsigned short*)(base + 16 * MB);
    unsigned short* Xlo = (unsigned short*)(base + 24 * MB);
    unsigned short* Qhi = (unsigned short*)(base + 32 * MB);
    unsigned short* Qlo = (unsigned short*)(base + 40 * MB);
    unsigned short* Khi = (unsigned short*)(base + 48 * MB);
    unsigned short* Klo = (unsigned short*)(base + 56 * MB);
    unsigned short* Vh  = (unsigned short*)(base + 64 * MB);
    unsigned short* VTp = (unsigned short*)(base + 72 * MB);
    unsigned short* CTX = (unsigned short*)(base + 16 * MB);   // reuse X region

    CorePtrs cp;
    for (int p = 0; p < 4; ++p) {
        cp.c0[p] = (const float*)d_in[1 + 4 * p];
        cp.c1[p] = (const float*)d_in[2 + 4 * p];
        cp.c2[p] = (const float*)d_in[3 + 4 * p];
    }
    const size_t WSZ = (size_t)1024 * 1024;
    const float QSCALE = 0.125f * 1.44269504088896340736f;   // fold log2(e)

    build_w_kernel<<<dim3(64, 4), 256, 0, stream>>>(cp, Whi, Wlo);
    convert_x_kernel<<<4096, 256, 0, stream>>>(query, Xhi, Xlo, 1048576);

    QkvOut op;
    op.hi[0] = Qhi; op.hi[1] = Khi; op.hi[2] = Vh;
    op.lo[0] = Qlo; op.lo[1] = Klo;
    op.bias[0] = (const float*)d_in[4];
    op.bias[1] = (const float*)d_in[8];
    op.bias[2] = (const float*)d_in[12];
    op.osc[0] = QSCALE; op.osc[1] = 1.0f; op.osc[2] = 1.0f;

    gemm_qkv_kernel<<<dim3(24, 32), 256, 0, stream>>>(Xhi, Xlo, Whi, Wlo, op);

    transpose_kernel<<<dim3(16, 64), 256, 0, stream>>>(Vh, VTp);

    attn_kernel<<<dim3(16, 16, 2), 256, 0, stream>>>(Qhi, Qlo, Khi, Klo, VTp, CTX);

    gemm_out_kernel<<<dim3(8, 32), 256, 0, stream>>>(
        CTX, Whi + 3 * WSZ, (const float*)d_in[16], (float*)d_out);
}

// Round 7
// 285.290 us; speedup vs baseline: 4.1614x; 1.0332x over previous
//
#include <hip/hip_runtime.h>
#include <hip/hip_bf16.h>
#include <stdint.h>

#define LQ 2048
#define NTOK 4096

typedef __attribute__((ext_vector_type(8))) short short8;
typedef __attribute__((ext_vector_type(4))) float f32x4;
typedef __attribute__((ext_vector_type(16))) float f32x16;
typedef __attribute__((ext_vector_type(4))) unsigned short u16x4;

#define MFMA16(a, b, c) __builtin_amdgcn_mfma_f32_16x16x32_bf16((a), (b), (c), 0, 0, 0)
#define MFMA32(a, b, c) __builtin_amdgcn_mfma_f32_32x32x16_bf16((a), (b), (c), 0, 0, 0)

__device__ __forceinline__ unsigned short f2bf(float x) {
    union { __hip_bfloat16 b; unsigned short u; } v;
    v.b = __float2bfloat16(x);
    return v.u;
}
__device__ __forceinline__ float bf2f(unsigned short h) {
    union { uint32_t u; float f; } v; v.u = ((uint32_t)h) << 16; return v.f;
}
__device__ __forceinline__ unsigned int cvtpk_bf16(float lo, float hi_) {
    unsigned int r;
    asm("v_cvt_pk_bf16_f32 %0, %1, %2" : "=v"(r) : "v"(lo), "v"(hi_));
    return r;
}
__device__ __forceinline__ void permswap(unsigned int &a, unsigned int &b) {
    asm("v_permlane32_swap_b32 %0, %1" : "+v"(a), "+v"(b));
}
__device__ __forceinline__ float fast_exp2(float x) {
    float r;
    asm("v_exp_f32 %0, %1" : "=v"(r) : "v"(x));
    return r;
}

struct CorePtrs {
    const float* c0[4];
    const float* c1[4];
    const float* c2[4];
};

struct QkvOut {
    unsigned short* hi[3];       // Qhi, Khi, Vh
    unsigned short* lo[2];       // Qlo, Klo
    const float* bias[3];
    float osc[3];
};

// ---------------------------------------------------------------------------
// Kernel 1: materialize W (bf16 hi + lo residual) for all 4 projections.
// ---------------------------------------------------------------------------
__global__ __launch_bounds__(256) void build_w_kernel(
    CorePtrs cp, unsigned short* __restrict__ Whi, unsigned short* __restrict__ Wlo)
{
    __shared__ float B1[16 * 16 * 16];   // [i1][q1][s2]
    const int p  = blockIdx.y;
    const int i0 = blockIdx.x >> 3;
    const int q0 = blockIdx.x & 7;
    const int t  = threadIdx.x;
    const float* __restrict__ c0 = cp.c0[p];
    const float* __restrict__ c1 = cp.c1[p];
    const float* __restrict__ c2 = cp.c2[p];

    float g0[16];
#pragma unroll
    for (int s = 0; s < 16; ++s) g0[s] = c0[(i0 * 8 + q0) * 16 + s];

    for (int idx = t; idx < 4096; idx += 256) {
        const int s2 = idx & 15;
        const int q1 = (idx >> 4) & 15;
        const int i1 = idx >> 8;
        float acc = 0.f;
#pragma unroll
        for (int s = 0; s < 16; ++s)
            acc += g0[s] * c1[((s * 16 + i1) * 16 + q1) * 16 + s2];
        B1[idx] = acc;
    }
    __syncthreads();

    const size_t base = (size_t)p * 1024 * 1024;
    for (int idx = t; idx < 16384; idx += 256) {
        const int q2 = idx & 7;
        const int i2 = (idx >> 3) & 7;
        const int q1 = (idx >> 6) & 15;
        const int i1 = idx >> 10;
        float acc = 0.f;
#pragma unroll
        for (int s2 = 0; s2 < 16; ++s2)
            acc += B1[(i1 * 16 + q1) * 16 + s2] * c2[(s2 * 8 + i2) * 8 + q2];
        const int o = q0 * 128 + q1 * 8 + q2;
        const int e = i0 * 128 + i1 * 8 + i2;
        const unsigned short hi = f2bf(acc);
        Whi[base + o * 1024 + e] = hi;
        Wlo[base + o * 1024 + e] = f2bf(acc - bf2f(hi));
    }
}

// ---------------------------------------------------------------------------
// Kernel 2: fp32 -> bf16 hi/lo split of the input activations.
// ---------------------------------------------------------------------------
__global__ __launch_bounds__(256) void convert_x_kernel(
    const float* __restrict__ X, unsigned short* __restrict__ Xhi,
    unsigned short* __restrict__ Xlo, int n4)
{
    const int i = blockIdx.x * 256 + threadIdx.x;
    if (i >= n4) return;
    const float4 v = ((const float4*)X)[i];
    u16x4 hi, lo;
    float vv[4] = {v.x, v.y, v.z, v.w};
#pragma unroll
    for (int j = 0; j < 4; ++j) {
        unsigned short h = f2bf(vv[j]);
        hi[j] = h;
        lo[j] = f2bf(vv[j] - bf2f(h));
    }
    ((u16x4*)Xhi)[i] = hi;
    ((u16x4*)Xlo)[i] = lo;
}

// ---------------------------------------------------------------------------
// Kernel 3a: FUSED QKV split GEMM over N=3072.
// R7: V-blocks (bn>>10 == 2) skip the lo staging and both lo MFMA passes —
// they only need the plain-bf16 product (2/9 of total MFMA work removed).
// ---------------------------------------------------------------------------
__global__ __launch_bounds__(256) void gemm_qkv_kernel(
    const unsigned short* __restrict__ Xh, const unsigned short* __restrict__ Xl,
    const unsigned short* __restrict__ Wh, const unsigned short* __restrict__ Wl,
    QkvOut op)
{
    __shared__ unsigned short Ah[128 * 32];
    __shared__ unsigned short Bh[128 * 32];
    __shared__ unsigned short Al[128 * 32];
    __shared__ unsigned short Bl[128 * 32];

    const int t = threadIdx.x;
    const int l = t & 63;
    const int w = t >> 6;
    const int wr = (w >> 1) * 64, wc = (w & 1) * 64;
    const int bm = blockIdx.y * 128, bn = blockIdx.x * 128;
    const bool is_v = (bn >> 10) == 2;     // block-uniform

    f32x4 acc[4][4];
#pragma unroll
    for (int i = 0; i < 4; ++i)
#pragma unroll
        for (int j = 0; j < 4; ++j) acc[i][j] = (f32x4){0.f, 0.f, 0.f, 0.f};

    const int srow = t >> 1;
    const int sch  = (t & 1) * 2;
    const int ssel = (srow >> 1) & 3;
    const int sd0  = srow * 32 + (((sch)     ^ ssel) << 3);
    const int sd1  = srow * 32 + (((sch + 1) ^ ssel) << 3);
    const size_t xoff = (size_t)(bm + srow) * 1024 + sch * 8;
    const size_t woff = (size_t)(bn + srow) * 1024 + sch * 8;

    const int fsel = ((l & 15) >> 1) & 3;
    const int fpos = ((l >> 4) ^ fsel) << 3;
    const int fra  = (wr + (l & 15)) * 32 + fpos;
    const int frb  = (wc + (l & 15)) * 32 + fpos;

    short8 pXh0, pXh1, pWh0, pWh1, pXl0, pXl1, pWl0, pWl1;
    pXh0 = *(const short8*)&Xh[xoff];     pXh1 = *(const short8*)&Xh[xoff + 8];
    pWh0 = *(const short8*)&Wh[woff];     pWh1 = *(const short8*)&Wh[woff + 8];
    if (!is_v) {
        pXl0 = *(const short8*)&Xl[xoff]; pXl1 = *(const short8*)&Xl[xoff + 8];
        pWl0 = *(const short8*)&Wl[woff]; pWl1 = *(const short8*)&Wl[woff + 8];
    }

    for (int e0 = 0; e0 < 1024; e0 += 32) {
        __syncthreads();
        *(short8*)&Ah[sd0] = pXh0; *(short8*)&Ah[sd1] = pXh1;
        *(short8*)&Bh[sd0] = pWh0; *(short8*)&Bh[sd1] = pWh1;
        if (!is_v) {
            *(short8*)&Al[sd0] = pXl0; *(short8*)&Al[sd1] = pXl1;
            *(short8*)&Bl[sd0] = pWl0; *(short8*)&Bl[sd1] = pWl1;
        }
        __syncthreads();

        if (e0 + 32 < 1024) {
            const size_t xo = xoff + e0 + 32, wo = woff + e0 + 32;
            pXh0 = *(const short8*)&Xh[xo];     pXh1 = *(const short8*)&Xh[xo + 8];
            pWh0 = *(const short8*)&Wh[wo];     pWh1 = *(const short8*)&Wh[wo + 8];
            if (!is_v) {
                pXl0 = *(const short8*)&Xl[xo]; pXl1 = *(const short8*)&Xl[xo + 8];
                pWl0 = *(const short8*)&Wl[wo]; pWl1 = *(const short8*)&Wl[wo + 8];
            }
        }

        short8 af[4], bfv[4], afl[4], bfl[4];
#pragma unroll
        for (int rb = 0; rb < 4; ++rb) {
            af[rb]  = *(const short8*)&Ah[fra + rb * 512];
            bfv[rb] = *(const short8*)&Bh[frb + rb * 512];
        }
#pragma unroll
        for (int rb = 0; rb < 4; ++rb)
#pragma unroll
            for (int cb = 0; cb < 4; ++cb)
                acc[rb][cb] = MFMA16(af[rb], bfv[cb], acc[rb][cb]);
        if (!is_v) {
#pragma unroll
            for (int rb = 0; rb < 4; ++rb) afl[rb] = *(const short8*)&Al[fra + rb * 512];
#pragma unroll
            for (int rb = 0; rb < 4; ++rb)
#pragma unroll
                for (int cb = 0; cb < 4; ++cb)
                    acc[rb][cb] = MFMA16(afl[rb], bfv[cb], acc[rb][cb]);
#pragma unroll
            for (int rb = 0; rb < 4; ++rb) bfl[rb] = *(const short8*)&Bl[frb + rb * 512];
#pragma unroll
            for (int rb = 0; rb < 4; ++rb)
#pragma unroll
                for (int cb = 0; cb < 4; ++cb)
                    acc[rb][cb] = MFMA16(af[rb], bfl[cb], acc[rb][cb]);
        }
    }

    const int p = bn >> 10;                       // 0=Q 1=K 2=V (block-uniform)
    unsigned short* __restrict__ yh = op.hi[p];
    unsigned short* __restrict__ yl = (p < 2) ? op.lo[p] : nullptr;
    const float* __restrict__ bp = op.bias[p];
    const float osc = op.osc[p];
    const int bnl = bn & 1023;

    const int r0 = (l >> 4) * 4;
    const int cc = l & 15;
#pragma unroll
    for (int rb = 0; rb < 4; ++rb)
#pragma unroll
        for (int cb = 0; cb < 4; ++cb) {
            const int col = bnl + wc + cb * 16 + cc;
            const float bv = bp[col];
#pragma unroll
            for (int r = 0; r < 4; ++r) {
                const int row = bm + wr + rb * 16 + r0 + r;
                const float v = (acc[rb][cb][r] + bv) * osc;
                const unsigned short hi = f2bf(v);
                yh[(size_t)row * 1024 + col] = hi;
                if (p < 2)
                    yl[(size_t)row * 1024 + col] = f2bf(v - bf2f(hi));
            }
        }
}

// ---------------------------------------------------------------------------
// Kernel 3b (R7 retile): output projection GEMM, 64x128 tile, 4 waves
// (2x2, each 32x64 = 2x4 frags), BK=32. grid (8, 64) = 512 blocks = 2/CU
// so barrier drains overlap across blocks (the 128^2 version ran 1/CU).
// ---------------------------------------------------------------------------
__global__ __launch_bounds__(256) void gemm_out_kernel(
    const unsigned short* __restrict__ Xh,
    const unsigned short* __restrict__ Wh,
    const float* __restrict__ bias,
    float* __restrict__ Yf)
{
    __shared__ unsigned short Ah[64 * 32];
    __shared__ unsigned short Bh[128 * 32];

    const int t = threadIdx.x;
    const int l = t & 63;
    const int w = t >> 6;
    const int wr = (w >> 1) * 32, wc = (w & 1) * 64;
    const int bm = blockIdx.y * 64, bn = blockIdx.x * 128;

    f32x4 acc[2][4];
#pragma unroll
    for (int i = 0; i < 2; ++i)
#pragma unroll
        for (int j = 0; j < 4; ++j) acc[i][j] = (f32x4){0.f, 0.f, 0.f, 0.f};

    // A staging: 64 rows x 4 chunks, 1 chunk/thread
    const int arow = t >> 2, ach = t & 3;
    const int asd  = arow * 32 + ((ach ^ ((arow >> 1) & 3)) << 3);
    const size_t xoff = (size_t)(bm + arow) * 1024 + ach * 8;
    // B staging: 128 rows x 2 chunks/thread
    const int brow = t >> 1, bch = (t & 1) * 2;
    const int bsel = (brow >> 1) & 3;
    const int bsd0 = brow * 32 + (((bch)     ^ bsel) << 3);
    const int bsd1 = brow * 32 + (((bch + 1) ^ bsel) << 3);
    const size_t woff = (size_t)(bn + brow) * 1024 + bch * 8;

    const int fsel = ((l & 15) >> 1) & 3;
    const int fpos = ((l >> 4) ^ fsel) << 3;
    const int fra  = (wr + (l & 15)) * 32 + fpos;
    const int frb  = (wc + (l & 15)) * 32 + fpos;

    short8 pA0, pB0, pB1;
    pA0 = *(const short8*)&Xh[xoff];
    pB0 = *(const short8*)&Wh[woff]; pB1 = *(const short8*)&Wh[woff + 8];

    for (int e0 = 0; e0 < 1024; e0 += 32) {
        __syncthreads();
        *(short8*)&Ah[asd]  = pA0;
        *(short8*)&Bh[bsd0] = pB0; *(short8*)&Bh[bsd1] = pB1;
        __syncthreads();

        if (e0 + 32 < 1024) {
            pA0 = *(const short8*)&Xh[xoff + e0 + 32];
            pB0 = *(const short8*)&Wh[woff + e0 + 32];
            pB1 = *(const short8*)&Wh[woff + e0 + 40];
        }

        short8 af[2], bfv[4];
#pragma unroll
        for (int rb = 0; rb < 2; ++rb) af[rb] = *(const short8*)&Ah[fra + rb * 512];
#pragma unroll
        for (int cb = 0; cb < 4; ++cb) bfv[cb] = *(const short8*)&Bh[frb + cb * 512];
#pragma unroll
        for (int rb = 0; rb < 2; ++rb)
#pragma unroll
            for (int cb = 0; cb < 4; ++cb)
                acc[rb][cb] = MFMA16(af[rb], bfv[cb], acc[rb][cb]);
    }

    const int r0 = (l >> 4) * 4;
    const int cc = l & 15;
#pragma unroll
    for (int rb = 0; rb < 2; ++rb)
#pragma unroll
        for (int cb = 0; cb < 4; ++cb) {
            const int col = bn + wc + cb * 16 + cc;
            const float bv = bias[col];
#pragma unroll
            for (int r = 0; r < 4; ++r) {
                const int row = bm + wr + rb * 16 + r0 + r;
                Yf[(size_t)row * 1024 + col] = acc[rb][cb][r] + bv;
            }
        }
}

// ---------------------------------------------------------------------------
// Kernel 4: 64x64 bf16 transpose: V [4096][1024] -> VT [1024][4096].
// ---------------------------------------------------------------------------
__global__ __launch_bounds__(256) void transpose_kernel(
    const unsigned short* __restrict__ V, unsigned short* __restrict__ VT)
{
    __shared__ unsigned short tile[64][65];
    const int t = threadIdx.x;
    const int c0 = blockIdx.x * 64;
    const int r0 = blockIdx.y * 64;
    {
        const int r = t >> 2;
        const int q = (t & 3) * 16;
        short8 v0 = *(const short8*)&V[(size_t)(r0 + r) * 1024 + c0 + q];
        short8 v1 = *(const short8*)&V[(size_t)(r0 + r) * 1024 + c0 + q + 8];
#pragma unroll
        for (int i = 0; i < 8; ++i) {
            tile[r][q + i]     = (unsigned short)v0[i];
            tile[r][q + 8 + i] = (unsigned short)v1[i];
        }
    }
    __syncthreads();
    {
        const int c = t >> 2;
        const int g = (t & 3) * 16;
        short8 out0, out1;
#pragma unroll
        for (int i = 0; i < 8; ++i) {
            out0[i] = (short)tile[g + i][c];
            out1[i] = (short)tile[g + 8 + i][c];
        }
        *(short8*)&VT[(size_t)(c0 + c) * 4096 + r0 + g]     = out0;
        *(short8*)&VT[(size_t)(c0 + c) * 4096 + r0 + g + 8] = out1;
    }
}

// ---------------------------------------------------------------------------
// Kernel 5: flash attention, 32x32 MFMA, swapped QK^T. (unchanged from R6)
// ---------------------------------------------------------------------------
__global__ __launch_bounds__(256) void attn_kernel(
    const unsigned short* __restrict__ Qh, const unsigned short* __restrict__ Ql,
    const unsigned short* __restrict__ Kh_g, const unsigned short* __restrict__ Kl_g,
    const unsigned short* __restrict__ VT, unsigned short* __restrict__ CTX)
{
    __shared__ unsigned short Khs[2][64 * 64];
    __shared__ unsigned short Kls[2][64 * 64];
    __shared__ unsigned short Vts[2][64 * 64];   // [d][k]

    const int t = threadIdx.x;
    const int l = t & 63;
    const int w = t >> 6;
    const int qt = blockIdx.x, h = blockIdx.y, b = blockIdx.z;
    const int lq = l & 31;
    const int hi = l >> 5;
    const int tokq = b * LQ + qt * 128 + w * 32;

    short8 qhf[4], qlf[4];
    {
        const size_t qr = (size_t)(tokq + lq) * 1024 + h * 64 + hi * 8;
#pragma unroll
        for (int ds = 0; ds < 4; ++ds) {
            qhf[ds] = *(const short8*)&Qh[qr + ds * 16];
            qlf[ds] = *(const short8*)&Ql[qr + ds * 16];
        }
    }

    f32x16 o0, o1;
#pragma unroll
    for (int i = 0; i < 16; ++i) { o0[i] = 0.f; o1[i] = 0.f; }
    float m = -1e30f, lsum = 0.f;

    const int srow = t >> 2;          // 0..63
    const int sch  = (t & 3) * 2;
    int sdst[2];
#pragma unroll
    for (int it = 0; it < 2; ++it)
        sdst[it] = srow * 64 + (((sch + it) ^ (srow & 7)) << 3);

    const unsigned short* pkh = Kh_g + (size_t)(b * LQ + srow) * 1024 + h * 64 + sch * 8;
    const unsigned short* pkl = Kl_g + (size_t)(b * LQ + srow) * 1024 + h * 64 + sch * 8;
    const unsigned short* pvt = VT + (size_t)(h * 64 + srow) * 4096 + b * LQ + sch * 8;

    short8 pf_kh[2], pf_kl[2], pf_vt[2];
    pf_kh[0] = *(const short8*)pkh;       pf_kh[1] = *(const short8*)(pkh + 8);
    pf_kl[0] = *(const short8*)pkl;       pf_kl[1] = *(const short8*)(pkl + 8);
    pf_vt[0] = *(const short8*)pvt;       pf_vt[1] = *(const short8*)(pvt + 8);

    const int lq7 = lq & 7;
    int qkoff[4], pvslot[4];
#pragma unroll
    for (int i = 0; i < 4; ++i) {
        qkoff[i]  = lq * 64 + (((2 * i + hi) ^ lq7) << 3);
        pvslot[i] = (((2 * i + hi) ^ lq7) << 3);
    }

    int cur = 0;
    for (int kt = 0; kt < 32; ++kt) {
#pragma unroll
        for (int it = 0; it < 2; ++it) {
            *(short8*)&Khs[cur][sdst[it]] = pf_kh[it];
            *(short8*)&Kls[cur][sdst[it]] = pf_kl[it];
            *(short8*)&Vts[cur][sdst[it]] = pf_vt[it];
        }
        if (kt < 31) {
            pkh += 64 * 1024; pkl += 64 * 1024; pvt += 64;
            pf_kh[0] = *(const short8*)pkh;  pf_kh[1] = *(const short8*)(pkh + 8);
            pf_kl[0] = *(const short8*)pkl;  pf_kl[1] = *(const short8*)(pkl + 8);
            pf_vt[0] = *(const short8*)pvt;  pf_vt[1] = *(const short8*)(pvt + 8);
        }
        __syncthreads();

        // ---- swapped QK^T (3-pass split): S'[key][q] ----
        f32x16 s0, s1;
#pragma unroll
        for (int i = 0; i < 16; ++i) { s0[i] = 0.f; s1[i] = 0.f; }
        __builtin_amdgcn_s_setprio(1);
#pragma unroll
        for (int ds = 0; ds < 4; ++ds) {
            const int off = qkoff[ds];
            short8 kh0 = *(const short8*)&Khs[cur][off];
            short8 kh1 = *(const short8*)&Khs[cur][off + 2048];
            short8 kl0 = *(const short8*)&Kls[cur][off];
            short8 kl1 = *(const short8*)&Kls[cur][off + 2048];
            s0 = MFMA32(kh0, qhf[ds], s0);
            s1 = MFMA32(kh1, qhf[ds], s1);
            s0 = MFMA32(kl0, qhf[ds], s0);
            s1 = MFMA32(kl1, qhf[ds], s1);
            s0 = MFMA32(kh0, qlf[ds], s0);
            s1 = MFMA32(kh1, qlf[ds], s1);
        }
        __builtin_amdgcn_s_setprio(0);

        // ---- lane-local online softmax (base 2), defer-max THR=8 ----
        float vm = fmaxf(fmaxf(s0[0], s0[1]), s0[2]);
#pragma unroll
        for (int i = 3; i < 15; i += 2) vm = fmaxf(fmaxf(s0[i], s0[i + 1]), vm);
        vm = fmaxf(fmaxf(s0[15], s1[0]), vm);
#pragma unroll
        for (int i = 1; i < 15; i += 2) vm = fmaxf(fmaxf(s1[i], s1[i + 1]), vm);
        vm = fmaxf(s1[15], vm);
        vm = fmaxf(vm, __shfl_xor(vm, 32));
        const float mg = fmaxf(m, vm);
        if (__any(mg > m + 8.f)) {
            const float mu = (mg > m + 8.f) ? mg : m;
            const float alpha = fast_exp2(m - mu);
            lsum *= alpha;
            o0 *= alpha;
            o1 *= alpha;
            m = mu;
        }
        float ps = 0.f;
#pragma unroll
        for (int i = 0; i < 16; ++i) { s0[i] = fast_exp2(s0[i] - m); ps += s0[i]; }
#pragma unroll
        for (int i = 0; i < 16; ++i) { s1[i] = fast_exp2(s1[i] - m); ps += s1[i]; }
        lsum += ps;

        // ---- pack P into PV B-fragments (cvt_pk + permlane32_swap) ----
        unsigned int pw[4][4];
        {
            unsigned int a, bb;
            a = cvtpk_bf16(s0[0], s0[1]); bb = cvtpk_bf16(s0[4], s0[5]);
            permswap(a, bb); pw[0][0] = a; pw[0][2] = bb;
            a = cvtpk_bf16(s0[2], s0[3]); bb = cvtpk_bf16(s0[6], s0[7]);
            permswap(a, bb); pw[0][1] = a; pw[0][3] = bb;
            a = cvtpk_bf16(s0[8], s0[9]); bb = cvtpk_bf16(s0[12], s0[13]);
            permswap(a, bb); pw[1][0] = a; pw[1][2] = bb;
            a = cvtpk_bf16(s0[10], s0[11]); bb = cvtpk_bf16(s0[14], s0[15]);
            permswap(a, bb); pw[1][1] = a; pw[1][3] = bb;
            a = cvtpk_bf16(s1[0], s1[1]); bb = cvtpk_bf16(s1[4], s1[5]);
            permswap(a, bb); pw[2][0] = a; pw[2][2] = bb;
            a = cvtpk_bf16(s1[2], s1[3]); bb = cvtpk_bf16(s1[6], s1[7]);
            permswap(a, bb); pw[2][1] = a; pw[2][3] = bb;
            a = cvtpk_bf16(s1[8], s1[9]); bb = cvtpk_bf16(s1[12], s1[13]);
            permswap(a, bb); pw[3][0] = a; pw[3][2] = bb;
            a = cvtpk_bf16(s1[10], s1[11]); bb = cvtpk_bf16(s1[14], s1[15]);
            permswap(a, bb); pw[3][1] = a; pw[3][3] = bb;
        }

        // ---- PV: O^T += V^T-frag x P-frag ----
        __builtin_amdgcn_s_setprio(1);
#pragma unroll
        for (int ks = 0; ks < 4; ++ks) {
            union { unsigned int u[4]; short8 v; } pa;
            pa.u[0] = pw[ks][0]; pa.u[1] = pw[ks][1];
            pa.u[2] = pw[ks][2]; pa.u[3] = pw[ks][3];
            const int slot = pvslot[ks];
            short8 v0 = *(const short8*)&Vts[cur][lq * 64 + slot];
            short8 v1 = *(const short8*)&Vts[cur][(32 + lq) * 64 + slot];
            o0 = MFMA32(v0, pa.v, o0);
            o1 = MFMA32(v1, pa.v, o1);
        }
        __builtin_amdgcn_s_setprio(0);
        cur ^= 1;
    }

    // ---- finalize ----
    lsum += __shfl_xor(lsum, 32);
    const float inv = 1.f / lsum;
    const size_t orow = (size_t)(tokq + lq) * 1024 + h * 64 + hi * 4;
#pragma unroll
    for (int g = 0; g < 4; ++g) {
        u16x4 pack0, pack1;
#pragma unroll
        for (int j = 0; j < 4; ++j) {
            pack0[j] = f2bf(o0[4 * g + j] * inv);
            pack1[j] = f2bf(o1[4 * g + j] * inv);
        }
        *(u16x4*)&CTX[orow + 8 * g]      = pack0;
        *(u16x4*)&CTX[orow + 32 + 8 * g] = pack1;
    }
}

// ---------------------------------------------------------------------------
extern "C" void kernel_launch(void* const* d_in, const int* in_sizes, int n_in,
                              void* d_out, int out_size, void* d_ws, size_t ws_size,
                              hipStream_t stream)
{
    (void)in_sizes; (void)n_in; (void)out_size; (void)ws_size;
    const float* query = (const float*)d_in[0];
    char* base = (char*)d_ws;
    const size_t MB = 1 << 20;
    unsigned short* Whi = (unsigned short*)(base + 0 * MB);
    unsigned short* Wlo = (unsigned short*)(base + 8 * MB);
    unsigned short* Xhi = (unsigned short*)(base + 16 * MB);
    unsigned short* Xlo = (unsigned short*)(base + 24 * MB);
    unsigned short* Qhi = (unsigned short*)(base + 32 * MB);
    unsigned short* Qlo = (unsigned short*)(base + 40 * MB);
    unsigned short* Khi = (unsigned short*)(base + 48 * MB);
    unsigned short* Klo = (unsigned short*)(base + 56 * MB);
    unsigned short* Vh  = (unsigned short*)(base + 64 * MB);
    unsigned short* VTp = (unsigned short*)(base + 72 * MB);
    unsigned short* CTX = (unsigned short*)(base + 16 * MB);   // reuse X region

    CorePtrs cp;
    for (int p = 0; p < 4; ++p) {
        cp.c0[p] = (const float*)d_in[1 + 4 * p];
        cp.c1[p] = (const float*)d_in[2 + 4 * p];
        cp.c2[p] = (const float*)d_in[3 + 4 * p];
    }
    const size_t WSZ = (size_t)1024 * 1024;
    const float QSCALE = 0.125f * 1.44269504088896340736f;   // fold log2(e)

    build_w_kernel<<<dim3(64, 4), 256, 0, stream>>>(cp, Whi, Wlo);
    convert_x_kernel<<<4096, 256, 0, stream>>>(query, Xhi, Xlo, 1048576);

    QkvOut op;
    op.hi[0] = Qhi; op.hi[1] = Khi; op.hi[2] = Vh;
    op.lo[0] = Qlo; op.lo[1] = Klo;
    op.bias[0] = (const float*)d_in[4];
    op.bias[1] = (const float*)d_in[8];
    op.bias[2] = (const float*)d_in[12];
    op.osc[0] = QSCALE; op.osc[1] = 1.0f; op.osc[2] = 1.0f;

    gemm_qkv_kernel<<<dim3(24, 32), 256, 0, stream>>>(Xhi, Xlo, Whi, Wlo, op);

    transpose_kernel<<<dim3(16, 64), 256, 0, stream>>>(Vh, VTp);

    attn_kernel<<<dim3(16, 16, 2), 256, 0, stream>>>(Qhi, Qlo, Khi, Klo, VTp, CTX);

    gemm_out_kernel<<<dim3(8, 64), 256, 0, stream>>>(
        CTX, Whi + 3 * WSZ, (const float*)d_in[16], (float*)d_out);
}

// Round 9
// 275.053 us; speedup vs baseline: 4.3162x; 1.0372x over previous
//
#include <hip/hip_runtime.h>
#include <hip/hip_bf16.h>
#include <stdint.h>

#define LQ 2048
#define NTOK 4096

typedef __attribute__((ext_vector_type(8))) short short8;
typedef __attribute__((ext_vector_type(4))) float f32x4;
typedef __attribute__((ext_vector_type(16))) float f32x16;
typedef __attribute__((ext_vector_type(4))) unsigned short u16x4;

#define MFMA16(a, b, c) __builtin_amdgcn_mfma_f32_16x16x32_bf16((a), (b), (c), 0, 0, 0)
#define MFMA32(a, b, c) __builtin_amdgcn_mfma_f32_32x32x16_bf16((a), (b), (c), 0, 0, 0)

__device__ __forceinline__ unsigned short f2bf(float x) {
    union { __hip_bfloat16 b; unsigned short u; } v;
    v.b = __float2bfloat16(x);
    return v.u;
}
__device__ __forceinline__ float bf2f(unsigned short h) {
    union { uint32_t u; float f; } v; v.u = ((uint32_t)h) << 16; return v.f;
}
__device__ __forceinline__ unsigned int cvtpk_bf16(float lo, float hi_) {
    unsigned int r;
    asm("v_cvt_pk_bf16_f32 %0, %1, %2" : "=v"(r) : "v"(lo), "v"(hi_));
    return r;
}
__device__ __forceinline__ void permswap(unsigned int &a, unsigned int &b) {
    asm("v_permlane32_swap_b32 %0, %1" : "+v"(a), "+v"(b));
}
__device__ __forceinline__ float fast_exp2(float x) {
    float r;
    asm("v_exp_f32 %0, %1" : "=v"(r) : "v"(x));
    return r;
}

struct CorePtrs {
    const float* c0[4];
    const float* c1[4];
    const float* c2[4];
};

struct QkvOut {
    unsigned short* qhi;
    unsigned short* qlo;
    unsigned short* khi;
    unsigned short* klo;
    unsigned short* vt;          // [1024][4096] transposed V
    const float* bias[3];
    float qscale;
};

// ---------------------------------------------------------------------------
// Kernel 1 (R8 merged): blocks 0..255 materialize W hi/lo (4 projections);
// blocks 256..4351 split the input activations fp32 -> bf16 hi/lo.
// ---------------------------------------------------------------------------
__global__ __launch_bounds__(256) void prep_kernel(
    CorePtrs cp, unsigned short* __restrict__ Whi, unsigned short* __restrict__ Wlo,
    const float* __restrict__ X, unsigned short* __restrict__ Xhi,
    unsigned short* __restrict__ Xlo)
{
    const int blk = blockIdx.x;
    const int t = threadIdx.x;
    if (blk >= 256) {
        // ---- convert_x part ----
        const int i = (blk - 256) * 256 + t;
        const float4 v = ((const float4*)X)[i];
        u16x4 hi, lo;
        float vv[4] = {v.x, v.y, v.z, v.w};
#pragma unroll
        for (int j = 0; j < 4; ++j) {
            unsigned short h = f2bf(vv[j]);
            hi[j] = h;
            lo[j] = f2bf(vv[j] - bf2f(h));
        }
        ((u16x4*)Xhi)[i] = hi;
        ((u16x4*)Xlo)[i] = lo;
        return;
    }
    // ---- build_w part ----
    __shared__ float B1[16 * 16 * 16];   // [i1][q1][s2]
    const int p  = blk >> 6;
    const int i0 = (blk & 63) >> 3;
    const int q0 = blk & 7;
    const float* __restrict__ c0 = cp.c0[p];
    const float* __restrict__ c1 = cp.c1[p];
    const float* __restrict__ c2 = cp.c2[p];

    float g0[16];
#pragma unroll
    for (int s = 0; s < 16; ++s) g0[s] = c0[(i0 * 8 + q0) * 16 + s];

    for (int idx = t; idx < 4096; idx += 256) {
        const int s2 = idx & 15;
        const int q1 = (idx >> 4) & 15;
        const int i1 = idx >> 8;
        float acc = 0.f;
#pragma unroll
        for (int s = 0; s < 16; ++s)
            acc += g0[s] * c1[((s * 16 + i1) * 16 + q1) * 16 + s2];
        B1[idx] = acc;
    }
    __syncthreads();

    const size_t base = (size_t)p * 1024 * 1024;
    for (int idx = t; idx < 16384; idx += 256) {
        const int q2 = idx & 7;
        const int i2 = (idx >> 3) & 7;
        const int q1 = (idx >> 6) & 15;
        const int i1 = idx >> 10;
        float acc = 0.f;
#pragma unroll
        for (int s2 = 0; s2 < 16; ++s2)
            acc += B1[(i1 * 16 + q1) * 16 + s2] * c2[(s2 * 8 + i2) * 8 + q2];
        const int o = q0 * 128 + q1 * 8 + q2;
        const int e = i0 * 128 + i1 * 8 + i2;
        const unsigned short hi = f2bf(acc);
        Whi[base + o * 1024 + e] = hi;
        Wlo[base + o * 1024 + e] = f2bf(acc - bf2f(hi));
    }
}

// ---------------------------------------------------------------------------
// Kernel 2: FUSED QKV split GEMM over N=3072.
// Q/K blocks: 3-pass hi/lo, bf16 hi/lo outputs. V blocks (bn>>10==2): hi pass
// only, and the epilogue writes V TRANSPOSED (VT[col][row]) directly — the
// separate transpose kernel and the Vh buffer are gone (R8).
// ---------------------------------------------------------------------------
__global__ __launch_bounds__(256) void gemm_qkv_kernel(
    const unsigned short* __restrict__ Xh, const unsigned short* __restrict__ Xl,
    const unsigned short* __restrict__ Wh, const unsigned short* __restrict__ Wl,
    QkvOut op)
{
    __shared__ unsigned short Ah[128 * 32];
    __shared__ unsigned short Bh[128 * 32];
    __shared__ unsigned short Al[128 * 32];
    __shared__ unsigned short Bl[128 * 32];

    const int t = threadIdx.x;
    const int l = t & 63;
    const int w = t >> 6;
    const int wr = (w >> 1) * 64, wc = (w & 1) * 64;
    const int bm = blockIdx.y * 128, bn = blockIdx.x * 128;
    const bool is_v = (bn >> 10) == 2;     // block-uniform

    f32x4 acc[4][4];
#pragma unroll
    for (int i = 0; i < 4; ++i)
#pragma unroll
        for (int j = 0; j < 4; ++j) acc[i][j] = (f32x4){0.f, 0.f, 0.f, 0.f};

    const int srow = t >> 1;
    const int sch  = (t & 1) * 2;
    const int ssel = (srow >> 1) & 3;
    const int sd0  = srow * 32 + (((sch)     ^ ssel) << 3);
    const int sd1  = srow * 32 + (((sch + 1) ^ ssel) << 3);
    const size_t xoff = (size_t)(bm + srow) * 1024 + sch * 8;
    const size_t woff = (size_t)(bn + srow) * 1024 + sch * 8;

    const int fsel = ((l & 15) >> 1) & 3;
    const int fpos = ((l >> 4) ^ fsel) << 3;
    const int fra  = (wr + (l & 15)) * 32 + fpos;
    const int frb  = (wc + (l & 15)) * 32 + fpos;

    short8 pXh0, pXh1, pWh0, pWh1, pXl0, pXl1, pWl0, pWl1;
    pXh0 = *(const short8*)&Xh[xoff];     pXh1 = *(const short8*)&Xh[xoff + 8];
    pWh0 = *(const short8*)&Wh[woff];     pWh1 = *(const short8*)&Wh[woff + 8];
    if (!is_v) {
        pXl0 = *(const short8*)&Xl[xoff]; pXl1 = *(const short8*)&Xl[xoff + 8];
        pWl0 = *(const short8*)&Wl[woff]; pWl1 = *(const short8*)&Wl[woff + 8];
    }

    for (int e0 = 0; e0 < 1024; e0 += 32) {
        __syncthreads();
        *(short8*)&Ah[sd0] = pXh0; *(short8*)&Ah[sd1] = pXh1;
        *(short8*)&Bh[sd0] = pWh0; *(short8*)&Bh[sd1] = pWh1;
        if (!is_v) {
            *(short8*)&Al[sd0] = pXl0; *(short8*)&Al[sd1] = pXl1;
            *(short8*)&Bl[sd0] = pWl0; *(short8*)&Bl[sd1] = pWl1;
        }
        __syncthreads();

        if (e0 + 32 < 1024) {
            const size_t xo = xoff + e0 + 32, wo = woff + e0 + 32;
            pXh0 = *(const short8*)&Xh[xo];     pXh1 = *(const short8*)&Xh[xo + 8];
            pWh0 = *(const short8*)&Wh[wo];     pWh1 = *(const short8*)&Wh[wo + 8];
            if (!is_v) {
                pXl0 = *(const short8*)&Xl[xo]; pXl1 = *(const short8*)&Xl[xo + 8];
                pWl0 = *(const short8*)&Wl[wo]; pWl1 = *(const short8*)&Wl[wo + 8];
            }
        }

        short8 af[4], bfv[4], afl[4], bfl[4];
#pragma unroll
        for (int rb = 0; rb < 4; ++rb) {
            af[rb]  = *(const short8*)&Ah[fra + rb * 512];
            bfv[rb] = *(const short8*)&Bh[frb + rb * 512];
        }
#pragma unroll
        for (int rb = 0; rb < 4; ++rb)
#pragma unroll
            for (int cb = 0; cb < 4; ++cb)
                acc[rb][cb] = MFMA16(af[rb], bfv[cb], acc[rb][cb]);
        if (!is_v) {
#pragma unroll
            for (int rb = 0; rb < 4; ++rb) afl[rb] = *(const short8*)&Al[fra + rb * 512];
#pragma unroll
            for (int rb = 0; rb < 4; ++rb)
#pragma unroll
                for (int cb = 0; cb < 4; ++cb)
                    acc[rb][cb] = MFMA16(afl[rb], bfv[cb], acc[rb][cb]);
#pragma unroll
            for (int rb = 0; rb < 4; ++rb) bfl[rb] = *(const short8*)&Bl[frb + rb * 512];
#pragma unroll
            for (int rb = 0; rb < 4; ++rb)
#pragma unroll
                for (int cb = 0; cb < 4; ++cb)
                    acc[rb][cb] = MFMA16(af[rb], bfl[cb], acc[rb][cb]);
        }
    }

    const int p = bn >> 10;                       // 0=Q 1=K 2=V (block-uniform)
    const float* __restrict__ bp = op.bias[p];
    const int bnl = bn & 1023;
    const int r0 = (l >> 4) * 4;
    const int cc = l & 15;

    if (p < 2) {
        unsigned short* __restrict__ yh = (p == 0) ? op.qhi : op.khi;
        unsigned short* __restrict__ yl = (p == 0) ? op.qlo : op.klo;
        const float osc = (p == 0) ? op.qscale : 1.0f;
#pragma unroll
        for (int rb = 0; rb < 4; ++rb)
#pragma unroll
            for (int cb = 0; cb < 4; ++cb) {
                const int col = bnl + wc + cb * 16 + cc;
                const float bv = bp[col];
#pragma unroll
                for (int r = 0; r < 4; ++r) {
                    const int row = bm + wr + rb * 16 + r0 + r;
                    const float v = (acc[rb][cb][r] + bv) * osc;
                    const unsigned short hi = f2bf(v);
                    yh[(size_t)row * 1024 + col] = hi;
                    yl[(size_t)row * 1024 + col] = f2bf(v - bf2f(hi));
                }
            }
    } else {
        // V: write transposed directly. Each lane holds 4 consecutive rows
        // (tokens) per (rb,cb) -> one 8B u16x4 store at VT[col][row0..3].
        unsigned short* __restrict__ vt = op.vt;
#pragma unroll
        for (int rb = 0; rb < 4; ++rb)
#pragma unroll
            for (int cb = 0; cb < 4; ++cb) {
                const int col = bnl + wc + cb * 16 + cc;
                const float bv = bp[col];
                u16x4 pk;
#pragma unroll
                for (int r = 0; r < 4; ++r)
                    pk[r] = f2bf(acc[rb][cb][r] + bv);
                const int row0 = bm + wr + rb * 16 + r0;
                *(u16x4*)&vt[(size_t)col * 4096 + row0] = pk;
            }
    }
}

// ---------------------------------------------------------------------------
// Kernel 3: output projection GEMM, 64x128 tile, grid (8,64)=512 blocks.
// ---------------------------------------------------------------------------
__global__ __launch_bounds__(256) void gemm_out_kernel(
    const unsigned short* __restrict__ Xh,
    const unsigned short* __restrict__ Wh,
    const float* __restrict__ bias,
    float* __restrict__ Yf)
{
    __shared__ unsigned short Ah[64 * 32];
    __shared__ unsigned short Bh[128 * 32];

    const int t = threadIdx.x;
    const int l = t & 63;
    const int w = t >> 6;
    const int wr = (w >> 1) * 32, wc = (w & 1) * 64;
    const int bm = blockIdx.y * 64, bn = blockIdx.x * 128;

    f32x4 acc[2][4];
#pragma unroll
    for (int i = 0; i < 2; ++i)
#pragma unroll
        for (int j = 0; j < 4; ++j) acc[i][j] = (f32x4){0.f, 0.f, 0.f, 0.f};

    const int arow = t >> 2, ach = t & 3;
    const int asd  = arow * 32 + ((ach ^ ((arow >> 1) & 3)) << 3);
    const size_t xoff = (size_t)(bm + arow) * 1024 + ach * 8;
    const int brow = t >> 1, bch = (t & 1) * 2;
    const int bsel = (brow >> 1) & 3;
    const int bsd0 = brow * 32 + (((bch)     ^ bsel) << 3);
    const int bsd1 = brow * 32 + (((bch + 1) ^ bsel) << 3);
    const size_t woff = (size_t)(bn + brow) * 1024 + bch * 8;

    const int fsel = ((l & 15) >> 1) & 3;
    const int fpos = ((l >> 4) ^ fsel) << 3;
    const int fra  = (wr + (l & 15)) * 32 + fpos;
    const int frb  = (wc + (l & 15)) * 32 + fpos;

    short8 pA0, pB0, pB1;
    pA0 = *(const short8*)&Xh[xoff];
    pB0 = *(const short8*)&Wh[woff]; pB1 = *(const short8*)&Wh[woff + 8];

    for (int e0 = 0; e0 < 1024; e0 += 32) {
        __syncthreads();
        *(short8*)&Ah[asd]  = pA0;
        *(short8*)&Bh[bsd0] = pB0; *(short8*)&Bh[bsd1] = pB1;
        __syncthreads();

        if (e0 + 32 < 1024) {
            pA0 = *(const short8*)&Xh[xoff + e0 + 32];
            pB0 = *(const short8*)&Wh[woff + e0 + 32];
            pB1 = *(const short8*)&Wh[woff + e0 + 40];
        }

        short8 af[2], bfv[4];
#pragma unroll
        for (int rb = 0; rb < 2; ++rb) af[rb] = *(const short8*)&Ah[fra + rb * 512];
#pragma unroll
        for (int cb = 0; cb < 4; ++cb) bfv[cb] = *(const short8*)&Bh[frb + cb * 512];
#pragma unroll
        for (int rb = 0; rb < 2; ++rb)
#pragma unroll
            for (int cb = 0; cb < 4; ++cb)
                acc[rb][cb] = MFMA16(af[rb], bfv[cb], acc[rb][cb]);
    }

    const int r0 = (l >> 4) * 4;
    const int cc = l & 15;
#pragma unroll
    for (int rb = 0; rb < 2; ++rb)
#pragma unroll
        for (int cb = 0; cb < 4; ++cb) {
            const int col = bn + wc + cb * 16 + cc;
            const float bv = bias[col];
#pragma unroll
            for (int r = 0; r < 4; ++r) {
                const int row = bm + wr + rb * 16 + r0 + r;
                Yf[(size_t)row * 1024 + col] = acc[rb][cb][r] + bv;
            }
        }
}

// ---------------------------------------------------------------------------
// Kernel 4: flash attention, 32x32 MFMA, swapped QK^T.
// R8: reduction chains broken into 4 interleaved partials (no fast-math
// reassociation otherwise).
// ---------------------------------------------------------------------------
__global__ __launch_bounds__(256) void attn_kernel(
    const unsigned short* __restrict__ Qh, const unsigned short* __restrict__ Ql,
    const unsigned short* __restrict__ Kh_g, const unsigned short* __restrict__ Kl_g,
    const unsigned short* __restrict__ VT, unsigned short* __restrict__ CTX)
{
    __shared__ unsigned short Khs[2][64 * 64];
    __shared__ unsigned short Kls[2][64 * 64];
    __shared__ unsigned short Vts[2][64 * 64];   // [d][k]

    const int t = threadIdx.x;
    const int l = t & 63;
    const int w = t >> 6;
    const int qt = blockIdx.x, h = blockIdx.y, b = blockIdx.z;
    const int lq = l & 31;
    const int hi = l >> 5;
    const int tokq = b * LQ + qt * 128 + w * 32;

    short8 qhf[4], qlf[4];
    {
        const size_t qr = (size_t)(tokq + lq) * 1024 + h * 64 + hi * 8;
#pragma unroll
        for (int ds = 0; ds < 4; ++ds) {
            qhf[ds] = *(const short8*)&Qh[qr + ds * 16];
            qlf[ds] = *(const short8*)&Ql[qr + ds * 16];
        }
    }

    f32x16 o0, o1;
#pragma unroll
    for (int i = 0; i < 16; ++i) { o0[i] = 0.f; o1[i] = 0.f; }
    float m = -1e30f, lsum = 0.f;

    const int srow = t >> 2;          // 0..63
    const int sch  = (t & 3) * 2;
    int sdst[2];
#pragma unroll
    for (int it = 0; it < 2; ++it)
        sdst[it] = srow * 64 + (((sch + it) ^ (srow & 7)) << 3);

    const unsigned short* pkh = Kh_g + (size_t)(b * LQ + srow) * 1024 + h * 64 + sch * 8;
    const unsigned short* pkl = Kl_g + (size_t)(b * LQ + srow) * 1024 + h * 64 + sch * 8;
    const unsigned short* pvt = VT + (size_t)(h * 64 + srow) * 4096 + b * LQ + sch * 8;

    short8 pf_kh[2], pf_kl[2], pf_vt[2];
    pf_kh[0] = *(const short8*)pkh;       pf_kh[1] = *(const short8*)(pkh + 8);
    pf_kl[0] = *(const short8*)pkl;       pf_kl[1] = *(const short8*)(pkl + 8);
    pf_vt[0] = *(const short8*)pvt;       pf_vt[1] = *(const short8*)(pvt + 8);

    const int lq7 = lq & 7;
    int qkoff[4], pvslot[4];
#pragma unroll
    for (int i = 0; i < 4; ++i) {
        qkoff[i]  = lq * 64 + (((2 * i + hi) ^ lq7) << 3);
        pvslot[i] = (((2 * i + hi) ^ lq7) << 3);
    }

    int cur = 0;
    for (int kt = 0; kt < 32; ++kt) {
#pragma unroll
        for (int it = 0; it < 2; ++it) {
            *(short8*)&Khs[cur][sdst[it]] = pf_kh[it];
            *(short8*)&Kls[cur][sdst[it]] = pf_kl[it];
            *(short8*)&Vts[cur][sdst[it]] = pf_vt[it];
        }
        if (kt < 31) {
            pkh += 64 * 1024; pkl += 64 * 1024; pvt += 64;
            pf_kh[0] = *(const short8*)pkh;  pf_kh[1] = *(const short8*)(pkh + 8);
            pf_kl[0] = *(const short8*)pkl;  pf_kl[1] = *(const short8*)(pkl + 8);
            pf_vt[0] = *(const short8*)pvt;  pf_vt[1] = *(const short8*)(pvt + 8);
        }
        __syncthreads();

        // ---- swapped QK^T (3-pass split): S'[key][q] ----
        f32x16 s0, s1;
#pragma unroll
        for (int i = 0; i < 16; ++i) { s0[i] = 0.f; s1[i] = 0.f; }
        __builtin_amdgcn_s_setprio(1);
#pragma unroll
        for (int ds = 0; ds < 4; ++ds) {
            const int off = qkoff[ds];
            short8 kh0 = *(const short8*)&Khs[cur][off];
            short8 kh1 = *(const short8*)&Khs[cur][off + 2048];
            short8 kl0 = *(const short8*)&Kls[cur][off];
            short8 kl1 = *(const short8*)&Kls[cur][off + 2048];
            s0 = MFMA32(kh0, qhf[ds], s0);
            s1 = MFMA32(kh1, qhf[ds], s1);
            s0 = MFMA32(kl0, qhf[ds], s0);
            s1 = MFMA32(kl1, qhf[ds], s1);
            s0 = MFMA32(kh0, qlf[ds], s0);
            s1 = MFMA32(kh1, qlf[ds], s1);
        }
        __builtin_amdgcn_s_setprio(0);

        // ---- lane-local online softmax (base 2), defer-max THR=8 ----
        float v0 = fmaxf(s0[0], s0[1]), v1 = fmaxf(s0[2], s0[3]);
        float v2 = fmaxf(s0[4], s0[5]), v3 = fmaxf(s0[6], s0[7]);
#pragma unroll
        for (int i = 8; i < 16; i += 4) {
            v0 = fmaxf(v0, fmaxf(s0[i], s0[i + 1]));
            v1 = fmaxf(v1, fmaxf(s0[i + 2], s0[i + 3]));
        }
#pragma unroll
        for (int i = 0; i < 16; i += 4) {
            v2 = fmaxf(v2, fmaxf(s1[i], s1[i + 1]));
            v3 = fmaxf(v3, fmaxf(s1[i + 2], s1[i + 3]));
        }
        float vm = fmaxf(fmaxf(v0, v1), fmaxf(v2, v3));
        vm = fmaxf(vm, __shfl_xor(vm, 32));
        const float mg = fmaxf(m, vm);
        if (__any(mg > m + 8.f)) {
            const float mu = (mg > m + 8.f) ? mg : m;
            const float alpha = fast_exp2(m - mu);
            lsum *= alpha;
            o0 *= alpha;
            o1 *= alpha;
            m = mu;
        }
        float p0 = 0.f, p1 = 0.f, p2 = 0.f, p3 = 0.f;
#pragma unroll
        for (int i = 0; i < 16; i += 4) {
            s0[i]     = fast_exp2(s0[i] - m);     p0 += s0[i];
            s0[i + 1] = fast_exp2(s0[i + 1] - m); p1 += s0[i + 1];
            s0[i + 2] = fast_exp2(s0[i + 2] - m); p2 += s0[i + 2];
            s0[i + 3] = fast_exp2(s0[i + 3] - m); p3 += s0[i + 3];
        }
#pragma unroll
        for (int i = 0; i < 16; i += 4) {
            s1[i]     = fast_exp2(s1[i] - m);     p0 += s1[i];
            s1[i + 1] = fast_exp2(s1[i + 1] - m); p1 += s1[i + 1];
            s1[i + 2] = fast_exp2(s1[i + 2] - m); p2 += s1[i + 2];
            s1[i + 3] = fast_exp2(s1[i + 3] - m); p3 += s1[i + 3];
        }
        lsum += (p0 + p1) + (p2 + p3);

        // ---- pack P into PV B-fragments (cvt_pk + permlane32_swap) ----
        unsigned int pw[4][4];
        {
            unsigned int a, bb;
            a = cvtpk_bf16(s0[0], s0[1]); bb = cvtpk_bf16(s0[4], s0[5]);
            permswap(a, bb); pw[0][0] = a; pw[0][2] = bb;
            a = cvtpk_bf16(s0[2], s0[3]); bb = cvtpk_bf16(s0[6], s0[7]);
            permswap(a, bb); pw[0][1] = a; pw[0][3] = bb;
            a = cvtpk_bf16(s0[8], s0[9]); bb = cvtpk_bf16(s0[12], s0[13]);
            permswap(a, bb); pw[1][0] = a; pw[1][2] = bb;
            a = cvtpk_bf16(s0[10], s0[11]); bb = cvtpk_bf16(s0[14], s0[15]);
            permswap(a, bb); pw[1][1] = a; pw[1][3] = bb;
            a = cvtpk_bf16(s1[0], s1[1]); bb = cvtpk_bf16(s1[4], s1[5]);
            permswap(a, bb); pw[2][0] = a; pw[2][2] = bb;
            a = cvtpk_bf16(s1[2], s1[3]); bb = cvtpk_bf16(s1[6], s1[7]);
            permswap(a, bb); pw[2][1] = a; pw[2][3] = bb;
            a = cvtpk_bf16(s1[8], s1[9]); bb = cvtpk_bf16(s1[12], s1[13]);
            permswap(a, bb); pw[3][0] = a; pw[3][2] = bb;
            a = cvtpk_bf16(s1[10], s1[11]); bb = cvtpk_bf16(s1[14], s1[15]);
            permswap(a, bb); pw[3][1] = a; pw[3][3] = bb;
        }

        // ---- PV: O^T += V^T-frag x P-frag ----
        __builtin_amdgcn_s_setprio(1);
#pragma unroll
        for (int ks = 0; ks < 4; ++ks) {
            union { unsigned int u[4]; short8 v; } pa;
            pa.u[0] = pw[ks][0]; pa.u[1] = pw[ks][1];
            pa.u[2] = pw[ks][2]; pa.u[3] = pw[ks][3];
            const int slot = pvslot[ks];
            short8 va = *(const short8*)&Vts[cur][lq * 64 + slot];
            short8 vb = *(const short8*)&Vts[cur][(32 + lq) * 64 + slot];
            o0 = MFMA32(va, pa.v, o0);
            o1 = MFMA32(vb, pa.v, o1);
        }
        __builtin_amdgcn_s_setprio(0);
        cur ^= 1;
    }

    // ---- finalize ----
    lsum += __shfl_xor(lsum, 32);
    const float inv = 1.f / lsum;
    const size_t orow = (size_t)(tokq + lq) * 1024 + h * 64 + hi * 4;
#pragma unroll
    for (int g = 0; g < 4; ++g) {
        u16x4 pack0, pack1;
#pragma unroll
        for (int j = 0; j < 4; ++j) {
            pack0[j] = f2bf(o0[4 * g + j] * inv);
            pack1[j] = f2bf(o1[4 * g + j] * inv);
        }
        *(u16x4*)&CTX[orow + 8 * g]      = pack0;
        *(u16x4*)&CTX[orow + 32 + 8 * g] = pack1;
    }
}

// ---------------------------------------------------------------------------
extern "C" void kernel_launch(void* const* d_in, const int* in_sizes, int n_in,
                              void* d_out, int out_size, void* d_ws, size_t ws_size,
                              hipStream_t stream)
{
    (void)in_sizes; (void)n_in; (void)out_size; (void)ws_size;
    const float* query = (const float*)d_in[0];
    char* base = (char*)d_ws;
    const size_t MB = 1 << 20;
    unsigned short* Whi = (unsigned short*)(base + 0 * MB);
    unsigned short* Wlo = (unsigned short*)(base + 8 * MB);
    unsigned short* Xhi = (unsigned short*)(base + 16 * MB);
    unsigned short* Xlo = (unsigned short*)(base + 24 * MB);
    unsigned short* Qhi = (unsigned short*)(base + 32 * MB);
    unsigned short* Qlo = (unsigned short*)(base + 40 * MB);
    unsigned short* Khi = (unsigned short*)(base + 48 * MB);
    unsigned short* Klo = (unsigned short*)(base + 56 * MB);
    unsigned short* VTp = (unsigned short*)(base + 72 * MB);
    unsigned short* CTX = (unsigned short*)(base + 16 * MB);   // reuse X region

    CorePtrs cp;
    for (int p = 0; p < 4; ++p) {
        cp.c0[p] = (const float*)d_in[1 + 4 * p];
        cp.c1[p] = (const float*)d_in[2 + 4 * p];
        cp.c2[p] = (const float*)d_in[3 + 4 * p];
    }
    const size_t WSZ = (size_t)1024 * 1024;
    const float QSCALE = 0.125f * 1.44269504088896340736f;   // fold log2(e)

    // 1) W materialization + X split, one launch (block-uniform branch)
    prep_kernel<<<4352, 256, 0, stream>>>(cp, Whi, Wlo, query, Xhi, Xlo);

    // 2) fused QKV (V written pre-transposed)
    QkvOut op;
    op.qhi = Qhi; op.qlo = Qlo; op.khi = Khi; op.klo = Klo; op.vt = VTp;
    op.bias[0] = (const float*)d_in[4];
    op.bias[1] = (const float*)d_in[8];
    op.bias[2] = (const float*)d_in[12];
    op.qscale = QSCALE;
    gemm_qkv_kernel<<<dim3(24, 32), 256, 0, stream>>>(Xhi, Xlo, Whi, Wlo, op);

    // 3) attention
    attn_kernel<<<dim3(16, 16, 2), 256, 0, stream>>>(Qhi, Qlo, Khi, Klo, VTp, CTX);

    // 4) output projection
    gemm_out_kernel<<<dim3(8, 64), 256, 0, stream>>>(
        CTX, Whi + 3 * WSZ, (const float*)d_in[16], (float*)d_out);
}

// Round 10
// 268.984 us; speedup vs baseline: 4.4136x; 1.0226x over previous
//
#include <hip/hip_runtime.h>
#include <hip/hip_bf16.h>
#include <stdint.h>

#define LQ 2048
#define NTOK 4096

typedef __attribute__((ext_vector_type(8))) short short8;
typedef __attribute__((ext_vector_type(4))) float f32x4;
typedef __attribute__((ext_vector_type(16))) float f32x16;
typedef __attribute__((ext_vector_type(4))) unsigned short u16x4;

#define MFMA16(a, b, c) __builtin_amdgcn_mfma_f32_16x16x32_bf16((a), (b), (c), 0, 0, 0)
#define MFMA32(a, b, c) __builtin_amdgcn_mfma_f32_32x32x16_bf16((a), (b), (c), 0, 0, 0)

__device__ __forceinline__ unsigned short f2bf(float x) {
    union { __hip_bfloat16 b; unsigned short u; } v;
    v.b = __float2bfloat16(x);
    return v.u;
}
__device__ __forceinline__ float bf2f(unsigned short h) {
    union { uint32_t u; float f; } v; v.u = ((uint32_t)h) << 16; return v.f;
}
__device__ __forceinline__ unsigned int cvtpk_bf16(float lo, float hi_) {
    unsigned int r;
    asm("v_cvt_pk_bf16_f32 %0, %1, %2" : "=v"(r) : "v"(lo), "v"(hi_));
    return r;
}
__device__ __forceinline__ void permswap(unsigned int &a, unsigned int &b) {
    asm("v_permlane32_swap_b32 %0, %1" : "+v"(a), "+v"(b));
}
__device__ __forceinline__ float fast_exp2(float x) {
    float r;
    asm("v_exp_f32 %0, %1" : "=v"(r) : "v"(x));
    return r;
}

struct CorePtrs {
    const float* c0[4];
    const float* c1[4];
    const float* c2[4];
};

struct QkvOut {
    unsigned short* qhi;
    unsigned short* qlo;
    unsigned short* khi;
    unsigned short* klo;
    unsigned short* vt;          // [1024][4096] transposed V
    const float* bias[3];
    float qscale;
};

// ---------------------------------------------------------------------------
// Kernel 1: blocks 0..255 materialize W hi/lo (4 projections);
// blocks 256..4351 split the input activations fp32 -> bf16 hi/lo.
// ---------------------------------------------------------------------------
__global__ __launch_bounds__(256) void prep_kernel(
    CorePtrs cp, unsigned short* __restrict__ Whi, unsigned short* __restrict__ Wlo,
    const float* __restrict__ X, unsigned short* __restrict__ Xhi,
    unsigned short* __restrict__ Xlo)
{
    const int blk = blockIdx.x;
    const int t = threadIdx.x;
    if (blk >= 256) {
        const int i = (blk - 256) * 256 + t;
        const float4 v = ((const float4*)X)[i];
        u16x4 hi, lo;
        float vv[4] = {v.x, v.y, v.z, v.w};
#pragma unroll
        for (int j = 0; j < 4; ++j) {
            unsigned short h = f2bf(vv[j]);
            hi[j] = h;
            lo[j] = f2bf(vv[j] - bf2f(h));
        }
        ((u16x4*)Xhi)[i] = hi;
        ((u16x4*)Xlo)[i] = lo;
        return;
    }
    __shared__ float B1[16 * 16 * 16];   // [i1][q1][s2]
    const int p  = blk >> 6;
    const int i0 = (blk & 63) >> 3;
    const int q0 = blk & 7;
    const float* __restrict__ c0 = cp.c0[p];
    const float* __restrict__ c1 = cp.c1[p];
    const float* __restrict__ c2 = cp.c2[p];

    float g0[16];
#pragma unroll
    for (int s = 0; s < 16; ++s) g0[s] = c0[(i0 * 8 + q0) * 16 + s];

    for (int idx = t; idx < 4096; idx += 256) {
        const int s2 = idx & 15;
        const int q1 = (idx >> 4) & 15;
        const int i1 = idx >> 8;
        float acc = 0.f;
#pragma unroll
        for (int s = 0; s < 16; ++s)
            acc += g0[s] * c1[((s * 16 + i1) * 16 + q1) * 16 + s2];
        B1[idx] = acc;
    }
    __syncthreads();

    const size_t base = (size_t)p * 1024 * 1024;
    for (int idx = t; idx < 16384; idx += 256) {
        const int q2 = idx & 7;
        const int i2 = (idx >> 3) & 7;
        const int q1 = (idx >> 6) & 15;
        const int i1 = idx >> 10;
        float acc = 0.f;
#pragma unroll
        for (int s2 = 0; s2 < 16; ++s2)
            acc += B1[(i1 * 16 + q1) * 16 + s2] * c2[(s2 * 8 + i2) * 8 + q2];
        const int o = q0 * 128 + q1 * 8 + q2;
        const int e = i0 * 128 + i1 * 8 + i2;
        const unsigned short hi = f2bf(acc);
        Whi[base + o * 1024 + e] = hi;
        Wlo[base + o * 1024 + e] = f2bf(acc - bf2f(hi));
    }
}

// ---------------------------------------------------------------------------
// Kernel 2: FUSED QKV split GEMM over N=3072. V blocks: hi pass only,
// epilogue writes V transposed directly.
// ---------------------------------------------------------------------------
__global__ __launch_bounds__(256) void gemm_qkv_kernel(
    const unsigned short* __restrict__ Xh, const unsigned short* __restrict__ Xl,
    const unsigned short* __restrict__ Wh, const unsigned short* __restrict__ Wl,
    QkvOut op)
{
    __shared__ unsigned short Ah[128 * 32];
    __shared__ unsigned short Bh[128 * 32];
    __shared__ unsigned short Al[128 * 32];
    __shared__ unsigned short Bl[128 * 32];

    const int t = threadIdx.x;
    const int l = t & 63;
    const int w = t >> 6;
    const int wr = (w >> 1) * 64, wc = (w & 1) * 64;
    const int bm = blockIdx.y * 128, bn = blockIdx.x * 128;
    const bool is_v = (bn >> 10) == 2;     // block-uniform

    f32x4 acc[4][4];
#pragma unroll
    for (int i = 0; i < 4; ++i)
#pragma unroll
        for (int j = 0; j < 4; ++j) acc[i][j] = (f32x4){0.f, 0.f, 0.f, 0.f};

    const int srow = t >> 1;
    const int sch  = (t & 1) * 2;
    const int ssel = (srow >> 1) & 3;
    const int sd0  = srow * 32 + (((sch)     ^ ssel) << 3);
    const int sd1  = srow * 32 + (((sch + 1) ^ ssel) << 3);
    const size_t xoff = (size_t)(bm + srow) * 1024 + sch * 8;
    const size_t woff = (size_t)(bn + srow) * 1024 + sch * 8;

    const int fsel = ((l & 15) >> 1) & 3;
    const int fpos = ((l >> 4) ^ fsel) << 3;
    const int fra  = (wr + (l & 15)) * 32 + fpos;
    const int frb  = (wc + (l & 15)) * 32 + fpos;

    short8 pXh0, pXh1, pWh0, pWh1, pXl0, pXl1, pWl0, pWl1;
    pXh0 = *(const short8*)&Xh[xoff];     pXh1 = *(const short8*)&Xh[xoff + 8];
    pWh0 = *(const short8*)&Wh[woff];     pWh1 = *(const short8*)&Wh[woff + 8];
    if (!is_v) {
        pXl0 = *(const short8*)&Xl[xoff]; pXl1 = *(const short8*)&Xl[xoff + 8];
        pWl0 = *(const short8*)&Wl[woff]; pWl1 = *(const short8*)&Wl[woff + 8];
    }

    for (int e0 = 0; e0 < 1024; e0 += 32) {
        __syncthreads();
        *(short8*)&Ah[sd0] = pXh0; *(short8*)&Ah[sd1] = pXh1;
        *(short8*)&Bh[sd0] = pWh0; *(short8*)&Bh[sd1] = pWh1;
        if (!is_v) {
            *(short8*)&Al[sd0] = pXl0; *(short8*)&Al[sd1] = pXl1;
            *(short8*)&Bl[sd0] = pWl0; *(short8*)&Bl[sd1] = pWl1;
        }
        __syncthreads();

        if (e0 + 32 < 1024) {
            const size_t xo = xoff + e0 + 32, wo = woff + e0 + 32;
            pXh0 = *(const short8*)&Xh[xo];     pXh1 = *(const short8*)&Xh[xo + 8];
            pWh0 = *(const short8*)&Wh[wo];     pWh1 = *(const short8*)&Wh[wo + 8];
            if (!is_v) {
                pXl0 = *(const short8*)&Xl[xo]; pXl1 = *(const short8*)&Xl[xo + 8];
                pWl0 = *(const short8*)&Wl[wo]; pWl1 = *(const short8*)&Wl[wo + 8];
            }
        }

        short8 af[4], bfv[4], afl[4], bfl[4];
#pragma unroll
        for (int rb = 0; rb < 4; ++rb) {
            af[rb]  = *(const short8*)&Ah[fra + rb * 512];
            bfv[rb] = *(const short8*)&Bh[frb + rb * 512];
        }
#pragma unroll
        for (int rb = 0; rb < 4; ++rb)
#pragma unroll
            for (int cb = 0; cb < 4; ++cb)
                acc[rb][cb] = MFMA16(af[rb], bfv[cb], acc[rb][cb]);
        if (!is_v) {
#pragma unroll
            for (int rb = 0; rb < 4; ++rb) afl[rb] = *(const short8*)&Al[fra + rb * 512];
#pragma unroll
            for (int rb = 0; rb < 4; ++rb)
#pragma unroll
                for (int cb = 0; cb < 4; ++cb)
                    acc[rb][cb] = MFMA16(afl[rb], bfv[cb], acc[rb][cb]);
#pragma unroll
            for (int rb = 0; rb < 4; ++rb) bfl[rb] = *(const short8*)&Bl[frb + rb * 512];
#pragma unroll
            for (int rb = 0; rb < 4; ++rb)
#pragma unroll
                for (int cb = 0; cb < 4; ++cb)
                    acc[rb][cb] = MFMA16(af[rb], bfl[cb], acc[rb][cb]);
        }
    }

    const int p = bn >> 10;                       // 0=Q 1=K 2=V (block-uniform)
    const float* __restrict__ bp = op.bias[p];
    const int bnl = bn & 1023;
    const int r0 = (l >> 4) * 4;
    const int cc = l & 15;

    if (p < 2) {
        unsigned short* __restrict__ yh = (p == 0) ? op.qhi : op.khi;
        unsigned short* __restrict__ yl = (p == 0) ? op.qlo : op.klo;
        const float osc = (p == 0) ? op.qscale : 1.0f;
#pragma unroll
        for (int rb = 0; rb < 4; ++rb)
#pragma unroll
            for (int cb = 0; cb < 4; ++cb) {
                const int col = bnl + wc + cb * 16 + cc;
                const float bv = bp[col];
#pragma unroll
                for (int r = 0; r < 4; ++r) {
                    const int row = bm + wr + rb * 16 + r0 + r;
                    const float v = (acc[rb][cb][r] + bv) * osc;
                    const unsigned short hi = f2bf(v);
                    yh[(size_t)row * 1024 + col] = hi;
                    yl[(size_t)row * 1024 + col] = f2bf(v - bf2f(hi));
                }
            }
    } else {
        unsigned short* __restrict__ vt = op.vt;
#pragma unroll
        for (int rb = 0; rb < 4; ++rb)
#pragma unroll
            for (int cb = 0; cb < 4; ++cb) {
                const int col = bnl + wc + cb * 16 + cc;
                const float bv = bp[col];
                u16x4 pk;
#pragma unroll
                for (int r = 0; r < 4; ++r)
                    pk[r] = f2bf(acc[rb][cb][r] + bv);
                const int row0 = bm + wr + rb * 16 + r0;
                *(u16x4*)&vt[(size_t)col * 4096 + row0] = pk;
            }
    }
}

// ---------------------------------------------------------------------------
// Kernel 3 (R10 retile): output projection GEMM, 64x64 tile, 4 waves (2x2,
// each 32x32 = 2x2 frags). grid (16,64) = 1024 blocks = 4/CU; LDS only 8KB,
// so barrier drains overlap across 4 co-resident blocks.
// ---------------------------------------------------------------------------
__global__ __launch_bounds__(256) void gemm_out_kernel(
    const unsigned short* __restrict__ Xh,
    const unsigned short* __restrict__ Wh,
    const float* __restrict__ bias,
    float* __restrict__ Yf)
{
    __shared__ unsigned short Ah[64 * 32];
    __shared__ unsigned short Bh[64 * 32];

    const int t = threadIdx.x;
    const int l = t & 63;
    const int w = t >> 6;
    const int wr = (w >> 1) * 32, wc = (w & 1) * 32;
    const int bm = blockIdx.y * 64, bn = blockIdx.x * 64;

    f32x4 acc[2][2];
#pragma unroll
    for (int i = 0; i < 2; ++i)
#pragma unroll
        for (int j = 0; j < 2; ++j) acc[i][j] = (f32x4){0.f, 0.f, 0.f, 0.f};

    // staging: 64 rows x 4 chunks(16B) each for A and B, 1 chunk/thread
    const int srow = t >> 2, sch = t & 3;
    const int sd   = srow * 32 + ((sch ^ ((srow >> 1) & 3)) << 3);
    const size_t xoff = (size_t)(bm + srow) * 1024 + sch * 8;
    const size_t woff = (size_t)(bn + srow) * 1024 + sch * 8;

    const int fsel = ((l & 15) >> 1) & 3;
    const int fpos = ((l >> 4) ^ fsel) << 3;
    const int fra  = (wr + (l & 15)) * 32 + fpos;
    const int frb  = (wc + (l & 15)) * 32 + fpos;

    short8 pA, pB;
    pA = *(const short8*)&Xh[xoff];
    pB = *(const short8*)&Wh[woff];

    for (int e0 = 0; e0 < 1024; e0 += 32) {
        __syncthreads();
        *(short8*)&Ah[sd] = pA;
        *(short8*)&Bh[sd] = pB;
        __syncthreads();

        if (e0 + 32 < 1024) {
            pA = *(const short8*)&Xh[xoff + e0 + 32];
            pB = *(const short8*)&Wh[woff + e0 + 32];
        }

        short8 af[2], bfv[2];
#pragma unroll
        for (int rb = 0; rb < 2; ++rb) af[rb] = *(const short8*)&Ah[fra + rb * 512];
#pragma unroll
        for (int cb = 0; cb < 2; ++cb) bfv[cb] = *(const short8*)&Bh[frb + cb * 512];
#pragma unroll
        for (int rb = 0; rb < 2; ++rb)
#pragma unroll
            for (int cb = 0; cb < 2; ++cb)
                acc[rb][cb] = MFMA16(af[rb], bfv[cb], acc[rb][cb]);
    }

    const int r0 = (l >> 4) * 4;
    const int cc = l & 15;
#pragma unroll
    for (int rb = 0; rb < 2; ++rb)
#pragma unroll
        for (int cb = 0; cb < 2; ++cb) {
            const int col = bn + wc + cb * 16 + cc;
            const float bv = bias[col];
#pragma unroll
            for (int r = 0; r < 4; ++r) {
                const int row = bm + wr + rb * 16 + r0 + r;
                Yf[(size_t)row * 1024 + col] = acc[rb][cb][r] + bv;
            }
        }
}

// ---------------------------------------------------------------------------
// Kernel 4: flash attention, 32x32 MFMA, swapped QK^T — exact R7 body
// (measured 81 µs; R8's reduction-partial tweak reverted: measured −9.5 µs).
// ---------------------------------------------------------------------------
__global__ __launch_bounds__(256) void attn_kernel(
    const unsigned short* __restrict__ Qh, const unsigned short* __restrict__ Ql,
    const unsigned short* __restrict__ Kh_g, const unsigned short* __restrict__ Kl_g,
    const unsigned short* __restrict__ VT, unsigned short* __restrict__ CTX)
{
    __shared__ unsigned short Khs[2][64 * 64];
    __shared__ unsigned short Kls[2][64 * 64];
    __shared__ unsigned short Vts[2][64 * 64];   // [d][k]

    const int t = threadIdx.x;
    const int l = t & 63;
    const int w = t >> 6;
    const int qt = blockIdx.x, h = blockIdx.y, b = blockIdx.z;
    const int lq = l & 31;
    const int hi = l >> 5;
    const int tokq = b * LQ + qt * 128 + w * 32;

    short8 qhf[4], qlf[4];
    {
        const size_t qr = (size_t)(tokq + lq) * 1024 + h * 64 + hi * 8;
#pragma unroll
        for (int ds = 0; ds < 4; ++ds) {
            qhf[ds] = *(const short8*)&Qh[qr + ds * 16];
            qlf[ds] = *(const short8*)&Ql[qr + ds * 16];
        }
    }

    f32x16 o0, o1;
#pragma unroll
    for (int i = 0; i < 16; ++i) { o0[i] = 0.f; o1[i] = 0.f; }
    float m = -1e30f, lsum = 0.f;

    const int srow = t >> 2;          // 0..63
    const int sch  = (t & 3) * 2;
    int sdst[2];
#pragma unroll
    for (int it = 0; it < 2; ++it)
        sdst[it] = srow * 64 + (((sch + it) ^ (srow & 7)) << 3);

    const unsigned short* pkh = Kh_g + (size_t)(b * LQ + srow) * 1024 + h * 64 + sch * 8;
    const unsigned short* pkl = Kl_g + (size_t)(b * LQ + srow) * 1024 + h * 64 + sch * 8;
    const unsigned short* pvt = VT + (size_t)(h * 64 + srow) * 4096 + b * LQ + sch * 8;

    short8 pf_kh[2], pf_kl[2], pf_vt[2];
    pf_kh[0] = *(const short8*)pkh;       pf_kh[1] = *(const short8*)(pkh + 8);
    pf_kl[0] = *(const short8*)pkl;       pf_kl[1] = *(const short8*)(pkl + 8);
    pf_vt[0] = *(const short8*)pvt;       pf_vt[1] = *(const short8*)(pvt + 8);

    const int lq7 = lq & 7;
    int qkoff[4], pvslot[4];
#pragma unroll
    for (int i = 0; i < 4; ++i) {
        qkoff[i]  = lq * 64 + (((2 * i + hi) ^ lq7) << 3);
        pvslot[i] = (((2 * i + hi) ^ lq7) << 3);
    }

    int cur = 0;
    for (int kt = 0; kt < 32; ++kt) {
#pragma unroll
        for (int it = 0; it < 2; ++it) {
            *(short8*)&Khs[cur][sdst[it]] = pf_kh[it];
            *(short8*)&Kls[cur][sdst[it]] = pf_kl[it];
            *(short8*)&Vts[cur][sdst[it]] = pf_vt[it];
        }
        if (kt < 31) {
            pkh += 64 * 1024; pkl += 64 * 1024; pvt += 64;
            pf_kh[0] = *(const short8*)pkh;  pf_kh[1] = *(const short8*)(pkh + 8);
            pf_kl[0] = *(const short8*)pkl;  pf_kl[1] = *(const short8*)(pkl + 8);
            pf_vt[0] = *(const short8*)pvt;  pf_vt[1] = *(const short8*)(pvt + 8);
        }
        __syncthreads();

        // ---- swapped QK^T (3-pass split): S'[key][q] ----
        f32x16 s0, s1;
#pragma unroll
        for (int i = 0; i < 16; ++i) { s0[i] = 0.f; s1[i] = 0.f; }
        __builtin_amdgcn_s_setprio(1);
#pragma unroll
        for (int ds = 0; ds < 4; ++ds) {
            const int off = qkoff[ds];
            short8 kh0 = *(const short8*)&Khs[cur][off];
            short8 kh1 = *(const short8*)&Khs[cur][off + 2048];
            short8 kl0 = *(const short8*)&Kls[cur][off];
            short8 kl1 = *(const short8*)&Kls[cur][off + 2048];
            s0 = MFMA32(kh0, qhf[ds], s0);
            s1 = MFMA32(kh1, qhf[ds], s1);
            s0 = MFMA32(kl0, qhf[ds], s0);
            s1 = MFMA32(kl1, qhf[ds], s1);
            s0 = MFMA32(kh0, qlf[ds], s0);
            s1 = MFMA32(kh1, qlf[ds], s1);
        }
        __builtin_amdgcn_s_setprio(0);

        // ---- lane-local online softmax (base 2), defer-max THR=8 ----
        float vm = fmaxf(fmaxf(s0[0], s0[1]), s0[2]);
#pragma unroll
        for (int i = 3; i < 15; i += 2) vm = fmaxf(fmaxf(s0[i], s0[i + 1]), vm);
        vm = fmaxf(fmaxf(s0[15], s1[0]), vm);
#pragma unroll
        for (int i = 1; i < 15; i += 2) vm = fmaxf(fmaxf(s1[i], s1[i + 1]), vm);
        vm = fmaxf(s1[15], vm);
        vm = fmaxf(vm, __shfl_xor(vm, 32));
        const float mg = fmaxf(m, vm);
        if (__any(mg > m + 8.f)) {
            const float mu = (mg > m + 8.f) ? mg : m;
            const float alpha = fast_exp2(m - mu);
            lsum *= alpha;
            o0 *= alpha;
            o1 *= alpha;
            m = mu;
        }
        float ps = 0.f;
#pragma unroll
        for (int i = 0; i < 16; ++i) { s0[i] = fast_exp2(s0[i] - m); ps += s0[i]; }
#pragma unroll
        for (int i = 0; i < 16; ++i) { s1[i] = fast_exp2(s1[i] - m); ps += s1[i]; }
        lsum += ps;

        // ---- pack P into PV B-fragments (cvt_pk + permlane32_swap) ----
        unsigned int pw[4][4];
        {
            unsigned int a, bb;
            a = cvtpk_bf16(s0[0], s0[1]); bb = cvtpk_bf16(s0[4], s0[5]);
            permswap(a, bb); pw[0][0] = a; pw[0][2] = bb;
            a = cvtpk_bf16(s0[2], s0[3]); bb = cvtpk_bf16(s0[6], s0[7]);
            permswap(a, bb); pw[0][1] = a; pw[0][3] = bb;
            a = cvtpk_bf16(s0[8], s0[9]); bb = cvtpk_bf16(s0[12], s0[13]);
            permswap(a, bb); pw[1][0] = a; pw[1][2] = bb;
            a = cvtpk_bf16(s0[10], s0[11]); bb = cvtpk_bf16(s0[14], s0[15]);
            permswap(a, bb); pw[1][1] = a; pw[1][3] = bb;
            a = cvtpk_bf16(s1[0], s1[1]); bb = cvtpk_bf16(s1[4], s1[5]);
            permswap(a, bb); pw[2][0] = a; pw[2][2] = bb;
            a = cvtpk_bf16(s1[2], s1[3]); bb = cvtpk_bf16(s1[6], s1[7]);
            permswap(a, bb); pw[2][1] = a; pw[2][3] = bb;
            a = cvtpk_bf16(s1[8], s1[9]); bb = cvtpk_bf16(s1[12], s1[13]);
            permswap(a, bb); pw[3][0] = a; pw[3][2] = bb;
            a = cvtpk_bf16(s1[10], s1[11]); bb = cvtpk_bf16(s1[14], s1[15]);
            permswap(a, bb); pw[3][1] = a; pw[3][3] = bb;
        }

        // ---- PV: O^T += V^T-frag x P-frag ----
        __builtin_amdgcn_s_setprio(1);
#pragma unroll
        for (int ks = 0; ks < 4; ++ks) {
            union { unsigned int u[4]; short8 v; } pa;
            pa.u[0] = pw[ks][0]; pa.u[1] = pw[ks][1];
            pa.u[2] = pw[ks][2]; pa.u[3] = pw[ks][3];
            const int slot = pvslot[ks];
            short8 va = *(const short8*)&Vts[cur][lq * 64 + slot];
            short8 vb = *(const short8*)&Vts[cur][(32 + lq) * 64 + slot];
            o0 = MFMA32(va, pa.v, o0);
            o1 = MFMA32(vb, pa.v, o1);
        }
        __builtin_amdgcn_s_setprio(0);
        cur ^= 1;
    }

    // ---- finalize ----
    lsum += __shfl_xor(lsum, 32);
    const float inv = 1.f / lsum;
    const size_t orow = (size_t)(tokq + lq) * 1024 + h * 64 + hi * 4;
#pragma unroll
    for (int g = 0; g < 4; ++g) {
        u16x4 pack0, pack1;
#pragma unroll
        for (int j = 0; j < 4; ++j) {
            pack0[j] = f2bf(o0[4 * g + j] * inv);
            pack1[j] = f2bf(o1[4 * g + j] * inv);
        }
        *(u16x4*)&CTX[orow + 8 * g]      = pack0;
        *(u16x4*)&CTX[orow + 32 + 8 * g] = pack1;
    }
}

// ---------------------------------------------------------------------------
extern "C" void kernel_launch(void* const* d_in, const int* in_sizes, int n_in,
                              void* d_out, int out_size, void* d_ws, size_t ws_size,
                              hipStream_t stream)
{
    (void)in_sizes; (void)n_in; (void)out_size; (void)ws_size;
    const float* query = (const float*)d_in[0];
    char* base = (char*)d_ws;
    const size_t MB = 1 << 20;
    unsigned short* Whi = (unsigned short*)(base + 0 * MB);
    unsigned short* Wlo = (unsigned short*)(base + 8 * MB);
    unsigned short* Xhi = (unsigned short*)(base + 16 * MB);
    unsigned short* Xlo = (unsigned short*)(base + 24 * MB);
    unsigned short* Qhi = (unsigned short*)(base + 32 * MB);
    unsigned short* Qlo = (unsigned short*)(base + 40 * MB);
    unsigned short* Khi = (unsigned short*)(base + 48 * MB);
    unsigned short* Klo = (unsigned short*)(base + 56 * MB);
    unsigned short* VTp = (unsigned short*)(base + 72 * MB);
    unsigned short* CTX = (unsigned short*)(base + 16 * MB);   // reuse X region

    CorePtrs cp;
    for (int p = 0; p < 4; ++p) {
        cp.c0[p] = (const float*)d_in[1 + 4 * p];
        cp.c1[p] = (const float*)d_in[2 + 4 * p];
        cp.c2[p] = (const float*)d_in[3 + 4 * p];
    }
    const size_t WSZ = (size_t)1024 * 1024;
    const float QSCALE = 0.125f * 1.44269504088896340736f;   // fold log2(e)

    prep_kernel<<<4352, 256, 0, stream>>>(cp, Whi, Wlo, query, Xhi, Xlo);

    QkvOut op;
    op.qhi = Qhi; op.qlo = Qlo; op.khi = Khi; op.klo = Klo; op.vt = VTp;
    op.bias[0] = (const float*)d_in[4];
    op.bias[1] = (const float*)d_in[8];
    op.bias[2] = (const float*)d_in[12];
    op.qscale = QSCALE;
    gemm_qkv_kernel<<<dim3(24, 32), 256, 0, stream>>>(Xhi, Xlo, Whi, Wlo, op);

    attn_kernel<<<dim3(16, 16, 2), 256, 0, stream>>>(Qhi, Qlo, Khi, Klo, VTp, CTX);

    gemm_out_kernel<<<dim3(16, 64), 256, 0, stream>>>(
        CTX, Whi + 3 * WSZ, (const float*)d_in[16], (float*)d_out);
}

// Round 11
// 265.661 us; speedup vs baseline: 4.4688x; 1.0125x over previous
//
#include <hip/hip_runtime.h>
#include <hip/hip_bf16.h>
#include <stdint.h>

#define LQ 2048
#define NTOK 4096

typedef __attribute__((ext_vector_type(8))) short short8;
typedef __attribute__((ext_vector_type(4))) float f32x4;
typedef __attribute__((ext_vector_type(16))) float f32x16;
typedef __attribute__((ext_vector_type(4))) unsigned short u16x4;

#define MFMA16(a, b, c) __builtin_amdgcn_mfma_f32_16x16x32_bf16((a), (b), (c), 0, 0, 0)
#define MFMA32(a, b, c) __builtin_amdgcn_mfma_f32_32x32x16_bf16((a), (b), (c), 0, 0, 0)

__device__ __forceinline__ unsigned short f2bf(float x) {
    union { __hip_bfloat16 b; unsigned short u; } v;
    v.b = __float2bfloat16(x);
    return v.u;
}
__device__ __forceinline__ float bf2f(unsigned short h) {
    union { uint32_t u; float f; } v; v.u = ((uint32_t)h) << 16; return v.f;
}
__device__ __forceinline__ unsigned int cvtpk_bf16(float lo, float hi_) {
    unsigned int r;
    asm("v_cvt_pk_bf16_f32 %0, %1, %2" : "=v"(r) : "v"(lo), "v"(hi_));
    return r;
}
__device__ __forceinline__ void permswap(unsigned int &a, unsigned int &b) {
    asm("v_permlane32_swap_b32 %0, %1" : "+v"(a), "+v"(b));
}
__device__ __forceinline__ float fast_exp2(float x) {
    float r;
    asm("v_exp_f32 %0, %1" : "=v"(r) : "v"(x));
    return r;
}
// async global->LDS DMA, 16B/lane. LDS dest must be wave-uniform base
// (HW adds lane*16); global src is per-lane.
__device__ __forceinline__ void gld16(const void* g, void* l) {
    __builtin_amdgcn_global_load_lds(
        (const __attribute__((address_space(1))) void*)g,
        (__attribute__((address_space(3))) void*)l,
        16, 0, 0);
}

struct CorePtrs {
    const float* c0[4];
    const float* c1[4];
    const float* c2[4];
};

struct QkvOut {
    unsigned short* qhi;
    unsigned short* qlo;
    unsigned short* khi;
    unsigned short* klo;
    unsigned short* vt;          // [1024][4096] transposed V
    const float* bias[3];
    float qscale;
};

// ---------------------------------------------------------------------------
// Kernel 1: blocks 0..255 materialize W hi/lo (4 projections);
// blocks 256..4351 split the input activations fp32 -> bf16 hi/lo.
// ---------------------------------------------------------------------------
__global__ __launch_bounds__(256) void prep_kernel(
    CorePtrs cp, unsigned short* __restrict__ Whi, unsigned short* __restrict__ Wlo,
    const float* __restrict__ X, unsigned short* __restrict__ Xhi,
    unsigned short* __restrict__ Xlo)
{
    const int blk = blockIdx.x;
    const int t = threadIdx.x;
    if (blk >= 256) {
        const int i = (blk - 256) * 256 + t;
        const float4 v = ((const float4*)X)[i];
        u16x4 hi, lo;
        float vv[4] = {v.x, v.y, v.z, v.w};
#pragma unroll
        for (int j = 0; j < 4; ++j) {
            unsigned short h = f2bf(vv[j]);
            hi[j] = h;
            lo[j] = f2bf(vv[j] - bf2f(h));
        }
        ((u16x4*)Xhi)[i] = hi;
        ((u16x4*)Xlo)[i] = lo;
        return;
    }
    __shared__ float B1[16 * 16 * 16];   // [i1][q1][s2]
    const int p  = blk >> 6;
    const int i0 = (blk & 63) >> 3;
    const int q0 = blk & 7;
    const float* __restrict__ c0 = cp.c0[p];
    const float* __restrict__ c1 = cp.c1[p];
    const float* __restrict__ c2 = cp.c2[p];

    float g0[16];
#pragma unroll
    for (int s = 0; s < 16; ++s) g0[s] = c0[(i0 * 8 + q0) * 16 + s];

    for (int idx = t; idx < 4096; idx += 256) {
        const int s2 = idx & 15;
        const int q1 = (idx >> 4) & 15;
        const int i1 = idx >> 8;
        float acc = 0.f;
#pragma unroll
        for (int s = 0; s < 16; ++s)
            acc += g0[s] * c1[((s * 16 + i1) * 16 + q1) * 16 + s2];
        B1[idx] = acc;
    }
    __syncthreads();

    const size_t base = (size_t)p * 1024 * 1024;
    for (int idx = t; idx < 16384; idx += 256) {
        const int q2 = idx & 7;
        const int i2 = (idx >> 3) & 7;
        const int q1 = (idx >> 6) & 15;
        const int i1 = idx >> 10;
        float acc = 0.f;
#pragma unroll
        for (int s2 = 0; s2 < 16; ++s2)
            acc += B1[(i1 * 16 + q1) * 16 + s2] * c2[(s2 * 8 + i2) * 8 + q2];
        const int o = q0 * 128 + q1 * 8 + q2;
        const int e = i0 * 128 + i1 * 8 + i2;
        const unsigned short hi = f2bf(acc);
        Whi[base + o * 1024 + e] = hi;
        Wlo[base + o * 1024 + e] = f2bf(acc - bf2f(hi));
    }
}

// ---------------------------------------------------------------------------
// Kernel 2 (R11): FUSED QKV split GEMM, global_load_lds staging.
// LDS layout linear (DMA requirement); the SOURCE address is pre-swizzled
// (chunk = pos ^ ((row>>1)&3), a permutation inside each 64B segment -> still
// coalesced) so the existing swizzled ds_read fragment addressing is unchanged.
// Single buffer, 2 barriers/iter. V blocks: hi pass only + transposed output.
// ---------------------------------------------------------------------------
__global__ __launch_bounds__(256) void gemm_qkv_kernel(
    const unsigned short* __restrict__ Xh, const unsigned short* __restrict__ Xl,
    const unsigned short* __restrict__ Wh, const unsigned short* __restrict__ Wl,
    QkvOut op)
{
    __shared__ unsigned short Ah[128 * 32];
    __shared__ unsigned short Bh[128 * 32];
    __shared__ unsigned short Al[128 * 32];
    __shared__ unsigned short Bl[128 * 32];

    const int t = threadIdx.x;
    const int l = t & 63;
    const int w = t >> 6;
    const int wr = (w >> 1) * 64, wc = (w & 1) * 64;
    const int bm = blockIdx.y * 128, bn = blockIdx.x * 128;
    const bool is_v = (bn >> 10) == 2;     // block-uniform

    f32x4 acc[4][4];
#pragma unroll
    for (int i = 0; i < 4; ++i)
#pragma unroll
        for (int j = 0; j < 4; ++j) acc[i][j] = (f32x4){0.f, 0.f, 0.f, 0.f};

    // DMA staging: wave w stages rows [w*32, w*32+32) of each array,
    // 2 instrs per array (16 rows x 64B = 1KB each).
    const int lrow = l >> 2;                       // 0..15 row within group
    const int lpos = l & 3;                        // linear LDS chunk position
    const int schunk = lpos ^ ((lrow >> 1) & 3);   // pre-swizzled source chunk
    const size_t xrow0 = (size_t)(bm + w * 32 + lrow) * 1024 + schunk * 8;
    const size_t wrow0 = (size_t)(bn + w * 32 + lrow) * 1024 + schunk * 8;
    unsigned short* ldsA0 = &Ah[(w * 32) * 32];
    unsigned short* ldsA1 = &Ah[(w * 32 + 16) * 32];
    unsigned short* ldsB0 = &Bh[(w * 32) * 32];
    unsigned short* ldsB1 = &Bh[(w * 32 + 16) * 32];
    unsigned short* ldsC0 = &Al[(w * 32) * 32];
    unsigned short* ldsC1 = &Al[(w * 32 + 16) * 32];
    unsigned short* ldsD0 = &Bl[(w * 32) * 32];
    unsigned short* ldsD1 = &Bl[(w * 32 + 16) * 32];

#define STAGE_QKV(E0) do {                                         \
        gld16(&Xh[xrow0 + (E0)], ldsA0);                           \
        gld16(&Xh[xrow0 + 16 * 1024 + (E0)], ldsA1);               \
        gld16(&Wh[wrow0 + (E0)], ldsB0);                           \
        gld16(&Wh[wrow0 + 16 * 1024 + (E0)], ldsB1);               \
        if (!is_v) {                                               \
            gld16(&Xl[xrow0 + (E0)], ldsC0);                       \
            gld16(&Xl[xrow0 + 16 * 1024 + (E0)], ldsC1);           \
            gld16(&Wl[wrow0 + (E0)], ldsD0);                       \
            gld16(&Wl[wrow0 + 16 * 1024 + (E0)], ldsD1);           \
        }                                                          \
    } while (0)

    const int fsel = ((l & 15) >> 1) & 3;
    const int fpos = ((l >> 4) ^ fsel) << 3;
    const int fra  = (wr + (l & 15)) * 32 + fpos;
    const int frb  = (wc + (l & 15)) * 32 + fpos;

    STAGE_QKV(0);
    for (int e0 = 0; e0 < 1024; e0 += 32) {
        __syncthreads();        // drains DMA (vmcnt0) for this tile

        short8 af[4], bfv[4], afl[4], bfl[4];
#pragma unroll
        for (int rb = 0; rb < 4; ++rb) {
            af[rb]  = *(const short8*)&Ah[fra + rb * 512];
            bfv[rb] = *(const short8*)&Bh[frb + rb * 512];
        }
#pragma unroll
        for (int rb = 0; rb < 4; ++rb)
#pragma unroll
            for (int cb = 0; cb < 4; ++cb)
                acc[rb][cb] = MFMA16(af[rb], bfv[cb], acc[rb][cb]);
        if (!is_v) {
#pragma unroll
            for (int rb = 0; rb < 4; ++rb) afl[rb] = *(const short8*)&Al[fra + rb * 512];
#pragma unroll
            for (int rb = 0; rb < 4; ++rb)
#pragma unroll
                for (int cb = 0; cb < 4; ++cb)
                    acc[rb][cb] = MFMA16(afl[rb], bfv[cb], acc[rb][cb]);
#pragma unroll
            for (int rb = 0; rb < 4; ++rb) bfl[rb] = *(const short8*)&Bl[frb + rb * 512];
#pragma unroll
            for (int rb = 0; rb < 4; ++rb)
#pragma unroll
                for (int cb = 0; cb < 4; ++cb)
                    acc[rb][cb] = MFMA16(af[rb], bfl[cb], acc[rb][cb]);
        }

        __syncthreads();        // all reads done before next DMA overwrites
        if (e0 + 32 < 1024) STAGE_QKV(e0 + 32);
    }
#undef STAGE_QKV

    const int p = bn >> 10;                       // 0=Q 1=K 2=V (block-uniform)
    const float* __restrict__ bp = op.bias[p];
    const int bnl = bn & 1023;
    const int r0 = (l >> 4) * 4;
    const int cc = l & 15;

    if (p < 2) {
        unsigned short* __restrict__ yh = (p == 0) ? op.qhi : op.khi;
        unsigned short* __restrict__ yl = (p == 0) ? op.qlo : op.klo;
        const float osc = (p == 0) ? op.qscale : 1.0f;
#pragma unroll
        for (int rb = 0; rb < 4; ++rb)
#pragma unroll
            for (int cb = 0; cb < 4; ++cb) {
                const int col = bnl + wc + cb * 16 + cc;
                const float bv = bp[col];
#pragma unroll
                for (int r = 0; r < 4; ++r) {
                    const int row = bm + wr + rb * 16 + r0 + r;
                    const float v = (acc[rb][cb][r] + bv) * osc;
                    const unsigned short hi = f2bf(v);
                    yh[(size_t)row * 1024 + col] = hi;
                    yl[(size_t)row * 1024 + col] = f2bf(v - bf2f(hi));
                }
            }
    } else {
        unsigned short* __restrict__ vt = op.vt;
#pragma unroll
        for (int rb = 0; rb < 4; ++rb)
#pragma unroll
            for (int cb = 0; cb < 4; ++cb) {
                const int col = bnl + wc + cb * 16 + cc;
                const float bv = bp[col];
                u16x4 pk;
#pragma unroll
                for (int r = 0; r < 4; ++r)
                    pk[r] = f2bf(acc[rb][cb][r] + bv);
                const int row0 = bm + wr + rb * 16 + r0;
                *(u16x4*)&vt[(size_t)col * 4096 + row0] = pk;
            }
    }
}

// ---------------------------------------------------------------------------
// Kernel 3 (R11): output projection GEMM, 64x64 tile, global_load_lds staging
// (same pre-swizzled-source scheme). grid (16,64) = 1024 blocks.
// ---------------------------------------------------------------------------
__global__ __launch_bounds__(256) void gemm_out_kernel(
    const unsigned short* __restrict__ Xh,
    const unsigned short* __restrict__ Wh,
    const float* __restrict__ bias,
    float* __restrict__ Yf)
{
    __shared__ unsigned short Ah[64 * 32];
    __shared__ unsigned short Bh[64 * 32];

    const int t = threadIdx.x;
    const int l = t & 63;
    const int w = t >> 6;
    const int wr = (w >> 1) * 32, wc = (w & 1) * 32;
    const int bm = blockIdx.y * 64, bn = blockIdx.x * 64;

    f32x4 acc[2][2];
#pragma unroll
    for (int i = 0; i < 2; ++i)
#pragma unroll
        for (int j = 0; j < 2; ++j) acc[i][j] = (f32x4){0.f, 0.f, 0.f, 0.f};

    // DMA staging: wave w stages rows [w*16, w*16+16) of A and B (1 instr each)
    const int lrow = l >> 2;
    const int lpos = l & 3;
    const int schunk = lpos ^ ((lrow >> 1) & 3);
    const size_t xrow0 = (size_t)(bm + w * 16 + lrow) * 1024 + schunk * 8;
    const size_t wrow0 = (size_t)(bn + w * 16 + lrow) * 1024 + schunk * 8;
    unsigned short* ldsA = &Ah[(w * 16) * 32];
    unsigned short* ldsB = &Bh[(w * 16) * 32];

    const int fsel = ((l & 15) >> 1) & 3;
    const int fpos = ((l >> 4) ^ fsel) << 3;
    const int fra  = (wr + (l & 15)) * 32 + fpos;
    const int frb  = (wc + (l & 15)) * 32 + fpos;

    gld16(&Xh[xrow0], ldsA);
    gld16(&Wh[wrow0], ldsB);
    for (int e0 = 0; e0 < 1024; e0 += 32) {
        __syncthreads();    // drain DMA

        short8 af[2], bfv[2];
#pragma unroll
        for (int rb = 0; rb < 2; ++rb) af[rb] = *(const short8*)&Ah[fra + rb * 512];
#pragma unroll
        for (int cb = 0; cb < 2; ++cb) bfv[cb] = *(const short8*)&Bh[frb + cb * 512];
#pragma unroll
        for (int rb = 0; rb < 2; ++rb)
#pragma unroll
            for (int cb = 0; cb < 2; ++cb)
                acc[rb][cb] = MFMA16(af[rb], bfv[cb], acc[rb][cb]);

        __syncthreads();    // reads done
        if (e0 + 32 < 1024) {
            gld16(&Xh[xrow0 + e0 + 32], ldsA);
            gld16(&Wh[wrow0 + e0 + 32], ldsB);
        }
    }

    const int r0 = (l >> 4) * 4;
    const int cc = l & 15;
#pragma unroll
    for (int rb = 0; rb < 2; ++rb)
#pragma unroll
        for (int cb = 0; cb < 2; ++cb) {
            const int col = bn + wc + cb * 16 + cc;
            const float bv = bias[col];
#pragma unroll
            for (int r = 0; r < 4; ++r) {
                const int row = bm + wr + rb * 16 + r0 + r;
                Yf[(size_t)row * 1024 + col] = acc[rb][cb][r] + bv;
            }
        }
}

// ---------------------------------------------------------------------------
// Kernel 4: flash attention, 32x32 MFMA, swapped QK^T — R7 measured-best body.
// R11: XCD-aware block swizzle only (T1): all 16 q-tiles of a given (h,b)
// land on ONE XCD so K/V stay L2-resident (K+V per (h,b) = 768KB; 4 pairs
// per XCD = 3MB < 4MB L2). grid = 512 x 1 x 1.
// ---------------------------------------------------------------------------
__global__ __launch_bounds__(256) void attn_kernel(
    const unsigned short* __restrict__ Qh, const unsigned short* __restrict__ Ql,
    const unsigned short* __restrict__ Kh_g, const unsigned short* __restrict__ Kl_g,
    const unsigned short* __restrict__ VT, unsigned short* __restrict__ CTX)
{
    __shared__ unsigned short Khs[2][64 * 64];
    __shared__ unsigned short Kls[2][64 * 64];
    __shared__ unsigned short Vts[2][64 * 64];   // [d][k]

    const int t = threadIdx.x;
    const int l = t & 63;
    const int w = t >> 6;
    // XCD swizzle: 512 blocks, bijective (512 % 8 == 0). Consecutive-orig
    // blocks round-robin XCDs; swz makes each XCD own 64 consecutive wgids
    // = 4 complete (h,b) groups of 16 q-tiles.
    const int wg  = (int)blockIdx.x;
    const int swz = (wg & 7) * 64 + (wg >> 3);
    const int qt = swz & 15;
    const int hb = swz >> 4;
    const int h  = hb & 15;
    const int b  = hb >> 4;
    const int lq = l & 31;
    const int hi = l >> 5;
    const int tokq = b * LQ + qt * 128 + w * 32;

    short8 qhf[4], qlf[4];
    {
        const size_t qr = (size_t)(tokq + lq) * 1024 + h * 64 + hi * 8;
#pragma unroll
        for (int ds = 0; ds < 4; ++ds) {
            qhf[ds] = *(const short8*)&Qh[qr + ds * 16];
            qlf[ds] = *(const short8*)&Ql[qr + ds * 16];
        }
    }

    f32x16 o0, o1;
#pragma unroll
    for (int i = 0; i < 16; ++i) { o0[i] = 0.f; o1[i] = 0.f; }
    float m = -1e30f, lsum = 0.f;

    const int srow = t >> 2;          // 0..63
    const int sch  = (t & 3) * 2;
    int sdst[2];
#pragma unroll
    for (int it = 0; it < 2; ++it)
        sdst[it] = srow * 64 + (((sch + it) ^ (srow & 7)) << 3);

    const unsigned short* pkh = Kh_g + (size_t)(b * LQ + srow) * 1024 + h * 64 + sch * 8;
    const unsigned short* pkl = Kl_g + (size_t)(b * LQ + srow) * 1024 + h * 64 + sch * 8;
    const unsigned short* pvt = VT + (size_t)(h * 64 + srow) * 4096 + b * LQ + sch * 8;

    short8 pf_kh[2], pf_kl[2], pf_vt[2];
    pf_kh[0] = *(const short8*)pkh;       pf_kh[1] = *(const short8*)(pkh + 8);
    pf_kl[0] = *(const short8*)pkl;       pf_kl[1] = *(const short8*)(pkl + 8);
    pf_vt[0] = *(const short8*)pvt;       pf_vt[1] = *(const short8*)(pvt + 8);

    const int lq7 = lq & 7;
    int qkoff[4], pvslot[4];
#pragma unroll
    for (int i = 0; i < 4; ++i) {
        qkoff[i]  = lq * 64 + (((2 * i + hi) ^ lq7) << 3);
        pvslot[i] = (((2 * i + hi) ^ lq7) << 3);
    }

    int cur = 0;
    for (int kt = 0; kt < 32; ++kt) {
#pragma unroll
        for (int it = 0; it < 2; ++it) {
            *(short8*)&Khs[cur][sdst[it]] = pf_kh[it];
            *(short8*)&Kls[cur][sdst[it]] = pf_kl[it];
            *(short8*)&Vts[cur][sdst[it]] = pf_vt[it];
        }
        if (kt < 31) {
            pkh += 64 * 1024; pkl += 64 * 1024; pvt += 64;
            pf_kh[0] = *(const short8*)pkh;  pf_kh[1] = *(const short8*)(pkh + 8);
            pf_kl[0] = *(const short8*)pkl;  pf_kl[1] = *(const short8*)(pkl + 8);
            pf_vt[0] = *(const short8*)pvt;  pf_vt[1] = *(const short8*)(pvt + 8);
        }
        __syncthreads();

        // ---- swapped QK^T (3-pass split): S'[key][q] ----
        f32x16 s0, s1;
#pragma unroll
        for (int i = 0; i < 16; ++i) { s0[i] = 0.f; s1[i] = 0.f; }
        __builtin_amdgcn_s_setprio(1);
#pragma unroll
        for (int ds = 0; ds < 4; ++ds) {
            const int off = qkoff[ds];
            short8 kh0 = *(const short8*)&Khs[cur][off];
            short8 kh1 = *(const short8*)&Khs[cur][off + 2048];
            short8 kl0 = *(const short8*)&Kls[cur][off];
            short8 kl1 = *(const short8*)&Kls[cur][off + 2048];
            s0 = MFMA32(kh0, qhf[ds], s0);
            s1 = MFMA32(kh1, qhf[ds], s1);
            s0 = MFMA32(kl0, qhf[ds], s0);
            s1 = MFMA32(kl1, qhf[ds], s1);
            s0 = MFMA32(kh0, qlf[ds], s0);
            s1 = MFMA32(kh1, qlf[ds], s1);
        }
        __builtin_amdgcn_s_setprio(0);

        // ---- lane-local online softmax (base 2), defer-max THR=8 ----
        float vm = fmaxf(fmaxf(s0[0], s0[1]), s0[2]);
#pragma unroll
        for (int i = 3; i < 15; i += 2) vm = fmaxf(fmaxf(s0[i], s0[i + 1]), vm);
        vm = fmaxf(fmaxf(s0[15], s1[0]), vm);
#pragma unroll
        for (int i = 1; i < 15; i += 2) vm = fmaxf(fmaxf(s1[i], s1[i + 1]), vm);
        vm = fmaxf(s1[15], vm);
        vm = fmaxf(vm, __shfl_xor(vm, 32));
        const float mg = fmaxf(m, vm);
        if (__any(mg > m + 8.f)) {
            const float mu = (mg > m + 8.f) ? mg : m;
            const float alpha = fast_exp2(m - mu);
            lsum *= alpha;
            o0 *= alpha;
            o1 *= alpha;
            m = mu;
        }
        float ps = 0.f;
#pragma unroll
        for (int i = 0; i < 16; ++i) { s0[i] = fast_exp2(s0[i] - m); ps += s0[i]; }
#pragma unroll
        for (int i = 0; i < 16; ++i) { s1[i] = fast_exp2(s1[i] - m); ps += s1[i]; }
        lsum += ps;

        // ---- pack P into PV B-fragments (cvt_pk + permlane32_swap) ----
        unsigned int pw[4][4];
        {
            unsigned int a, bb;
            a = cvtpk_bf16(s0[0], s0[1]); bb = cvtpk_bf16(s0[4], s0[5]);
            permswap(a, bb); pw[0][0] = a; pw[0][2] = bb;
            a = cvtpk_bf16(s0[2], s0[3]); bb = cvtpk_bf16(s0[6], s0[7]);
            permswap(a, bb); pw[0][1] = a; pw[0][3] = bb;
            a = cvtpk_bf16(s0[8], s0[9]); bb = cvtpk_bf16(s0[12], s0[13]);
            permswap(a, bb); pw[1][0] = a; pw[1][2] = bb;
            a = cvtpk_bf16(s0[10], s0[11]); bb = cvtpk_bf16(s0[14], s0[15]);
            permswap(a, bb); pw[1][1] = a; pw[1][3] = bb;
            a = cvtpk_bf16(s1[0], s1[1]); bb = cvtpk_bf16(s1[4], s1[5]);
            permswap(a, bb); pw[2][0] = a; pw[2][2] = bb;
            a = cvtpk_bf16(s1[2], s1[3]); bb = cvtpk_bf16(s1[6], s1[7]);
            permswap(a, bb); pw[2][1] = a; pw[2][3] = bb;
            a = cvtpk_bf16(s1[8], s1[9]); bb = cvtpk_bf16(s1[12], s1[13]);
            permswap(a, bb); pw[3][0] = a; pw[3][2] = bb;
            a = cvtpk_bf16(s1[10], s1[11]); bb = cvtpk_bf16(s1[14], s1[15]);
            permswap(a, bb); pw[3][1] = a; pw[3][3] = bb;
        }

        // ---- PV: O^T += V^T-frag x P-frag ----
        __builtin_amdgcn_s_setprio(1);
#pragma unroll
        for (int ks = 0; ks < 4; ++ks) {
            union { unsigned int u[4]; short8 v; } pa;
            pa.u[0] = pw[ks][0]; pa.u[1] = pw[ks][1];
            pa.u[2] = pw[ks][2]; pa.u[3] = pw[ks][3];
            const int slot = pvslot[ks];
            short8 va = *(const short8*)&Vts[cur][lq * 64 + slot];
            short8 vb = *(const short8*)&Vts[cur][(32 + lq) * 64 + slot];
            o0 = MFMA32(va, pa.v, o0);
            o1 = MFMA32(vb, pa.v, o1);
        }
        __builtin_amdgcn_s_setprio(0);
        cur ^= 1;
    }

    // ---- finalize ----
    lsum += __shfl_xor(lsum, 32);
    const float inv = 1.f / lsum;
    const size_t orow = (size_t)(tokq + lq) * 1024 + h * 64 + hi * 4;
#pragma unroll
    for (int g = 0; g < 4; ++g) {
        u16x4 pack0, pack1;
#pragma unroll
        for (int j = 0; j < 4; ++j) {
            pack0[j] = f2bf(o0[4 * g + j] * inv);
            pack1[j] = f2bf(o1[4 * g + j] * inv);
        }
        *(u16x4*)&CTX[orow + 8 * g]      = pack0;
        *(u16x4*)&CTX[orow + 32 + 8 * g] = pack1;
    }
}

// ---------------------------------------------------------------------------
extern "C" void kernel_launch(void* const* d_in, const int* in_sizes, int n_in,
                              void* d_out, int out_size, void* d_ws, size_t ws_size,
                              hipStream_t stream)
{
    (void)in_sizes; (void)n_in; (void)out_size; (void)ws_size;
    const float* query = (const float*)d_in[0];
    char* base = (char*)d_ws;
    const size_t MB = 1 << 20;
    unsigned short* Whi = (unsigned short*)(base + 0 * MB);
    unsigned short* Wlo = (unsigned short*)(base + 8 * MB);
    unsigned short* Xhi = (unsigned short*)(base + 16 * MB);
    unsigned short* Xlo = (unsigned short*)(base + 24 * MB);
    unsigned short* Qhi = (unsigned short*)(base + 32 * MB);
    unsigned short* Qlo = (unsigned short*)(base + 40 * MB);
    unsigned short* Khi = (unsigned short*)(base + 48 * MB);
    unsigned short* Klo = (unsigned short*)(base + 56 * MB);
    unsigned short* VTp = (unsigned short*)(base + 72 * MB);
    unsigned short* CTX = (unsigned short*)(base + 16 * MB);   // reuse X region

    CorePtrs cp;
    for (int p = 0; p < 4; ++p) {
        cp.c0[p] = (const float*)d_in[1 + 4 * p];
        cp.c1[p] = (const float*)d_in[2 + 4 * p];
        cp.c2[p] = (const float*)d_in[3 + 4 * p];
    }
    const size_t WSZ = (size_t)1024 * 1024;
    const float QSCALE = 0.125f * 1.44269504088896340736f;   // fold log2(e)

    prep_kernel<<<4352, 256, 0, stream>>>(cp, Whi, Wlo, query, Xhi, Xlo);

    QkvOut op;
    op.qhi = Qhi; op.qlo = Qlo; op.khi = Khi; op.klo = Klo; op.vt = VTp;
    op.bias[0] = (const float*)d_in[4];
    op.bias[1] = (const float*)d_in[8];
    op.bias[2] = (const float*)d_in[12];
    op.qscale = QSCALE;
    gemm_qkv_kernel<<<dim3(24, 32), 256, 0, stream>>>(Xhi, Xlo, Whi, Wlo, op);

    attn_kernel<<<512, 256, 0, stream>>>(Qhi, Qlo, Khi, Klo, VTp, CTX);

    gemm_out_kernel<<<dim3(16, 64), 256, 0, stream>>>(
        CTX, Whi + 3 * WSZ, (const float*)d_in[16], (float*)d_out);
}